// Round 1
// baseline (949.013 us; speedup 1.0000x reference)
//
#include <hip/hip_runtime.h>
#include <math.h>

#define LEAKY 0.01f
#define BN_EPS 1e-5f

// ---------------------------------------------------------------------------
// Probe: are edges int64 (odd 32-bit words all zero) or int32?
__global__ void k_probe(const int* __restrict__ raw, int* __restrict__ flag)
{
    if (threadIdx.x == 0) {
        int f = 1;
        for (int i = 1; i < 128; i += 2)
            if (raw[i] != 0) { f = 0; break; }
        *flag = f;   // 1 => int64 layout, 0 => int32
    }
}

// ---------------------------------------------------------------------------
// GEMM1: x = fea @ Wlin^T + blin.   64 rows/block, 256 threads.
// LDS: xs transposed [k][row] (32KB) + W-tile transposed [k][j] (32KB) = 64KB.
__global__ __launch_bounds__(256) void k_lin(const float* __restrict__ fea,
                                             const float* __restrict__ W,
                                             const float* __restrict__ bias,
                                             float* __restrict__ xout, int N)
{
    __shared__ float xs[128][64];
    __shared__ float Wt[64][128];
    const int tid = threadIdx.x;
    const int r0  = blockIdx.x * 64;

    #pragma unroll
    for (int it = 0; it < 8; ++it) {
        int flat = it * 256 + tid;
        int row  = flat & 63;
        int kq   = flat >> 6;                 // 0..31
        int r    = r0 + row;
        float4 v = make_float4(0.f, 0.f, 0.f, 0.f);
        if (r < N) v = *reinterpret_cast<const float4*>(&fea[(size_t)r * 128 + kq * 4]);
        xs[kq*4+0][row] = v.x; xs[kq*4+1][row] = v.y;
        xs[kq*4+2][row] = v.z; xs[kq*4+3][row] = v.w;
    }

    const int tx = tid & 15;
    const int ty = tid >> 4;
    float acc[4][8] = {};

    for (int kb = 0; kb < 128; kb += 64) {
        __syncthreads();
        #pragma unroll
        for (int it = 0; it < 8; ++it) {
            int flat = it * 256 + tid;
            int j    = flat & 127;
            int kq   = flat >> 7;             // 0..15
            float4 w = *reinterpret_cast<const float4*>(&W[(size_t)j * 128 + kb + kq * 4]);
            Wt[kq*4+0][j] = w.x; Wt[kq*4+1][j] = w.y;
            Wt[kq*4+2][j] = w.z; Wt[kq*4+3][j] = w.w;
        }
        __syncthreads();
        #pragma unroll 8
        for (int kk = 0; kk < 64; ++kk) {
            float4 xv = *reinterpret_cast<const float4*>(&xs[kb + kk][ty * 4]);
            float4 w0 = *reinterpret_cast<const float4*>(&Wt[kk][tx * 8]);
            float4 w1 = *reinterpret_cast<const float4*>(&Wt[kk][tx * 8 + 4]);
            float xr[4] = {xv.x, xv.y, xv.z, xv.w};
            float wr[8] = {w0.x, w0.y, w0.z, w0.w, w1.x, w1.y, w1.z, w1.w};
            #pragma unroll
            for (int a = 0; a < 4; ++a)
                #pragma unroll
                for (int b = 0; b < 8; ++b)
                    acc[a][b] = fmaf(xr[a], wr[b], acc[a][b]);
        }
    }

    float4 b0 = *reinterpret_cast<const float4*>(&bias[tx * 8]);
    float4 b1 = *reinterpret_cast<const float4*>(&bias[tx * 8 + 4]);
    #pragma unroll
    for (int a = 0; a < 4; ++a) {
        int r = r0 + ty * 4 + a;
        if (r < N) {
            float4 o0 = make_float4(acc[a][0] + b0.x, acc[a][1] + b0.y,
                                    acc[a][2] + b0.z, acc[a][3] + b0.w);
            float4 o1 = make_float4(acc[a][4] + b1.x, acc[a][5] + b1.y,
                                    acc[a][6] + b1.z, acc[a][7] + b1.w);
            *reinterpret_cast<float4*>(&xout[(size_t)r * 128 + tx * 8])     = o0;
            *reinterpret_cast<float4*>(&xout[(size_t)r * 128 + tx * 8 + 4]) = o1;
        }
    }
}

// ---------------------------------------------------------------------------
// Per-feature sum & sum-of-squares (BN batch stats).
__global__ __launch_bounds__(256) void k_stats(const float* __restrict__ x, int N,
                                               float* __restrict__ sums)
{
    const int c    = threadIdx.x & 127;
    const int half = threadIdx.x >> 7;
    float s = 0.f, q = 0.f;
    for (int r = blockIdx.x * 2 + half; r < N; r += gridDim.x * 2) {
        float v = x[(size_t)r * 128 + c];
        s += v; q += v * v;
    }
    __shared__ float ps[256], pq[256];
    ps[threadIdx.x] = s; pq[threadIdx.x] = q;
    __syncthreads();
    if (threadIdx.x < 128) {
        s = ps[threadIdx.x] + ps[threadIdx.x + 128];
        q = pq[threadIdx.x] + pq[threadIdx.x + 128];
        atomicAdd(&sums[c], s);
        atomicAdd(&sums[128 + c], q);
    }
}

__global__ void k_bnfinal(const float* __restrict__ sums,
                          const float* __restrict__ gamma,
                          const float* __restrict__ beta,
                          float invN, float* __restrict__ aff)
{
    int c = threadIdx.x;
    if (c < 128) {
        float mean = sums[c] * invN;
        float var  = sums[128 + c] * invN - mean * mean;
        float coef = gamma[c] * rsqrtf(var + BN_EPS);
        aff[c]       = coef;
        aff[128 + c] = beta[c] - coef * mean;
    }
}

// ---------------------------------------------------------------------------
// Degree histogram over dst (excluding self-loop; +1 applied in k_dinv).
__global__ void k_deg(const void* __restrict__ edges, int E,
                      const int* __restrict__ flag, int* __restrict__ cnt)
{
    const int isI64 = *flag;
    const long long* e64 = (const long long*)edges;
    const int*       e32 = (const int*)edges;
    for (int e = blockIdx.x * blockDim.x + threadIdx.x; e < E;
         e += gridDim.x * blockDim.x) {
        int dst = isI64 ? (int)e64[(size_t)E + e] : e32[(size_t)E + e];
        atomicAdd(&cnt[dst], 1);
    }
}

__global__ void k_dinv(const int* __restrict__ cnt, float* __restrict__ dinv, int N)
{
    int i = blockIdx.x * blockDim.x + threadIdx.x;
    if (i < N) dinv[i] = rsqrtf((float)(cnt[i] + 1));
}

// Single-block exclusive scan of cnt -> offs.
__global__ __launch_bounds__(1024) void k_scan(const int* __restrict__ cnt,
                                               int* __restrict__ offs, int N)
{
    __shared__ int ps[1024];
    const int t     = threadIdx.x;
    const int chunk = (N + 1023) / 1024;
    const int lo    = t * chunk;
    const int hi    = min(lo + chunk, N);
    int s = 0;
    for (int j = lo; j < hi; ++j) s += cnt[j];
    ps[t] = s;
    __syncthreads();
    for (int off = 1; off < 1024; off <<= 1) {
        int v = (t >= off) ? ps[t - off] : 0;
        __syncthreads();
        ps[t] += v;
        __syncthreads();
    }
    int run = ps[t] - s;                      // exclusive prefix
    for (int j = lo; j < hi; ++j) { offs[j] = run; run += cnt[j]; }
}

// Scatter edges into CSR (src list grouped by dst).
__global__ void k_scatter(const void* __restrict__ edges, int E,
                          const int* __restrict__ flag,
                          const int* __restrict__ offs,
                          int* __restrict__ cur, int* __restrict__ csr)
{
    const int isI64 = *flag;
    const long long* e64 = (const long long*)edges;
    const int*       e32 = (const int*)edges;
    for (int e = blockIdx.x * blockDim.x + threadIdx.x; e < E;
         e += gridDim.x * blockDim.x) {
        int src, dst;
        if (isI64) { src = (int)e64[e]; dst = (int)e64[(size_t)E + e]; }
        else       { src = e32[e];      dst = e32[(size_t)E + e]; }
        int pos = atomicAdd(&cur[dst], 1);
        csr[offs[dst] + pos] = src;
    }
}

// ---------------------------------------------------------------------------
// GEMM2 (in-place): h = leakyrelu(a*x + b) @ Wg^T, BN affine fused in staging.
__global__ __launch_bounds__(256) void k_h(float* __restrict__ xh,
                                           const float* __restrict__ W,
                                           const float* __restrict__ aff,
                                           int N)
{
    __shared__ float xs[128][64];
    __shared__ float Wt[64][128];
    const int tid = threadIdx.x;
    const int r0  = blockIdx.x * 64;

    #pragma unroll
    for (int it = 0; it < 8; ++it) {
        int flat = it * 256 + tid;
        int row  = flat & 63;
        int kq   = flat >> 6;
        int r    = r0 + row;
        float4 v = make_float4(0.f, 0.f, 0.f, 0.f);
        if (r < N) v = *reinterpret_cast<const float4*>(&xh[(size_t)r * 128 + kq * 4]);
        float4 a4 = *reinterpret_cast<const float4*>(&aff[kq * 4]);
        float4 c4 = *reinterpret_cast<const float4*>(&aff[128 + kq * 4]);
        float y0 = fmaf(a4.x, v.x, c4.x);
        float y1 = fmaf(a4.y, v.y, c4.y);
        float y2 = fmaf(a4.z, v.z, c4.z);
        float y3 = fmaf(a4.w, v.w, c4.w);
        y0 = (y0 >= 0.f) ? y0 : LEAKY * y0;
        y1 = (y1 >= 0.f) ? y1 : LEAKY * y1;
        y2 = (y2 >= 0.f) ? y2 : LEAKY * y2;
        y3 = (y3 >= 0.f) ? y3 : LEAKY * y3;
        xs[kq*4+0][row] = y0; xs[kq*4+1][row] = y1;
        xs[kq*4+2][row] = y2; xs[kq*4+3][row] = y3;
    }

    const int tx = tid & 15;
    const int ty = tid >> 4;
    float acc[4][8] = {};

    for (int kb = 0; kb < 128; kb += 64) {
        __syncthreads();
        #pragma unroll
        for (int it = 0; it < 8; ++it) {
            int flat = it * 256 + tid;
            int j    = flat & 127;
            int kq   = flat >> 7;
            float4 w = *reinterpret_cast<const float4*>(&W[(size_t)j * 128 + kb + kq * 4]);
            Wt[kq*4+0][j] = w.x; Wt[kq*4+1][j] = w.y;
            Wt[kq*4+2][j] = w.z; Wt[kq*4+3][j] = w.w;
        }
        __syncthreads();
        #pragma unroll 8
        for (int kk = 0; kk < 64; ++kk) {
            float4 xv = *reinterpret_cast<const float4*>(&xs[kb + kk][ty * 4]);
            float4 w0 = *reinterpret_cast<const float4*>(&Wt[kk][tx * 8]);
            float4 w1 = *reinterpret_cast<const float4*>(&Wt[kk][tx * 8 + 4]);
            float xr[4] = {xv.x, xv.y, xv.z, xv.w};
            float wr[8] = {w0.x, w0.y, w0.z, w0.w, w1.x, w1.y, w1.z, w1.w};
            #pragma unroll
            for (int a = 0; a < 4; ++a)
                #pragma unroll
                for (int b = 0; b < 8; ++b)
                    acc[a][b] = fmaf(xr[a], wr[b], acc[a][b]);
        }
    }

    #pragma unroll
    for (int a = 0; a < 4; ++a) {
        int r = r0 + ty * 4 + a;
        if (r < N) {
            float4 o0 = make_float4(acc[a][0], acc[a][1], acc[a][2], acc[a][3]);
            float4 o1 = make_float4(acc[a][4], acc[a][5], acc[a][6], acc[a][7]);
            *reinterpret_cast<float4*>(&xh[(size_t)r * 128 + tx * 8])     = o0;
            *reinterpret_cast<float4*>(&xh[(size_t)r * 128 + tx * 8 + 4]) = o1;
        }
    }
}

// ---------------------------------------------------------------------------
// Gather aggregation (one wave per node, lane = 2 features) + bias + log_softmax.
__global__ __launch_bounds__(256) void k_agg(const float* __restrict__ h,
                                             const int* __restrict__ csr,
                                             const int* __restrict__ offs,
                                             const int* __restrict__ cnt,
                                             const float* __restrict__ dinv,
                                             const float* __restrict__ bg,
                                             float* __restrict__ out, int N)
{
    const int wid  = (blockIdx.x * blockDim.x + threadIdx.x) >> 6;
    const int lane = threadIdx.x & 63;
    if (wid >= N) return;
    const int i = wid;

    const float d0   = dinv[i];
    const float self = d0 * d0;
    float2 hv = *reinterpret_cast<const float2*>(&h[(size_t)i * 128 + lane * 2]);
    float a0 = self * hv.x;
    float a1 = self * hv.y;

    const int start = offs[i];
    const int m     = cnt[i];
    for (int j = 0; j < m; ++j) {
        int   s  = csr[start + j];
        float nv = dinv[s] * d0;
        float2 v = *reinterpret_cast<const float2*>(&h[(size_t)s * 128 + lane * 2]);
        a0 = fmaf(nv, v.x, a0);
        a1 = fmaf(nv, v.y, a1);
    }

    float v0 = a0 + bg[lane * 2];
    float v1 = a1 + bg[lane * 2 + 1];

    float mx = fmaxf(v0, v1);
    #pragma unroll
    for (int o = 32; o > 0; o >>= 1) mx = fmaxf(mx, __shfl_xor(mx, o));
    float sum = __expf(v0 - mx) + __expf(v1 - mx);
    #pragma unroll
    for (int o = 32; o > 0; o >>= 1) sum += __shfl_xor(sum, o);
    float ls = __logf(sum);

    *reinterpret_cast<float2*>(&out[(size_t)i * 128 + lane * 2]) =
        make_float2(v0 - mx - ls, v1 - mx - ls);
}

// ---------------------------------------------------------------------------
extern "C" void kernel_launch(void* const* d_in, const int* in_sizes, int n_in,
                              void* d_out, int out_size, void* d_ws, size_t ws_size,
                              hipStream_t stream)
{
    (void)n_in; (void)out_size; (void)ws_size;
    const float* fea   = (const float*)d_in[0];
    const void*  edges = d_in[1];
    const float* Wlin  = (const float*)d_in[2];
    const float* blin  = (const float*)d_in[3];
    const float* gamma = (const float*)d_in[4];
    const float* beta  = (const float*)d_in[5];
    const float* Wg    = (const float*)d_in[6];
    const float* bg    = (const float*)d_in[7];
    float* out = (float*)d_out;

    const int N = in_sizes[0] / 128;
    const int E = in_sizes[1] / 2;

    char* p = (char*)d_ws;
    float* xh   = (float*)p;  p += (size_t)N * 128 * 4;
    float* sums = (float*)p;  p += 256 * 4;        // sums[0:128], sumsq[128:256]
    int*   cnt  = (int*)p;    p += (size_t)N * 4;
    int*   cur  = (int*)p;    p += (size_t)N * 4;
    float* aff  = (float*)p;  p += 256 * 4;        // a[0:128], b[128:256]
    int*   offs = (int*)p;    p += (size_t)N * 4;
    float* dinv = (float*)p;  p += (size_t)N * 4;
    int*   csr  = (int*)p;    p += (size_t)E * 4;
    int*   flag = (int*)p;

    // zero: sums+sumsq, cnt, cur (contiguous)
    hipMemsetAsync(sums, 0, (256 + 2 * (size_t)N) * 4, stream);

    k_probe<<<1, 64, 0, stream>>>((const int*)edges, flag);
    k_lin<<<(N + 63) / 64, 256, 0, stream>>>(fea, Wlin, blin, xh, N);
    k_stats<<<512, 256, 0, stream>>>(xh, N, sums);
    k_bnfinal<<<1, 128, 0, stream>>>(sums, gamma, beta, 1.0f / (float)N, aff);
    k_deg<<<1024, 256, 0, stream>>>(edges, E, flag, cnt);
    k_dinv<<<(N + 255) / 256, 256, 0, stream>>>(cnt, dinv, N);
    k_scan<<<1, 1024, 0, stream>>>(cnt, offs, N);
    k_scatter<<<1024, 256, 0, stream>>>(edges, E, flag, offs, cur, csr);
    k_h<<<(N + 63) / 64, 256, 0, stream>>>(xh, Wg, aff, N);
    k_agg<<<(N + 3) / 4, 256, 0, stream>>>(xh, csr, offs, cnt, dinv, bg, out, N);
}

// Round 3
// 626.736 us; speedup vs baseline: 1.5142x; 1.5142x over previous
//
#include <hip/hip_runtime.h>
#include <math.h>

#define LEAKY 0.01f
#define BN_EPS 1e-5f

typedef unsigned int uint;
typedef float f32x2 __attribute__((ext_vector_type(2)));

__device__ __forceinline__ float bflo(uint v) { return __uint_as_float(v << 16); }
__device__ __forceinline__ float bfhi(uint v) { return __uint_as_float(v & 0xffff0000u); }
__device__ __forceinline__ uint packbf(float a, float b) {
    uint ua = __float_as_uint(a), ub = __float_as_uint(b);
    ua += 0x7fffu + ((ua >> 16) & 1u);
    ub += 0x7fffu + ((ub >> 16) & 1u);
    return (ua >> 16) | (ub & 0xffff0000u);
}

// ---------------------------------------------------------------------------
// Probe: are edges int64 (odd 32-bit words all zero) or int32?
__global__ void k_probe(const int* __restrict__ raw, int* __restrict__ flag)
{
    if (threadIdx.x == 0) {
        int f = 1;
        for (int i = 1; i < 128; i += 2)
            if (raw[i] != 0) { f = 0; break; }
        *flag = f;   // 1 => int64 layout, 0 => int32
    }
}

// ---------------------------------------------------------------------------
// GEMM1: x = fea @ Wlin^T + blin -> bf16 xb.  64 rows/block, 256 threads.
__global__ __launch_bounds__(256) void k_lin(const float* __restrict__ fea,
                                             const float* __restrict__ W,
                                             const float* __restrict__ bias,
                                             uint* __restrict__ xb, int N)
{
    __shared__ float xs[128][64];
    __shared__ float Wt[64][128];
    const int tid = threadIdx.x;
    const int r0  = blockIdx.x * 64;

    #pragma unroll
    for (int it = 0; it < 8; ++it) {
        int flat = it * 256 + tid;
        int row  = flat & 63;
        int kq   = flat >> 6;                 // 0..31
        int r    = r0 + row;
        float4 v = make_float4(0.f, 0.f, 0.f, 0.f);
        if (r < N) v = *reinterpret_cast<const float4*>(&fea[(size_t)r * 128 + kq * 4]);
        xs[kq*4+0][row] = v.x; xs[kq*4+1][row] = v.y;
        xs[kq*4+2][row] = v.z; xs[kq*4+3][row] = v.w;
    }

    const int tx = tid & 15;
    const int ty = tid >> 4;
    float acc[4][8] = {};

    for (int kb = 0; kb < 128; kb += 64) {
        __syncthreads();
        #pragma unroll
        for (int it = 0; it < 8; ++it) {
            int flat = it * 256 + tid;
            int j    = flat & 127;
            int kq   = flat >> 7;             // 0..15
            float4 w = *reinterpret_cast<const float4*>(&W[(size_t)j * 128 + kb + kq * 4]);
            Wt[kq*4+0][j] = w.x; Wt[kq*4+1][j] = w.y;
            Wt[kq*4+2][j] = w.z; Wt[kq*4+3][j] = w.w;
        }
        __syncthreads();
        #pragma unroll 8
        for (int kk = 0; kk < 64; ++kk) {
            float4 xv = *reinterpret_cast<const float4*>(&xs[kb + kk][ty * 4]);
            float4 w0 = *reinterpret_cast<const float4*>(&Wt[kk][tx * 8]);
            float4 w1 = *reinterpret_cast<const float4*>(&Wt[kk][tx * 8 + 4]);
            float xr[4] = {xv.x, xv.y, xv.z, xv.w};
            float wr[8] = {w0.x, w0.y, w0.z, w0.w, w1.x, w1.y, w1.z, w1.w};
            #pragma unroll
            for (int a = 0; a < 4; ++a)
                #pragma unroll
                for (int b = 0; b < 8; ++b)
                    acc[a][b] = fmaf(xr[a], wr[b], acc[a][b]);
        }
    }

    float4 b0 = *reinterpret_cast<const float4*>(&bias[tx * 8]);
    float4 b1 = *reinterpret_cast<const float4*>(&bias[tx * 8 + 4]);
    #pragma unroll
    for (int a = 0; a < 4; ++a) {
        int r = r0 + ty * 4 + a;
        if (r < N) {
            uint4 o;
            o.x = packbf(acc[a][0] + b0.x, acc[a][1] + b0.y);
            o.y = packbf(acc[a][2] + b0.z, acc[a][3] + b0.w);
            o.z = packbf(acc[a][4] + b1.x, acc[a][5] + b1.y);
            o.w = packbf(acc[a][6] + b1.z, acc[a][7] + b1.w);
            *reinterpret_cast<uint4*>(&xb[(size_t)r * 64 + tx * 4]) = o;
        }
    }
}

// ---------------------------------------------------------------------------
// BN batch stats from bf16 x.
__global__ __launch_bounds__(256) void k_stats(const uint* __restrict__ xb, int N,
                                               float* __restrict__ sums)
{
    const int c  = threadIdx.x & 63;          // uint column (2 features)
    const int rq = threadIdx.x >> 6;          // 0..3
    float s0 = 0.f, s1 = 0.f, q0 = 0.f, q1 = 0.f;
    for (int r = blockIdx.x * 4 + rq; r < N; r += gridDim.x * 4) {
        uint v = xb[(size_t)r * 64 + c];
        float f0 = bflo(v), f1 = bfhi(v);
        s0 += f0; s1 += f1; q0 += f0 * f0; q1 += f1 * f1;
    }
    __shared__ float rs0[256], rs1[256], rq0[256], rq1[256];
    rs0[threadIdx.x] = s0; rs1[threadIdx.x] = s1;
    rq0[threadIdx.x] = q0; rq1[threadIdx.x] = q1;
    __syncthreads();
    if (threadIdx.x < 64) {
        int t = threadIdx.x;
        float S0 = rs0[t] + rs0[t+64] + rs0[t+128] + rs0[t+192];
        float S1 = rs1[t] + rs1[t+64] + rs1[t+128] + rs1[t+192];
        float Q0 = rq0[t] + rq0[t+64] + rq0[t+128] + rq0[t+192];
        float Q1 = rq1[t] + rq1[t+64] + rq1[t+128] + rq1[t+192];
        atomicAdd(&sums[2*t],       S0);
        atomicAdd(&sums[2*t+1],     S1);
        atomicAdd(&sums[128+2*t],   Q0);
        atomicAdd(&sums[128+2*t+1], Q1);
    }
}

__global__ void k_bnfinal(const float* __restrict__ sums,
                          const float* __restrict__ gamma,
                          const float* __restrict__ beta,
                          float invN, float* __restrict__ aff)
{
    int c = threadIdx.x;
    if (c < 128) {
        float mean = sums[c] * invN;
        float var  = sums[128 + c] * invN - mean * mean;
        float coef = gamma[c] * rsqrtf(var + BN_EPS);
        aff[c]       = coef;
        aff[128 + c] = beta[c] - coef * mean;
    }
}

// ---------------------------------------------------------------------------
// Degree histogram over dst (excluding self-loop; +1 applied later).
__global__ void k_deg(const void* __restrict__ edges, int E,
                      const int* __restrict__ flag, int* __restrict__ cnt)
{
    const int isI64 = *flag;
    const long long* e64 = (const long long*)edges;
    const int*       e32 = (const int*)edges;
    for (int e = blockIdx.x * blockDim.x + threadIdx.x; e < E;
         e += gridDim.x * blockDim.x) {
        int dst = isI64 ? (int)e64[(size_t)E + e] : e32[(size_t)E + e];
        atomicAdd(&cnt[dst], 1);
    }
}

// ---------------------------------------------------------------------------
// Parallel exclusive scan of cnt -> offs (3 kernels), dinv fused in pass 3.
__global__ __launch_bounds__(256) void k_scan1(const int* __restrict__ cnt,
                                               int* __restrict__ bsum, int N)
{
    int idx = blockIdx.x * 256 + threadIdx.x;
    int v = (idx < N) ? cnt[idx] : 0;
    __shared__ int sd[256];
    sd[threadIdx.x] = v;
    __syncthreads();
    for (int o = 128; o > 0; o >>= 1) {
        if (threadIdx.x < o) sd[threadIdx.x] += sd[threadIdx.x + o];
        __syncthreads();
    }
    if (threadIdx.x == 0) bsum[blockIdx.x] = sd[0];
}

__global__ __launch_bounds__(512) void k_scan2(const int* __restrict__ bsum,
                                               int* __restrict__ bpre, int NB)
{
    __shared__ int sd[512];
    int t = threadIdx.x;
    int v = (t < NB) ? bsum[t] : 0;
    sd[t] = v;
    __syncthreads();
    for (int o = 1; o < 512; o <<= 1) {
        int u = (t >= o) ? sd[t - o] : 0;
        __syncthreads();
        sd[t] += u;
        __syncthreads();
    }
    if (t < NB) bpre[t] = sd[t] - v;          // exclusive
}

__global__ __launch_bounds__(256) void k_scan3(const int* __restrict__ cnt,
                                               const int* __restrict__ bpre,
                                               int* __restrict__ offs,
                                               float* __restrict__ dinv, int N)
{
    int idx = blockIdx.x * 256 + threadIdx.x;
    int t = threadIdx.x;
    int v = (idx < N) ? cnt[idx] : 0;
    __shared__ int sd[256];
    sd[t] = v;
    __syncthreads();
    for (int o = 1; o < 256; o <<= 1) {
        int u = (t >= o) ? sd[t - o] : 0;
        __syncthreads();
        sd[t] += u;
        __syncthreads();
    }
    if (idx < N) {
        offs[idx] = bpre[blockIdx.x] + sd[t] - v;
        dinv[idx] = rsqrtf((float)(v + 1));
    }
}

// Scatter edges into CSR (src list grouped by dst).
__global__ void k_scatter(const void* __restrict__ edges, int E,
                          const int* __restrict__ flag,
                          const int* __restrict__ offs,
                          int* __restrict__ cur, int* __restrict__ csr)
{
    const int isI64 = *flag;
    const long long* e64 = (const long long*)edges;
    const int*       e32 = (const int*)edges;
    for (int e = blockIdx.x * blockDim.x + threadIdx.x; e < E;
         e += gridDim.x * blockDim.x) {
        int src, dst;
        if (isI64) { src = (int)e64[e]; dst = (int)e64[(size_t)E + e]; }
        else       { src = e32[e];      dst = e32[(size_t)E + e]; }
        int pos = atomicAdd(&cur[dst], 1);
        csr[offs[dst] + pos] = src;
    }
}

// ---------------------------------------------------------------------------
// GEMM2: h = leakyrelu(a*x + b) @ Wg^T, BN affine fused in staging.
// Reads bf16 xb, writes bf16 hb.
__global__ __launch_bounds__(256) void k_h(const uint* __restrict__ xb,
                                           const float* __restrict__ W,
                                           const float* __restrict__ aff,
                                           uint* __restrict__ hb, int N)
{
    __shared__ float xs[128][64];
    __shared__ float Wt[64][128];
    const int tid = threadIdx.x;
    const int r0  = blockIdx.x * 64;

    #pragma unroll
    for (int it = 0; it < 16; ++it) {
        int flat = it * 256 + tid;            // 0..4095 = 64 rows x 64 uints
        int row  = flat & 63;
        int u    = flat >> 6;                 // 0..63 (column pair)
        int r    = r0 + row;
        uint v   = (r < N) ? xb[(size_t)r * 64 + u] : 0u;
        float f0 = bflo(v), f1 = bfhi(v);
        float a0 = aff[2*u],       a1 = aff[2*u+1];
        float c0 = aff[128 + 2*u], c1 = aff[128 + 2*u+1];
        float y0 = fmaf(a0, f0, c0);
        float y1 = fmaf(a1, f1, c1);
        y0 = (y0 >= 0.f) ? y0 : LEAKY * y0;
        y1 = (y1 >= 0.f) ? y1 : LEAKY * y1;
        xs[2*u][row]   = y0;
        xs[2*u+1][row] = y1;
    }

    const int tx = tid & 15;
    const int ty = tid >> 4;
    float acc[4][8] = {};

    for (int kb = 0; kb < 128; kb += 64) {
        __syncthreads();
        #pragma unroll
        for (int it = 0; it < 8; ++it) {
            int flat = it * 256 + tid;
            int j    = flat & 127;
            int kq   = flat >> 7;
            float4 w = *reinterpret_cast<const float4*>(&W[(size_t)j * 128 + kb + kq * 4]);
            Wt[kq*4+0][j] = w.x; Wt[kq*4+1][j] = w.y;
            Wt[kq*4+2][j] = w.z; Wt[kq*4+3][j] = w.w;
        }
        __syncthreads();
        #pragma unroll 8
        for (int kk = 0; kk < 64; ++kk) {
            float4 xv = *reinterpret_cast<const float4*>(&xs[kb + kk][ty * 4]);
            float4 w0 = *reinterpret_cast<const float4*>(&Wt[kk][tx * 8]);
            float4 w1 = *reinterpret_cast<const float4*>(&Wt[kk][tx * 8 + 4]);
            float xr[4] = {xv.x, xv.y, xv.z, xv.w};
            float wr[8] = {w0.x, w0.y, w0.z, w0.w, w1.x, w1.y, w1.z, w1.w};
            #pragma unroll
            for (int a = 0; a < 4; ++a)
                #pragma unroll
                for (int b = 0; b < 8; ++b)
                    acc[a][b] = fmaf(xr[a], wr[b], acc[a][b]);
        }
    }

    #pragma unroll
    for (int a = 0; a < 4; ++a) {
        int r = r0 + ty * 4 + a;
        if (r < N) {
            uint4 o;
            o.x = packbf(acc[a][0], acc[a][1]);
            o.y = packbf(acc[a][2], acc[a][3]);
            o.z = packbf(acc[a][4], acc[a][5]);
            o.w = packbf(acc[a][6], acc[a][7]);
            *reinterpret_cast<uint4*>(&hb[(size_t)r * 64 + tx * 4]) = o;
        }
    }
}

// ---------------------------------------------------------------------------
// Gather aggregation: one wave per node, lane = 1 uint (2 bf16 features).
// Lane-batched csr/dinv loads, x8 unrolled independent row gathers.
__global__ __launch_bounds__(256) void k_agg(const uint* __restrict__ hb,
                                             const int* __restrict__ csr,
                                             const int* __restrict__ offs,
                                             const int* __restrict__ cnt,
                                             const float* __restrict__ dinv,
                                             const float* __restrict__ bg,
                                             float* __restrict__ out, int N)
{
    const int wid  = (blockIdx.x * blockDim.x + threadIdx.x) >> 6;
    const int lane = threadIdx.x & 63;
    if (wid >= N) return;
    const int i = wid;

    const float d0 = dinv[i];
    uint hv = hb[(size_t)i * 64 + lane];
    const float self = d0 * d0;
    float a0 = self * bflo(hv);
    float a1 = self * bfhi(hv);

    const int start = offs[i];
    const int m     = cnt[i];

    for (int base = 0; base < m; base += 64) {
        const int nb = min(64, m - base);
        int   sj = (lane < nb) ? csr[start + base + lane] : 0;
        float dj = (lane < nb) ? dinv[sj] : 0.f;

        int j = 0;
        for (; j + 7 < nb; j += 8) {
            #pragma unroll
            for (int q = 0; q < 8; ++q) {
                int   s  = __shfl(sj, j + q);
                float nv = __shfl(dj, j + q) * d0;
                uint  v  = hb[(size_t)s * 64 + lane];
                a0 = fmaf(nv, bflo(v), a0);
                a1 = fmaf(nv, bfhi(v), a1);
            }
        }
        for (; j < nb; ++j) {
            int   s  = __shfl(sj, j);
            float nv = __shfl(dj, j) * d0;
            uint  v  = hb[(size_t)s * 64 + lane];
            a0 = fmaf(nv, bflo(v), a0);
            a1 = fmaf(nv, bfhi(v), a1);
        }
    }

    float2 b2 = *reinterpret_cast<const float2*>(&bg[lane * 2]);
    float v0 = a0 + b2.x;
    float v1 = a1 + b2.y;

    float mx = fmaxf(v0, v1);
    #pragma unroll
    for (int o = 32; o > 0; o >>= 1) mx = fmaxf(mx, __shfl_xor(mx, o));
    float sum = __expf(v0 - mx) + __expf(v1 - mx);
    #pragma unroll
    for (int o = 32; o > 0; o >>= 1) sum += __shfl_xor(sum, o);
    float ls = __logf(sum);

    f32x2 r;
    r.x = v0 - mx - ls;
    r.y = v1 - mx - ls;
    __builtin_nontemporal_store(r, reinterpret_cast<f32x2*>(&out[(size_t)i * 128 + lane * 2]));
}

// ---------------------------------------------------------------------------
extern "C" void kernel_launch(void* const* d_in, const int* in_sizes, int n_in,
                              void* d_out, int out_size, void* d_ws, size_t ws_size,
                              hipStream_t stream)
{
    (void)n_in; (void)out_size; (void)ws_size;
    const float* fea   = (const float*)d_in[0];
    const void*  edges = d_in[1];
    const float* Wlin  = (const float*)d_in[2];
    const float* blin  = (const float*)d_in[3];
    const float* gamma = (const float*)d_in[4];
    const float* beta  = (const float*)d_in[5];
    const float* Wg    = (const float*)d_in[6];
    const float* bg    = (const float*)d_in[7];
    float* out = (float*)d_out;

    const int N = in_sizes[0] / 128;
    const int E = in_sizes[1] / 2;
    const int NB = (N + 255) / 256;           // scan blocks (<=512 required)

    char* p = (char*)d_ws;
    uint*  xb   = (uint*)p;   p += (size_t)N * 64 * 4;    // bf16 x, packed pairs
    uint*  hb   = (uint*)p;   p += (size_t)N * 64 * 4;    // bf16 h, packed pairs
    int*   csr  = (int*)p;    p += (size_t)E * 4;
    float* sums = (float*)p;  p += 256 * 4;               // zeroed ↓
    int*   cnt  = (int*)p;    p += (size_t)N * 4;         // zeroed ↓
    int*   cur  = (int*)p;    p += (size_t)N * 4;         // zeroed ↓
    int*   offs = (int*)p;    p += (size_t)N * 4;
    float* dinv = (float*)p;  p += (size_t)N * 4;
    float* aff  = (float*)p;  p += 256 * 4;
    int*   bsum = (int*)p;    p += 512 * 4;
    int*   bpre = (int*)p;    p += 512 * 4;
    int*   flag = (int*)p;

    // zero sums + cnt + cur (contiguous)
    (void)hipMemsetAsync(sums, 0, 256 * 4 + 2 * (size_t)N * 4, stream);

    k_probe<<<1, 64, 0, stream>>>((const int*)edges, flag);
    k_lin<<<(N + 63) / 64, 256, 0, stream>>>(fea, Wlin, blin, xb, N);
    k_stats<<<512, 256, 0, stream>>>(xb, N, sums);
    k_bnfinal<<<1, 128, 0, stream>>>(sums, gamma, beta, 1.0f / (float)N, aff);
    k_deg<<<1024, 256, 0, stream>>>(edges, E, flag, cnt);
    k_scan1<<<NB, 256, 0, stream>>>(cnt, bsum, N);
    k_scan2<<<1, 512, 0, stream>>>(bsum, bpre, NB);
    k_scan3<<<NB, 256, 0, stream>>>(cnt, bpre, offs, dinv, N);
    k_scatter<<<1024, 256, 0, stream>>>(edges, E, flag, offs, cur, csr);
    k_h<<<(N + 63) / 64, 256, 0, stream>>>(xb, Wg, aff, hb, N);
    k_agg<<<(N + 3) / 4, 256, 0, stream>>>(hb, csr, offs, cnt, dinv, bg, out, N);
}

// Round 4
// 390.609 us; speedup vs baseline: 2.4296x; 1.6045x over previous
//
#include <hip/hip_runtime.h>
#include <math.h>

#define LEAKY 0.01f
#define BN_EPS 1e-5f
#define NBLK 512          // partition blocks (fixed; histm row length)

typedef unsigned int uint;
typedef float f32x2 __attribute__((ext_vector_type(2)));

__device__ __forceinline__ float bflo(uint v) { return __uint_as_float(v << 16); }
__device__ __forceinline__ float bfhi(uint v) { return __uint_as_float(v & 0xffff0000u); }
__device__ __forceinline__ uint packbf(float a, float b) {
    uint ua = __float_as_uint(a), ub = __float_as_uint(b);
    ua += 0x7fffu + ((ua >> 16) & 1u);
    ub += 0x7fffu + ((ub >> 16) & 1u);
    return (ua >> 16) | (ub & 0xffff0000u);
}

// ---------------------------------------------------------------------------
// Probe: are edges int64 (odd 32-bit words all zero) or int32?
__global__ void k_probe(const int* __restrict__ raw, int* __restrict__ flag)
{
    if (threadIdx.x == 0) {
        int f = 1;
        for (int i = 1; i < 128; i += 2)
            if (raw[i] != 0) { f = 0; break; }
        *flag = f;   // 1 => int64 layout, 0 => int32
    }
}

// ---------------------------------------------------------------------------
// Partition pass A: per-block LDS histogram of dst>>8 over a contiguous
// edge range -> histm[bucket*NBLK + block].
__global__ __launch_bounds__(256) void k_bhist(const void* __restrict__ edges, int E,
                                               const int* __restrict__ flag,
                                               int* __restrict__ histm, int NBUK)
{
    __shared__ int hh[512];
    for (int b = threadIdx.x; b < 512; b += 256) hh[b] = 0;
    __syncthreads();

    const int isI64 = *flag;
    const long long* e64 = (const long long*)edges;
    const int*       e32 = (const int*)edges;
    const int chunk = (E + NBLK - 1) / NBLK;
    const int lo = blockIdx.x * chunk;
    const int hi = min(lo + chunk, E);
    for (int e = lo + threadIdx.x; e < hi; e += 256) {
        int dst = isI64 ? (int)e64[(size_t)E + e] : e32[(size_t)E + e];
        atomicAdd(&hh[dst >> 8], 1);
    }
    __syncthreads();
    for (int b = threadIdx.x; b < NBUK; b += 256)
        histm[(size_t)b * NBLK + blockIdx.x] = hh[b];
}

// Pass A2: per-bucket exclusive scan across blocks; emit bucket totals.
__global__ __launch_bounds__(512) void k_bscan(int* __restrict__ histm,
                                               int* __restrict__ btot)
{
    __shared__ int sd[512];
    const int bkt = blockIdx.x;
    const int t = threadIdx.x;
    int v = histm[(size_t)bkt * NBLK + t];
    sd[t] = v;
    __syncthreads();
    for (int o = 1; o < 512; o <<= 1) {
        int u = (t >= o) ? sd[t - o] : 0;
        __syncthreads();
        sd[t] += u;
        __syncthreads();
    }
    histm[(size_t)bkt * NBLK + t] = sd[t] - v;     // exclusive within bucket
    if (t == 511) btot[bkt] = sd[511];
}

// Pass A3: exclusive scan of bucket totals -> bucket bases.
__global__ __launch_bounds__(512) void k_btotscan(const int* __restrict__ btot,
                                                  int* __restrict__ bbase, int NBUK)
{
    __shared__ int sd[512];
    const int t = threadIdx.x;
    int v = (t < NBUK) ? btot[t] : 0;
    sd[t] = v;
    __syncthreads();
    for (int o = 1; o < 512; o <<= 1) {
        int u = (t >= o) ? sd[t - o] : 0;
        __syncthreads();
        sd[t] += u;
        __syncthreads();
    }
    if (t < NBUK) bbase[t] = sd[t] - v;
}

// Pass B: scatter (src,dst) into dst-bucketed bins at deterministic chunks.
__global__ __launch_bounds__(256) void k_binscatter(const void* __restrict__ edges, int E,
                                                    const int* __restrict__ flag,
                                                    const int* __restrict__ histm,
                                                    const int* __restrict__ bbase,
                                                    uint2* __restrict__ bins, int NBUK)
{
    __shared__ int cur[512];
    for (int b = threadIdx.x; b < NBUK; b += 256)
        cur[b] = bbase[b] + histm[(size_t)b * NBLK + blockIdx.x];
    __syncthreads();

    const int isI64 = *flag;
    const long long* e64 = (const long long*)edges;
    const int*       e32 = (const int*)edges;
    const int chunk = (E + NBLK - 1) / NBLK;
    const int lo = blockIdx.x * chunk;
    const int hi = min(lo + chunk, E);
    for (int e = lo + threadIdx.x; e < hi; e += 256) {
        int src, dst;
        if (isI64) { src = (int)e64[e]; dst = (int)e64[(size_t)E + e]; }
        else       { src = e32[e];      dst = e32[(size_t)E + e]; }
        int pos = atomicAdd(&cur[dst >> 8], 1);
        bins[pos] = make_uint2((uint)src, (uint)dst);
    }
}

// Per-bucket degree histogram from bins -> cnt (replaces global-atomic k_deg).
__global__ __launch_bounds__(256) void k_degdinv(const uint2* __restrict__ bins,
                                                 const int* __restrict__ bbase,
                                                 const int* __restrict__ btot,
                                                 int* __restrict__ cnt, int N)
{
    __shared__ int c[256];
    const int bkt = blockIdx.x;
    c[threadIdx.x] = 0;
    __syncthreads();
    const int lo = bbase[bkt];
    const int hi = lo + btot[bkt];
    for (int i = lo + threadIdx.x; i < hi; i += 256) {
        uint2 e = bins[i];
        atomicAdd(&c[e.y & 255u], 1);
    }
    __syncthreads();
    int node = (bkt << 8) + threadIdx.x;
    if (node < N) cnt[node] = c[threadIdx.x];
}

// ---------------------------------------------------------------------------
// Parallel exclusive scan of cnt -> offs (3 kernels), dinv fused in pass 3.
__global__ __launch_bounds__(256) void k_scan1(const int* __restrict__ cnt,
                                               int* __restrict__ bsum, int N)
{
    int idx = blockIdx.x * 256 + threadIdx.x;
    int v = (idx < N) ? cnt[idx] : 0;
    __shared__ int sd[256];
    sd[threadIdx.x] = v;
    __syncthreads();
    for (int o = 128; o > 0; o >>= 1) {
        if (threadIdx.x < o) sd[threadIdx.x] += sd[threadIdx.x + o];
        __syncthreads();
    }
    if (threadIdx.x == 0) bsum[blockIdx.x] = sd[0];
}

__global__ __launch_bounds__(512) void k_scan2(const int* __restrict__ bsum,
                                               int* __restrict__ bpre, int NB)
{
    __shared__ int sd[512];
    int t = threadIdx.x;
    int v = (t < NB) ? bsum[t] : 0;
    sd[t] = v;
    __syncthreads();
    for (int o = 1; o < 512; o <<= 1) {
        int u = (t >= o) ? sd[t - o] : 0;
        __syncthreads();
        sd[t] += u;
        __syncthreads();
    }
    if (t < NB) bpre[t] = sd[t] - v;          // exclusive
}

__global__ __launch_bounds__(256) void k_scan3(const int* __restrict__ cnt,
                                               const int* __restrict__ bpre,
                                               int* __restrict__ offs,
                                               float* __restrict__ dinv, int N)
{
    int idx = blockIdx.x * 256 + threadIdx.x;
    int t = threadIdx.x;
    int v = (idx < N) ? cnt[idx] : 0;
    __shared__ int sd[256];
    sd[t] = v;
    __syncthreads();
    for (int o = 1; o < 256; o <<= 1) {
        int u = (t >= o) ? sd[t - o] : 0;
        __syncthreads();
        sd[t] += u;
        __syncthreads();
    }
    if (idx < N) {
        offs[idx] = bpre[blockIdx.x] + sd[t] - v;
        dinv[idx] = rsqrtf((float)(v + 1));
    }
}

// Pass C: per-bucket CSR scatter; writes confined to the bucket's csr window.
__global__ __launch_bounds__(256) void k_csrbuild(const uint2* __restrict__ bins,
                                                  const int* __restrict__ bbase,
                                                  const int* __restrict__ btot,
                                                  const int* __restrict__ offs,
                                                  int* __restrict__ csr, int N)
{
    __shared__ int cur[256];
    const int bkt = blockIdx.x;
    int node = (bkt << 8) + threadIdx.x;
    cur[threadIdx.x] = (node < N) ? offs[node] : 0;
    __syncthreads();
    const int lo = bbase[bkt];
    const int hi = lo + btot[bkt];
    for (int i = lo + threadIdx.x; i < hi; i += 256) {
        uint2 e = bins[i];
        int pos = atomicAdd(&cur[e.y & 255u], 1);
        csr[pos] = (int)e.x;
    }
}

// ---------------------------------------------------------------------------
// GEMM1: x = fea @ Wlin^T + blin -> bf16 xb.  64 rows/block, 256 threads.
__global__ __launch_bounds__(256) void k_lin(const float* __restrict__ fea,
                                             const float* __restrict__ W,
                                             const float* __restrict__ bias,
                                             uint* __restrict__ xb, int N)
{
    __shared__ float xs[128][64];
    __shared__ float Wt[64][128];
    const int tid = threadIdx.x;
    const int r0  = blockIdx.x * 64;

    #pragma unroll
    for (int it = 0; it < 8; ++it) {
        int flat = it * 256 + tid;
        int row  = flat & 63;
        int kq   = flat >> 6;                 // 0..31
        int r    = r0 + row;
        float4 v = make_float4(0.f, 0.f, 0.f, 0.f);
        if (r < N) v = *reinterpret_cast<const float4*>(&fea[(size_t)r * 128 + kq * 4]);
        xs[kq*4+0][row] = v.x; xs[kq*4+1][row] = v.y;
        xs[kq*4+2][row] = v.z; xs[kq*4+3][row] = v.w;
    }

    const int tx = tid & 15;
    const int ty = tid >> 4;
    float acc[4][8] = {};

    for (int kb = 0; kb < 128; kb += 64) {
        __syncthreads();
        #pragma unroll
        for (int it = 0; it < 8; ++it) {
            int flat = it * 256 + tid;
            int j    = flat & 127;
            int kq   = flat >> 7;             // 0..15
            float4 w = *reinterpret_cast<const float4*>(&W[(size_t)j * 128 + kb + kq * 4]);
            Wt[kq*4+0][j] = w.x; Wt[kq*4+1][j] = w.y;
            Wt[kq*4+2][j] = w.z; Wt[kq*4+3][j] = w.w;
        }
        __syncthreads();
        #pragma unroll 8
        for (int kk = 0; kk < 64; ++kk) {
            float4 xv = *reinterpret_cast<const float4*>(&xs[kb + kk][ty * 4]);
            float4 w0 = *reinterpret_cast<const float4*>(&Wt[kk][tx * 8]);
            float4 w1 = *reinterpret_cast<const float4*>(&Wt[kk][tx * 8 + 4]);
            float xr[4] = {xv.x, xv.y, xv.z, xv.w};
            float wr[8] = {w0.x, w0.y, w0.z, w0.w, w1.x, w1.y, w1.z, w1.w};
            #pragma unroll
            for (int a = 0; a < 4; ++a)
                #pragma unroll
                for (int b = 0; b < 8; ++b)
                    acc[a][b] = fmaf(xr[a], wr[b], acc[a][b]);
        }
    }

    float4 b0 = *reinterpret_cast<const float4*>(&bias[tx * 8]);
    float4 b1 = *reinterpret_cast<const float4*>(&bias[tx * 8 + 4]);
    #pragma unroll
    for (int a = 0; a < 4; ++a) {
        int r = r0 + ty * 4 + a;
        if (r < N) {
            uint4 o;
            o.x = packbf(acc[a][0] + b0.x, acc[a][1] + b0.y);
            o.y = packbf(acc[a][2] + b0.z, acc[a][3] + b0.w);
            o.z = packbf(acc[a][4] + b1.x, acc[a][5] + b1.y);
            o.w = packbf(acc[a][6] + b1.z, acc[a][7] + b1.w);
            *reinterpret_cast<uint4*>(&xb[(size_t)r * 64 + tx * 4]) = o;
        }
    }
}

// ---------------------------------------------------------------------------
// BN batch stats from bf16 x.
__global__ __launch_bounds__(256) void k_stats(const uint* __restrict__ xb, int N,
                                               float* __restrict__ sums)
{
    const int c  = threadIdx.x & 63;          // uint column (2 features)
    const int rq = threadIdx.x >> 6;          // 0..3
    float s0 = 0.f, s1 = 0.f, q0 = 0.f, q1 = 0.f;
    for (int r = blockIdx.x * 4 + rq; r < N; r += gridDim.x * 4) {
        uint v = xb[(size_t)r * 64 + c];
        float f0 = bflo(v), f1 = bfhi(v);
        s0 += f0; s1 += f1; q0 += f0 * f0; q1 += f1 * f1;
    }
    __shared__ float rs0[256], rs1[256], rq0[256], rq1[256];
    rs0[threadIdx.x] = s0; rs1[threadIdx.x] = s1;
    rq0[threadIdx.x] = q0; rq1[threadIdx.x] = q1;
    __syncthreads();
    if (threadIdx.x < 64) {
        int t = threadIdx.x;
        float S0 = rs0[t] + rs0[t+64] + rs0[t+128] + rs0[t+192];
        float S1 = rs1[t] + rs1[t+64] + rs1[t+128] + rs1[t+192];
        float Q0 = rq0[t] + rq0[t+64] + rq0[t+128] + rq0[t+192];
        float Q1 = rq1[t] + rq1[t+64] + rq1[t+128] + rq1[t+192];
        atomicAdd(&sums[2*t],       S0);
        atomicAdd(&sums[2*t+1],     S1);
        atomicAdd(&sums[128+2*t],   Q0);
        atomicAdd(&sums[128+2*t+1], Q1);
    }
}

__global__ void k_bnfinal(const float* __restrict__ sums,
                          const float* __restrict__ gamma,
                          const float* __restrict__ beta,
                          float invN, float* __restrict__ aff)
{
    int c = threadIdx.x;
    if (c < 128) {
        float mean = sums[c] * invN;
        float var  = sums[128 + c] * invN - mean * mean;
        float coef = gamma[c] * rsqrtf(var + BN_EPS);
        aff[c]       = coef;
        aff[128 + c] = beta[c] - coef * mean;
    }
}

// ---------------------------------------------------------------------------
// GEMM2: h = leakyrelu(a*x + b) @ Wg^T, BN affine fused in staging.
__global__ __launch_bounds__(256) void k_h(const uint* __restrict__ xb,
                                           const float* __restrict__ W,
                                           const float* __restrict__ aff,
                                           uint* __restrict__ hb, int N)
{
    __shared__ float xs[128][64];
    __shared__ float Wt[64][128];
    const int tid = threadIdx.x;
    const int r0  = blockIdx.x * 64;

    #pragma unroll
    for (int it = 0; it < 16; ++it) {
        int flat = it * 256 + tid;            // 0..4095 = 64 rows x 64 uints
        int row  = flat & 63;
        int u    = flat >> 6;                 // 0..63 (column pair)
        int r    = r0 + row;
        uint v   = (r < N) ? xb[(size_t)r * 64 + u] : 0u;
        float f0 = bflo(v), f1 = bfhi(v);
        float a0 = aff[2*u],       a1 = aff[2*u+1];
        float c0 = aff[128 + 2*u], c1 = aff[128 + 2*u+1];
        float y0 = fmaf(a0, f0, c0);
        float y1 = fmaf(a1, f1, c1);
        y0 = (y0 >= 0.f) ? y0 : LEAKY * y0;
        y1 = (y1 >= 0.f) ? y1 : LEAKY * y1;
        xs[2*u][row]   = y0;
        xs[2*u+1][row] = y1;
    }

    const int tx = tid & 15;
    const int ty = tid >> 4;
    float acc[4][8] = {};

    for (int kb = 0; kb < 128; kb += 64) {
        __syncthreads();
        #pragma unroll
        for (int it = 0; it < 8; ++it) {
            int flat = it * 256 + tid;
            int j    = flat & 127;
            int kq   = flat >> 7;
            float4 w = *reinterpret_cast<const float4*>(&W[(size_t)j * 128 + kb + kq * 4]);
            Wt[kq*4+0][j] = w.x; Wt[kq*4+1][j] = w.y;
            Wt[kq*4+2][j] = w.z; Wt[kq*4+3][j] = w.w;
        }
        __syncthreads();
        #pragma unroll 8
        for (int kk = 0; kk < 64; ++kk) {
            float4 xv = *reinterpret_cast<const float4*>(&xs[kb + kk][ty * 4]);
            float4 w0 = *reinterpret_cast<const float4*>(&Wt[kk][tx * 8]);
            float4 w1 = *reinterpret_cast<const float4*>(&Wt[kk][tx * 8 + 4]);
            float xr[4] = {xv.x, xv.y, xv.z, xv.w};
            float wr[8] = {w0.x, w0.y, w0.z, w0.w, w1.x, w1.y, w1.z, w1.w};
            #pragma unroll
            for (int a = 0; a < 4; ++a)
                #pragma unroll
                for (int b = 0; b < 8; ++b)
                    acc[a][b] = fmaf(xr[a], wr[b], acc[a][b]);
        }
    }

    #pragma unroll
    for (int a = 0; a < 4; ++a) {
        int r = r0 + ty * 4 + a;
        if (r < N) {
            uint4 o;
            o.x = packbf(acc[a][0], acc[a][1]);
            o.y = packbf(acc[a][2], acc[a][3]);
            o.z = packbf(acc[a][4], acc[a][5]);
            o.w = packbf(acc[a][6], acc[a][7]);
            *reinterpret_cast<uint4*>(&hb[(size_t)r * 64 + tx * 4]) = o;
        }
    }
}

// ---------------------------------------------------------------------------
// Gather aggregation: one wave per node, lane = 1 uint (2 bf16 features).
__global__ __launch_bounds__(256) void k_agg(const uint* __restrict__ hb,
                                             const int* __restrict__ csr,
                                             const int* __restrict__ offs,
                                             const int* __restrict__ cnt,
                                             const float* __restrict__ dinv,
                                             const float* __restrict__ bg,
                                             float* __restrict__ out, int N)
{
    const int wid  = (blockIdx.x * blockDim.x + threadIdx.x) >> 6;
    const int lane = threadIdx.x & 63;
    if (wid >= N) return;
    const int i = wid;

    const float d0 = dinv[i];
    uint hv = hb[(size_t)i * 64 + lane];
    const float self = d0 * d0;
    float a0 = self * bflo(hv);
    float a1 = self * bfhi(hv);

    const int start = offs[i];
    const int m     = cnt[i];

    for (int base = 0; base < m; base += 64) {
        const int nb = min(64, m - base);
        int   sj = (lane < nb) ? csr[start + base + lane] : 0;
        float dj = (lane < nb) ? dinv[sj] : 0.f;

        int j = 0;
        for (; j + 7 < nb; j += 8) {
            #pragma unroll
            for (int q = 0; q < 8; ++q) {
                int   s  = __shfl(sj, j + q);
                float nv = __shfl(dj, j + q) * d0;
                uint  v  = hb[(size_t)s * 64 + lane];
                a0 = fmaf(nv, bflo(v), a0);
                a1 = fmaf(nv, bfhi(v), a1);
            }
        }
        for (; j < nb; ++j) {
            int   s  = __shfl(sj, j);
            float nv = __shfl(dj, j) * d0;
            uint  v  = hb[(size_t)s * 64 + lane];
            a0 = fmaf(nv, bflo(v), a0);
            a1 = fmaf(nv, bfhi(v), a1);
        }
    }

    float2 b2 = *reinterpret_cast<const float2*>(&bg[lane * 2]);
    float v0 = a0 + b2.x;
    float v1 = a1 + b2.y;

    float mx = fmaxf(v0, v1);
    #pragma unroll
    for (int o = 32; o > 0; o >>= 1) mx = fmaxf(mx, __shfl_xor(mx, o));
    float sum = __expf(v0 - mx) + __expf(v1 - mx);
    #pragma unroll
    for (int o = 32; o > 0; o >>= 1) sum += __shfl_xor(sum, o);
    float ls = __logf(sum);

    f32x2 r;
    r.x = v0 - mx - ls;
    r.y = v1 - mx - ls;
    __builtin_nontemporal_store(r, reinterpret_cast<f32x2*>(&out[(size_t)i * 128 + lane * 2]));
}

// ---------------------------------------------------------------------------
extern "C" void kernel_launch(void* const* d_in, const int* in_sizes, int n_in,
                              void* d_out, int out_size, void* d_ws, size_t ws_size,
                              hipStream_t stream)
{
    (void)n_in; (void)out_size; (void)ws_size;
    const float* fea   = (const float*)d_in[0];
    const void*  edges = d_in[1];
    const float* Wlin  = (const float*)d_in[2];
    const float* blin  = (const float*)d_in[3];
    const float* gamma = (const float*)d_in[4];
    const float* beta  = (const float*)d_in[5];
    const float* Wg    = (const float*)d_in[6];
    const float* bg    = (const float*)d_in[7];
    float* out = (float*)d_out;

    const int N    = in_sizes[0] / 128;
    const int E    = in_sizes[1] / 2;
    const int NB   = (N + 255) / 256;         // node-scan blocks (<=512)
    const int NBUK = (N + 255) >> 8;          // dst buckets (256 nodes each)

    char* p = (char*)d_ws;
    // bins (graph phase) aliases xb (GEMM phase): lifetimes are disjoint.
    size_t u0 = (size_t)N * 64 * 4;                      // xb bytes
    size_t u1 = (size_t)E * 8;                           // bins bytes
    uint*  xb   = (uint*)p;
    uint2* bins = (uint2*)p;   p += (u0 > u1 ? u0 : u1);
    uint*  hb   = (uint*)p;    p += (size_t)N * 64 * 4;
    int*   csr  = (int*)p;     p += (size_t)E * 4;
    int*   histm = (int*)p;    p += (size_t)NBUK * NBLK * 4;
    float* sums = (float*)p;   p += 256 * 4;             // zeroed below
    int*   cnt  = (int*)p;     p += (size_t)N * 4;
    int*   offs = (int*)p;     p += (size_t)N * 4;
    float* dinv = (float*)p;   p += (size_t)N * 4;
    float* aff  = (float*)p;   p += 256 * 4;
    int*   bsum = (int*)p;     p += 512 * 4;
    int*   bpre = (int*)p;     p += 512 * 4;
    int*   btot = (int*)p;     p += 512 * 4;
    int*   bbase = (int*)p;    p += 512 * 4;
    int*   flag = (int*)p;

    (void)hipMemsetAsync(sums, 0, 256 * 4, stream);

    // --- graph build (edges only; bins buffer free before GEMMs need xb) ---
    k_probe<<<1, 64, 0, stream>>>((const int*)edges, flag);
    k_bhist<<<NBLK, 256, 0, stream>>>(edges, E, flag, histm, NBUK);
    k_bscan<<<NBUK, 512, 0, stream>>>(histm, btot);
    k_btotscan<<<1, 512, 0, stream>>>(btot, bbase, NBUK);
    k_binscatter<<<NBLK, 256, 0, stream>>>(edges, E, flag, histm, bbase, bins, NBUK);
    k_degdinv<<<NBUK, 256, 0, stream>>>(bins, bbase, btot, cnt, N);
    k_scan1<<<NB, 256, 0, stream>>>(cnt, bsum, N);
    k_scan2<<<1, 512, 0, stream>>>(bsum, bpre, NB);
    k_scan3<<<NB, 256, 0, stream>>>(cnt, bpre, offs, dinv, N);
    k_csrbuild<<<NBUK, 256, 0, stream>>>(bins, bbase, btot, offs, csr, N);

    // --- dense path ---
    k_lin<<<(N + 63) / 64, 256, 0, stream>>>(fea, Wlin, blin, xb, N);
    k_stats<<<512, 256, 0, stream>>>(xb, N, sums);
    k_bnfinal<<<1, 128, 0, stream>>>(sums, gamma, beta, 1.0f / (float)N, aff);
    k_h<<<(N + 63) / 64, 256, 0, stream>>>(xb, Wg, aff, hb, N);

    // --- aggregation + log_softmax ---
    k_agg<<<(N + 3) / 4, 256, 0, stream>>>(hb, csr, offs, cnt, dinv, bg, out, N);
}

// Round 5
// 383.148 us; speedup vs baseline: 2.4769x; 1.0195x over previous
//
#include <hip/hip_runtime.h>
#include <math.h>

#define LEAKY 0.01f
#define BN_EPS 1e-5f
#define NBLK 512          // partition blocks (fixed; histm row length)

typedef unsigned int uint;
typedef float f32x2 __attribute__((ext_vector_type(2)));
typedef float f32x4 __attribute__((ext_vector_type(4)));

__device__ __forceinline__ float bflo(uint v) { return __uint_as_float(v << 16); }
__device__ __forceinline__ float bfhi(uint v) { return __uint_as_float(v & 0xffff0000u); }
__device__ __forceinline__ uint packbf(float a, float b) {
    uint ua = __float_as_uint(a), ub = __float_as_uint(b);
    ua += 0x7fffu + ((ua >> 16) & 1u);
    ub += 0x7fffu + ((ub >> 16) & 1u);
    return (ua >> 16) | (ub & 0xffff0000u);
}

// Inline probe: int64 edges have all-zero odd 32-bit words (first 64 checked).
__device__ __forceinline__ int detect_i64(const int* __restrict__ raw) {
    int t = threadIdx.x & 63;
    unsigned long long b = __ballot(raw[2 * t + 1] != 0);
    return b == 0ull;
}

// ---------------------------------------------------------------------------
// Partition pass A: per-block LDS histogram of dst>>8 -> histm[bucket][block].
__global__ __launch_bounds__(256) void k_bhist(const void* __restrict__ edges, int E,
                                               int* __restrict__ histm, int NBUK)
{
    __shared__ int hh[512];
    for (int b = threadIdx.x; b < 512; b += 256) hh[b] = 0;
    const int isI64 = detect_i64((const int*)edges);
    __syncthreads();

    const long long* e64 = (const long long*)edges;
    const int*       e32 = (const int*)edges;
    const int chunk = (E + NBLK - 1) / NBLK;
    const int lo = blockIdx.x * chunk;
    const int hi = min(lo + chunk, E);
    for (int e = lo + threadIdx.x; e < hi; e += 256) {
        int dst = isI64 ? (int)e64[(size_t)E + e] : e32[(size_t)E + e];
        atomicAdd(&hh[dst >> 8], 1);
    }
    __syncthreads();
    for (int b = threadIdx.x; b < NBUK; b += 256)
        histm[(size_t)b * NBLK + blockIdx.x] = hh[b];
}

// Pass A2: per-bucket exclusive scan across blocks; emit bucket totals.
__global__ __launch_bounds__(512) void k_bscan(int* __restrict__ histm,
                                               int* __restrict__ btot)
{
    __shared__ int sd[512];
    const int bkt = blockIdx.x;
    const int t = threadIdx.x;
    int v = histm[(size_t)bkt * NBLK + t];
    sd[t] = v;
    __syncthreads();
    for (int o = 1; o < 512; o <<= 1) {
        int u = (t >= o) ? sd[t - o] : 0;
        __syncthreads();
        sd[t] += u;
        __syncthreads();
    }
    histm[(size_t)bkt * NBLK + t] = sd[t] - v;     // exclusive within bucket
    if (t == 511) btot[bkt] = sd[511];
}

// Pass A3: exclusive scan of bucket totals -> bucket bases (= edge offsets).
__global__ __launch_bounds__(512) void k_btotscan(const int* __restrict__ btot,
                                                  int* __restrict__ bbase, int NBUK)
{
    __shared__ int sd[512];
    const int t = threadIdx.x;
    int v = (t < NBUK) ? btot[t] : 0;
    sd[t] = v;
    __syncthreads();
    for (int o = 1; o < 512; o <<= 1) {
        int u = (t >= o) ? sd[t - o] : 0;
        __syncthreads();
        sd[t] += u;
        __syncthreads();
    }
    if (t < NBUK) bbase[t] = sd[t] - v;
}

// Pass B: scatter packed (src | dstlow<<24) into dst-bucketed bins.
__global__ __launch_bounds__(256) void k_binscatter(const void* __restrict__ edges, int E,
                                                    const int* __restrict__ histm,
                                                    const int* __restrict__ bbase,
                                                    uint* __restrict__ bins, int NBUK)
{
    __shared__ int cur[512];
    const int isI64 = detect_i64((const int*)edges);
    for (int b = threadIdx.x; b < NBUK; b += 256)
        cur[b] = bbase[b] + histm[(size_t)b * NBLK + blockIdx.x];
    __syncthreads();

    const long long* e64 = (const long long*)edges;
    const int*       e32 = (const int*)edges;
    const int chunk = (E + NBLK - 1) / NBLK;
    const int lo = blockIdx.x * chunk;
    const int hi = min(lo + chunk, E);
    for (int e = lo + threadIdx.x; e < hi; e += 256) {
        int src, dst;
        if (isI64) { src = (int)e64[e]; dst = (int)e64[(size_t)E + e]; }
        else       { src = e32[e];      dst = e32[(size_t)E + e]; }
        int pos = atomicAdd(&cur[dst >> 8], 1);
        bins[pos] = (uint)src | ((uint)(dst & 255) << 24);
    }
}

// Per-bucket degree histogram -> cnt, dinv.
__global__ __launch_bounds__(256) void k_degdinv(const uint* __restrict__ bins,
                                                 const int* __restrict__ bbase,
                                                 const int* __restrict__ btot,
                                                 int* __restrict__ cnt,
                                                 float* __restrict__ dinv, int N)
{
    __shared__ int c[256];
    const int bkt = blockIdx.x;
    c[threadIdx.x] = 0;
    __syncthreads();
    const int lo = bbase[bkt];
    const int hi = lo + btot[bkt];
    for (int i = lo + threadIdx.x; i < hi; i += 256)
        atomicAdd(&c[bins[i] >> 24], 1);
    __syncthreads();
    int node = (bkt << 8) + threadIdx.x;
    if (node < N) {
        cnt[node]  = c[threadIdx.x];
        dinv[node] = rsqrtf((float)(c[threadIdx.x] + 1));
    }
}

// Pass C: per-bucket local scan -> offs; scatter csr2 = (src, norm).
__global__ __launch_bounds__(256) void k_csr(const uint* __restrict__ bins,
                                             const int* __restrict__ bbase,
                                             const int* __restrict__ btot,
                                             const int* __restrict__ cnt,
                                             const float* __restrict__ dinv,
                                             int* __restrict__ offs,
                                             uint2* __restrict__ csr2, int N)
{
    __shared__ int sd[256];
    __shared__ int cur[256];
    __shared__ float dloc[256];
    const int bkt = blockIdx.x;
    const int t = threadIdx.x;
    const int node = (bkt << 8) + t;
    int v = (node < N) ? cnt[node] : 0;
    dloc[t] = (node < N) ? dinv[node] : 0.f;
    sd[t] = v;
    __syncthreads();
    for (int o = 1; o < 256; o <<= 1) {
        int u = (t >= o) ? sd[t - o] : 0;
        __syncthreads();
        sd[t] += u;
        __syncthreads();
    }
    const int off = bbase[bkt] + sd[t] - v;       // exclusive prefix
    if (node < N) offs[node] = off;
    cur[t] = off;
    __syncthreads();
    const int lo = bbase[bkt];
    const int hi = lo + btot[bkt];
    for (int i = lo + t; i < hi; i += 256) {
        uint e = bins[i];
        uint src = e & 0x00ffffffu;
        uint dl  = e >> 24;
        int pos = atomicAdd(&cur[dl], 1);
        float nrm = dinv[src] * dloc[dl];
        csr2[pos] = make_uint2(src, __float_as_uint(nrm));
    }
}

// ---------------------------------------------------------------------------
// GEMM1: x = fea @ Wlin^T + blin -> bf16 xb.  Block 0 also zeroes sums.
__global__ __launch_bounds__(256) void k_lin(const float* __restrict__ fea,
                                             const float* __restrict__ W,
                                             const float* __restrict__ bias,
                                             uint* __restrict__ xb,
                                             float* __restrict__ sums, int N)
{
    __shared__ float xs[128][64];
    __shared__ float Wt[64][128];
    const int tid = threadIdx.x;
    const int r0  = blockIdx.x * 64;

    if (blockIdx.x == 0) sums[tid] = 0.f;     // 256 floats, done before k_stats

    #pragma unroll
    for (int it = 0; it < 8; ++it) {
        int flat = it * 256 + tid;
        int row  = flat & 63;
        int kq   = flat >> 6;                 // 0..31
        int r    = r0 + row;
        float4 v = make_float4(0.f, 0.f, 0.f, 0.f);
        if (r < N) v = *reinterpret_cast<const float4*>(&fea[(size_t)r * 128 + kq * 4]);
        xs[kq*4+0][row] = v.x; xs[kq*4+1][row] = v.y;
        xs[kq*4+2][row] = v.z; xs[kq*4+3][row] = v.w;
    }

    const int tx = tid & 15;
    const int ty = tid >> 4;
    float acc[4][8] = {};

    for (int kb = 0; kb < 128; kb += 64) {
        __syncthreads();
        #pragma unroll
        for (int it = 0; it < 8; ++it) {
            int flat = it * 256 + tid;
            int j    = flat & 127;
            int kq   = flat >> 7;             // 0..15
            float4 w = *reinterpret_cast<const float4*>(&W[(size_t)j * 128 + kb + kq * 4]);
            Wt[kq*4+0][j] = w.x; Wt[kq*4+1][j] = w.y;
            Wt[kq*4+2][j] = w.z; Wt[kq*4+3][j] = w.w;
        }
        __syncthreads();
        #pragma unroll 8
        for (int kk = 0; kk < 64; ++kk) {
            float4 xv = *reinterpret_cast<const float4*>(&xs[kb + kk][ty * 4]);
            float4 w0 = *reinterpret_cast<const float4*>(&Wt[kk][tx * 8]);
            float4 w1 = *reinterpret_cast<const float4*>(&Wt[kk][tx * 8 + 4]);
            float xr[4] = {xv.x, xv.y, xv.z, xv.w};
            float wr[8] = {w0.x, w0.y, w0.z, w0.w, w1.x, w1.y, w1.z, w1.w};
            #pragma unroll
            for (int a = 0; a < 4; ++a)
                #pragma unroll
                for (int b = 0; b < 8; ++b)
                    acc[a][b] = fmaf(xr[a], wr[b], acc[a][b]);
        }
    }

    float4 b0 = *reinterpret_cast<const float4*>(&bias[tx * 8]);
    float4 b1 = *reinterpret_cast<const float4*>(&bias[tx * 8 + 4]);
    #pragma unroll
    for (int a = 0; a < 4; ++a) {
        int r = r0 + ty * 4 + a;
        if (r < N) {
            uint4 o;
            o.x = packbf(acc[a][0] + b0.x, acc[a][1] + b0.y);
            o.y = packbf(acc[a][2] + b0.z, acc[a][3] + b0.w);
            o.z = packbf(acc[a][4] + b1.x, acc[a][5] + b1.y);
            o.w = packbf(acc[a][6] + b1.z, acc[a][7] + b1.w);
            *reinterpret_cast<uint4*>(&xb[(size_t)r * 64 + tx * 4]) = o;
        }
    }
}

// ---------------------------------------------------------------------------
// BN batch stats from bf16 x.
__global__ __launch_bounds__(256) void k_stats(const uint* __restrict__ xb, int N,
                                               float* __restrict__ sums)
{
    const int c  = threadIdx.x & 63;          // uint column (2 features)
    const int rq = threadIdx.x >> 6;          // 0..3
    float s0 = 0.f, s1 = 0.f, q0 = 0.f, q1 = 0.f;
    for (int r = blockIdx.x * 4 + rq; r < N; r += gridDim.x * 4) {
        uint v = xb[(size_t)r * 64 + c];
        float f0 = bflo(v), f1 = bfhi(v);
        s0 += f0; s1 += f1; q0 += f0 * f0; q1 += f1 * f1;
    }
    __shared__ float rs0[256], rs1[256], rq0[256], rq1[256];
    rs0[threadIdx.x] = s0; rs1[threadIdx.x] = s1;
    rq0[threadIdx.x] = q0; rq1[threadIdx.x] = q1;
    __syncthreads();
    if (threadIdx.x < 64) {
        int t = threadIdx.x;
        float S0 = rs0[t] + rs0[t+64] + rs0[t+128] + rs0[t+192];
        float S1 = rs1[t] + rs1[t+64] + rs1[t+128] + rs1[t+192];
        float Q0 = rq0[t] + rq0[t+64] + rq0[t+128] + rq0[t+192];
        float Q1 = rq1[t] + rq1[t+64] + rq1[t+128] + rq1[t+192];
        atomicAdd(&sums[2*t],       S0);
        atomicAdd(&sums[2*t+1],     S1);
        atomicAdd(&sums[128+2*t],   Q0);
        atomicAdd(&sums[128+2*t+1], Q1);
    }
}

// ---------------------------------------------------------------------------
// GEMM2: h = leakyrelu(a*x + b) @ Wg^T; BN-final computed inline from sums.
__global__ __launch_bounds__(256) void k_h(const uint* __restrict__ xb,
                                           const float* __restrict__ W,
                                           const float* __restrict__ sums,
                                           const float* __restrict__ gamma,
                                           const float* __restrict__ beta,
                                           float invN,
                                           uint* __restrict__ hb, int N)
{
    __shared__ float xs[128][64];
    __shared__ float Wt[64][128];
    __shared__ float aff_s[256];
    const int tid = threadIdx.x;
    const int r0  = blockIdx.x * 64;

    if (tid < 128) {
        float mean = sums[tid] * invN;
        float var  = sums[128 + tid] * invN - mean * mean;
        float coef = gamma[tid] * rsqrtf(var + BN_EPS);
        aff_s[tid]       = coef;
        aff_s[128 + tid] = beta[tid] - coef * mean;
    }
    __syncthreads();

    #pragma unroll
    for (int it = 0; it < 16; ++it) {
        int flat = it * 256 + tid;            // 64 rows x 64 uints
        int row  = flat & 63;
        int u    = flat >> 6;                 // column pair
        int r    = r0 + row;
        uint v   = (r < N) ? xb[(size_t)r * 64 + u] : 0u;
        float y0 = fmaf(aff_s[2*u],   bflo(v), aff_s[128 + 2*u]);
        float y1 = fmaf(aff_s[2*u+1], bfhi(v), aff_s[128 + 2*u+1]);
        y0 = (y0 >= 0.f) ? y0 : LEAKY * y0;
        y1 = (y1 >= 0.f) ? y1 : LEAKY * y1;
        xs[2*u][row]   = y0;
        xs[2*u+1][row] = y1;
    }

    const int tx = tid & 15;
    const int ty = tid >> 4;
    float acc[4][8] = {};

    for (int kb = 0; kb < 128; kb += 64) {
        __syncthreads();
        #pragma unroll
        for (int it = 0; it < 8; ++it) {
            int flat = it * 256 + tid;
            int j    = flat & 127;
            int kq   = flat >> 7;
            float4 w = *reinterpret_cast<const float4*>(&W[(size_t)j * 128 + kb + kq * 4]);
            Wt[kq*4+0][j] = w.x; Wt[kq*4+1][j] = w.y;
            Wt[kq*4+2][j] = w.z; Wt[kq*4+3][j] = w.w;
        }
        __syncthreads();
        #pragma unroll 8
        for (int kk = 0; kk < 64; ++kk) {
            float4 xv = *reinterpret_cast<const float4*>(&xs[kb + kk][ty * 4]);
            float4 w0 = *reinterpret_cast<const float4*>(&Wt[kk][tx * 8]);
            float4 w1 = *reinterpret_cast<const float4*>(&Wt[kk][tx * 8 + 4]);
            float xr[4] = {xv.x, xv.y, xv.z, xv.w};
            float wr[8] = {w0.x, w0.y, w0.z, w0.w, w1.x, w1.y, w1.z, w1.w};
            #pragma unroll
            for (int a = 0; a < 4; ++a)
                #pragma unroll
                for (int b = 0; b < 8; ++b)
                    acc[a][b] = fmaf(xr[a], wr[b], acc[a][b]);
        }
    }

    #pragma unroll
    for (int a = 0; a < 4; ++a) {
        int r = r0 + ty * 4 + a;
        if (r < N) {
            uint4 o;
            o.x = packbf(acc[a][0], acc[a][1]);
            o.y = packbf(acc[a][2], acc[a][3]);
            o.z = packbf(acc[a][4], acc[a][5]);
            o.w = packbf(acc[a][6], acc[a][7]);
            *reinterpret_cast<uint4*>(&hb[(size_t)r * 64 + tx * 4]) = o;
        }
    }
}

// ---------------------------------------------------------------------------
// Gather aggregation: 1 wave/node; lane = 16B chunk (8 features); 4 lane-groups
// process 4 edges per load instruction. csr2 = (src, norm) precomputed.
__global__ __launch_bounds__(256) void k_agg(const uint* __restrict__ hb,
                                             const uint2* __restrict__ csr2,
                                             const int* __restrict__ offs,
                                             const int* __restrict__ cnt,
                                             const float* __restrict__ dinv,
                                             const float* __restrict__ bg,
                                             float* __restrict__ out, int N)
{
    const int wid  = (blockIdx.x * blockDim.x + threadIdx.x) >> 6;
    const int lane = threadIdx.x & 63;
    if (wid >= N) return;
    const int i = wid;
    const int p = lane & 15;      // 16-B chunk within row (features 8p..8p+7)
    const int q = lane >> 4;      // edge subgroup 0..3

    float acc[8] = {};
    const int start = offs[i];
    const int m     = cnt[i];

    for (int base = 0; base < m; base += 64) {
        const int nb = min(64, m - base);
        uint sx = 0; float nv = 0.f;
        if (lane < nb) {
            unsigned long long cw = __builtin_nontemporal_load(
                reinterpret_cast<const unsigned long long*>(&csr2[start + base + lane]));
            sx = (uint)cw;
            nv = __uint_as_float((uint)(cw >> 32));
        }
        for (int j = 0; j < nb; j += 8) {
            #pragma unroll
            for (int hh = 0; hh < 2; ++hh) {
                int eidx = j + hh * 4 + q;
                int   s  = __shfl((int)sx, eidx);
                float nr = __shfl(nv, eidx);
                nr = (eidx < nb) ? nr : 0.f;
                const uint4 v = *reinterpret_cast<const uint4*>(
                    &hb[(size_t)(uint)s * 64 + p * 4]);
                acc[0] = fmaf(nr, bflo(v.x), acc[0]);
                acc[1] = fmaf(nr, bfhi(v.x), acc[1]);
                acc[2] = fmaf(nr, bflo(v.y), acc[2]);
                acc[3] = fmaf(nr, bfhi(v.y), acc[3]);
                acc[4] = fmaf(nr, bflo(v.z), acc[4]);
                acc[5] = fmaf(nr, bfhi(v.z), acc[5]);
                acc[6] = fmaf(nr, bflo(v.w), acc[6]);
                acc[7] = fmaf(nr, bfhi(v.w), acc[7]);
            }
        }
    }

    // reduce the 4 edge subgroups
    #pragma unroll
    for (int r = 0; r < 8; ++r) {
        acc[r] += __shfl_xor(acc[r], 16);
        acc[r] += __shfl_xor(acc[r], 32);
    }

    // self term + bias
    const float d0 = dinv[i];
    const float self = d0 * d0;
    const uint4 sv = *reinterpret_cast<const uint4*>(&hb[(size_t)i * 64 + p * 4]);
    float4 b0 = *reinterpret_cast<const float4*>(&bg[p * 8]);
    float4 b1 = *reinterpret_cast<const float4*>(&bg[p * 8 + 4]);
    float v0 = fmaf(self, bflo(sv.x), acc[0]) + b0.x;
    float v1 = fmaf(self, bfhi(sv.x), acc[1]) + b0.y;
    float v2 = fmaf(self, bflo(sv.y), acc[2]) + b0.z;
    float v3 = fmaf(self, bfhi(sv.y), acc[3]) + b0.w;
    float v4 = fmaf(self, bflo(sv.z), acc[4]) + b1.x;
    float v5 = fmaf(self, bfhi(sv.z), acc[5]) + b1.y;
    float v6 = fmaf(self, bflo(sv.w), acc[6]) + b1.z;
    float v7 = fmaf(self, bfhi(sv.w), acc[7]) + b1.w;

    // log_softmax over 128 features (distributed across 16 lanes)
    float mx = fmaxf(fmaxf(fmaxf(v0, v1), fmaxf(v2, v3)),
                     fmaxf(fmaxf(v4, v5), fmaxf(v6, v7)));
    #pragma unroll
    for (int o = 8; o > 0; o >>= 1) mx = fmaxf(mx, __shfl_xor(mx, o));
    float sum = __expf(v0 - mx) + __expf(v1 - mx) + __expf(v2 - mx) + __expf(v3 - mx)
              + __expf(v4 - mx) + __expf(v5 - mx) + __expf(v6 - mx) + __expf(v7 - mx);
    #pragma unroll
    for (int o = 8; o > 0; o >>= 1) sum += __shfl_xor(sum, o);
    float ls = mx + __logf(sum);

    if (q == 0) {
        f32x4 o0 = {v0 - ls, v1 - ls, v2 - ls, v3 - ls};
        f32x4 o1 = {v4 - ls, v5 - ls, v6 - ls, v7 - ls};
        __builtin_nontemporal_store(o0, reinterpret_cast<f32x4*>(&out[(size_t)i * 128 + p * 8]));
        __builtin_nontemporal_store(o1, reinterpret_cast<f32x4*>(&out[(size_t)i * 128 + p * 8 + 4]));
    }
}

// ---------------------------------------------------------------------------
extern "C" void kernel_launch(void* const* d_in, const int* in_sizes, int n_in,
                              void* d_out, int out_size, void* d_ws, size_t ws_size,
                              hipStream_t stream)
{
    (void)n_in; (void)out_size; (void)ws_size;
    const float* fea   = (const float*)d_in[0];
    const void*  edges = d_in[1];
    const float* Wlin  = (const float*)d_in[2];
    const float* blin  = (const float*)d_in[3];
    const float* gamma = (const float*)d_in[4];
    const float* beta  = (const float*)d_in[5];
    const float* Wg    = (const float*)d_in[6];
    const float* bg    = (const float*)d_in[7];
    float* out = (float*)d_out;

    const int N    = in_sizes[0] / 128;
    const int E    = in_sizes[1] / 2;
    const int NBUK = (N + 255) >> 8;          // dst buckets (256 nodes each)

    char* p = (char*)d_ws;
    // bins (graph phase, E*4 B) aliases xb (dense phase, N*256 B).
    size_t u0 = (size_t)N * 64 * 4;
    size_t u1 = (size_t)E * 4;
    uint*  xb   = (uint*)p;
    uint*  bins = (uint*)p;    p += (u0 > u1 ? u0 : u1);
    uint*  hb   = (uint*)p;    p += (size_t)N * 64 * 4;
    uint2* csr2 = (uint2*)p;   p += (size_t)E * 8;
    int*   histm = (int*)p;    p += (size_t)NBUK * NBLK * 4;
    float* sums = (float*)p;   p += 256 * 4;
    int*   cnt  = (int*)p;     p += (size_t)N * 4;
    int*   offs = (int*)p;     p += (size_t)N * 4;
    float* dinv = (float*)p;   p += (size_t)N * 4;
    int*   btot = (int*)p;     p += 512 * 4;
    int*   bbase = (int*)p;    p += 512 * 4;

    // --- graph build ---
    k_bhist<<<NBLK, 256, 0, stream>>>(edges, E, histm, NBUK);
    k_bscan<<<NBUK, 512, 0, stream>>>(histm, btot);
    k_btotscan<<<1, 512, 0, stream>>>(btot, bbase, NBUK);
    k_binscatter<<<NBLK, 256, 0, stream>>>(edges, E, histm, bbase, bins, NBUK);
    k_degdinv<<<NBUK, 256, 0, stream>>>(bins, bbase, btot, cnt, dinv, N);
    k_csr<<<NBUK, 256, 0, stream>>>(bins, bbase, btot, cnt, dinv, offs, csr2, N);

    // --- dense path ---
    k_lin<<<(N + 63) / 64, 256, 0, stream>>>(fea, Wlin, blin, xb, sums, N);
    k_stats<<<512, 256, 0, stream>>>(xb, N, sums);
    k_h<<<(N + 63) / 64, 256, 0, stream>>>(xb, Wg, sums, gamma, beta,
                                           1.0f / (float)N, hb, N);

    // --- aggregation + log_softmax ---
    k_agg<<<(N + 3) / 4, 256, 0, stream>>>(hb, csr2, offs, cnt, dinv, bg, out, N);
}

// Round 6
// 304.528 us; speedup vs baseline: 3.1163x; 1.2582x over previous
//
#include <hip/hip_runtime.h>
#include <math.h>

#define LEAKY 0.01f
#define BN_EPS 1e-5f
#define NBLK 512          // partition blocks (fixed; histm row length)

typedef unsigned int uint;
typedef float f32x4 __attribute__((ext_vector_type(4)));
typedef short bf16x8 __attribute__((ext_vector_type(8)));

__device__ __forceinline__ float bflo(uint v) { return __uint_as_float(v << 16); }
__device__ __forceinline__ float bfhi(uint v) { return __uint_as_float(v & 0xffff0000u); }
__device__ __forceinline__ uint packbf(float a, float b) {
    uint ua = __float_as_uint(a), ub = __float_as_uint(b);
    ua += 0x7fffu + ((ua >> 16) & 1u);
    ub += 0x7fffu + ((ub >> 16) & 1u);
    return (ua >> 16) | (ub & 0xffff0000u);
}

// Inline probe: int64 edges have all-zero odd 32-bit words (first 64 checked).
__device__ __forceinline__ int detect_i64(const int* __restrict__ raw) {
    int t = threadIdx.x & 63;
    unsigned long long b = __ballot(raw[2 * t + 1] != 0);
    return b == 0ull;
}

// ---------------------------------------------------------------------------
// Prep: Wlin, Wg -> bf16-pair arrays; zero sums. 64 blocks x 256.
__global__ __launch_bounds__(256) void k_prep(const float* __restrict__ Wlin,
                                              const float* __restrict__ Wg,
                                              uint* __restrict__ Wlinb,
                                              uint* __restrict__ Wgb,
                                              float* __restrict__ sums)
{
    const int idx = blockIdx.x * 256 + threadIdx.x;
    if (blockIdx.x == 0) sums[threadIdx.x] = 0.f;
    if (idx < 8192) {
        Wlinb[idx] = packbf(Wlin[2 * idx], Wlin[2 * idx + 1]);
    } else {
        int j = idx - 8192;
        Wgb[j] = packbf(Wg[2 * j], Wg[2 * j + 1]);
    }
}

// ---------------------------------------------------------------------------
// Partition pass A: per-block LDS histogram of dst>>8 -> histm[bucket][block].
__global__ __launch_bounds__(256) void k_bhist(const void* __restrict__ edges, int E,
                                               int* __restrict__ histm, int NBUK)
{
    __shared__ int hh[512];
    for (int b = threadIdx.x; b < 512; b += 256) hh[b] = 0;
    const int isI64 = detect_i64((const int*)edges);
    __syncthreads();

    const long long* e64 = (const long long*)edges;
    const int*       e32 = (const int*)edges;
    const int chunk = (E + NBLK - 1) / NBLK;
    const int lo = blockIdx.x * chunk;
    const int hi = min(lo + chunk, E);
    for (int e = lo + threadIdx.x; e < hi; e += 256) {
        int dst = isI64 ? (int)e64[(size_t)E + e] : e32[(size_t)E + e];
        atomicAdd(&hh[dst >> 8], 1);
    }
    __syncthreads();
    for (int b = threadIdx.x; b < NBUK; b += 256)
        histm[(size_t)b * NBLK + blockIdx.x] = hh[b];
}

// Pass A2: per-bucket exclusive scan across blocks; emit bucket totals.
__global__ __launch_bounds__(512) void k_bscan(int* __restrict__ histm,
                                               int* __restrict__ btot)
{
    __shared__ int sd[512];
    const int bkt = blockIdx.x;
    const int t = threadIdx.x;
    int v = histm[(size_t)bkt * NBLK + t];
    sd[t] = v;
    __syncthreads();
    for (int o = 1; o < 512; o <<= 1) {
        int u = (t >= o) ? sd[t - o] : 0;
        __syncthreads();
        sd[t] += u;
        __syncthreads();
    }
    histm[(size_t)bkt * NBLK + t] = sd[t] - v;     // exclusive within bucket
    if (t == 511) btot[bkt] = sd[511];
}

// Pass A3: exclusive scan of bucket totals -> bucket bases (= edge offsets).
__global__ __launch_bounds__(512) void k_btotscan(const int* __restrict__ btot,
                                                  int* __restrict__ bbase, int NBUK)
{
    __shared__ int sd[512];
    const int t = threadIdx.x;
    int v = (t < NBUK) ? btot[t] : 0;
    sd[t] = v;
    __syncthreads();
    for (int o = 1; o < 512; o <<= 1) {
        int u = (t >= o) ? sd[t - o] : 0;
        __syncthreads();
        sd[t] += u;
        __syncthreads();
    }
    if (t < NBUK) bbase[t] = sd[t] - v;
}

// Pass B: scatter packed (src | dstlow<<24) into dst-bucketed bins.
__global__ __launch_bounds__(256) void k_binscatter(const void* __restrict__ edges, int E,
                                                    const int* __restrict__ histm,
                                                    const int* __restrict__ bbase,
                                                    uint* __restrict__ bins, int NBUK)
{
    __shared__ int cur[512];
    const int isI64 = detect_i64((const int*)edges);
    for (int b = threadIdx.x; b < NBUK; b += 256)
        cur[b] = bbase[b] + histm[(size_t)b * NBLK + blockIdx.x];
    __syncthreads();

    const long long* e64 = (const long long*)edges;
    const int*       e32 = (const int*)edges;
    const int chunk = (E + NBLK - 1) / NBLK;
    const int lo = blockIdx.x * chunk;
    const int hi = min(lo + chunk, E);
    for (int e = lo + threadIdx.x; e < hi; e += 256) {
        int src, dst;
        if (isI64) { src = (int)e64[e]; dst = (int)e64[(size_t)E + e]; }
        else       { src = e32[e];      dst = e32[(size_t)E + e]; }
        int pos = atomicAdd(&cur[dst >> 8], 1);
        bins[pos] = (uint)src | ((uint)(dst & 255) << 24);
    }
}

// Per-bucket degree histogram -> cnt, dinv.
__global__ __launch_bounds__(256) void k_degdinv(const uint* __restrict__ bins,
                                                 const int* __restrict__ bbase,
                                                 const int* __restrict__ btot,
                                                 int* __restrict__ cnt,
                                                 float* __restrict__ dinv, int N)
{
    __shared__ int c[256];
    const int bkt = blockIdx.x;
    c[threadIdx.x] = 0;
    __syncthreads();
    const int lo = bbase[bkt];
    const int hi = lo + btot[bkt];
    for (int i = lo + threadIdx.x; i < hi; i += 256)
        atomicAdd(&c[bins[i] >> 24], 1);
    __syncthreads();
    int node = (bkt << 8) + threadIdx.x;
    if (node < N) {
        cnt[node]  = c[threadIdx.x];
        dinv[node] = rsqrtf((float)(c[threadIdx.x] + 1));
    }
}

// Pass C: per-bucket counting-sort by src>>8, local scan -> offs,
// scatter csr2 = (src, norm) with each dst list in ~ascending-src order.
__global__ __launch_bounds__(256) void k_csr(const uint* __restrict__ bins,
                                             const int* __restrict__ bbase,
                                             const int* __restrict__ btot,
                                             const int* __restrict__ cnt,
                                             const float* __restrict__ dinv,
                                             int* __restrict__ offs,
                                             uint2* __restrict__ csr2, int N)
{
    __shared__ uint  esort[10240];   // 40 KB sorted-edge buffer
    __shared__ int   sh[512];        // src-bucket hist / cursors
    __shared__ int   sd[256];
    __shared__ int   cur[256];
    __shared__ float dloc[256];
    const int bkt = blockIdx.x;
    const int t = threadIdx.x;
    const int node = (bkt << 8) + t;
    int v = (node < N) ? cnt[node] : 0;
    dloc[t] = (node < N) ? dinv[node] : 0.f;
    sd[t] = v;
    __syncthreads();
    for (int o = 1; o < 256; o <<= 1) {
        int u = (t >= o) ? sd[t - o] : 0;
        __syncthreads();
        sd[t] += u;
        __syncthreads();
    }
    const int off = bbase[bkt] + sd[t] - v;       // exclusive prefix
    if (node < N) offs[node] = off;
    cur[t] = off;
    for (int b = t; b < 512; b += 256) sh[b] = 0;
    __syncthreads();

    const int lo    = bbase[bkt];
    const int total = btot[bkt];
    const bool sorted = (total <= 10240);
    if (sorted) {
        for (int i = lo + t; i < lo + total; i += 256)
            atomicAdd(&sh[(bins[i] & 0x00ffffffu) >> 8], 1);
        __syncthreads();
        // exclusive scan of 512 counters with 256 threads (pairs)
        int a0 = sh[2 * t], a1 = sh[2 * t + 1];
        int s = a0 + a1;
        sd[t] = s;
        __syncthreads();
        for (int o = 1; o < 256; o <<= 1) {
            int u = (t >= o) ? sd[t - o] : 0;
            __syncthreads();
            sd[t] += u;
            __syncthreads();
        }
        int ex = sd[t] - s;
        sh[2 * t] = ex;
        sh[2 * t + 1] = ex + a0;
        __syncthreads();
        for (int i = lo + t; i < lo + total; i += 256) {
            uint e = bins[i];
            int pos = atomicAdd(&sh[(e & 0x00ffffffu) >> 8], 1);
            esort[pos] = e;
        }
        __syncthreads();
    }
    for (int i = t; i < total; i += 256) {
        uint e = sorted ? esort[i] : bins[lo + i];
        uint src = e & 0x00ffffffu;
        uint dl  = e >> 24;
        int pos = atomicAdd(&cur[dl], 1);
        csr2[pos] = make_uint2(src, __float_as_uint(dinv[src] * dloc[dl]));
    }
}

// ---------------------------------------------------------------------------
// GEMM1 (MFMA): x = fea @ Wlin^T + blin -> bf16 xb; fused BN batch stats.
// 64 rows/block, 4 waves; wave w does rows w*16..w*16+15 x all 128 cols.
__global__ __launch_bounds__(256) void k_lin(const float* __restrict__ fea,
                                             const uint* __restrict__ Wb,
                                             const float* __restrict__ bias,
                                             uint* __restrict__ xb,
                                             float* __restrict__ sums, int N)
{
    __shared__ uint xls[64][68];      // bf16 pairs, row-major, pad->conflict-free
    __shared__ float sred[16][128];
    __shared__ float qred[16][128];
    const int tid  = threadIdx.x;
    const int r0   = blockIdx.x * 64;
    const int lane = tid & 63;
    const int w    = tid >> 6;
    const int fr   = lane & 15;
    const int fk   = lane >> 4;

    // stage fea (f32) -> bf16 LDS
    #pragma unroll
    for (int it = 0; it < 8; ++it) {
        int flat = it * 256 + tid;
        int row  = flat >> 5;
        int c4   = flat & 31;
        int r    = r0 + row;
        float4 v = make_float4(0.f, 0.f, 0.f, 0.f);
        if (r < N) v = *reinterpret_cast<const float4*>(&fea[(size_t)r * 128 + c4 * 4]);
        xls[row][c4 * 2]     = packbf(v.x, v.y);
        xls[row][c4 * 2 + 1] = packbf(v.z, v.w);
    }
    __syncthreads();

    bf16x8 a[4];
    #pragma unroll
    for (int kk = 0; kk < 4; ++kk)
        a[kk] = *reinterpret_cast<const bf16x8*>(&xls[w * 16 + fr][kk * 16 + fk * 4]);

    f32x4 acc[8] = {};
    #pragma unroll
    for (int jt = 0; jt < 8; ++jt) {
        #pragma unroll
        for (int kk = 0; kk < 4; ++kk) {
            bf16x8 b = *reinterpret_cast<const bf16x8*>(
                &Wb[(size_t)(jt * 16 + fr) * 64 + kk * 16 + fk * 4]);
            acc[jt] = __builtin_amdgcn_mfma_f32_16x16x32_bf16(a[kk], b, acc[jt], 0, 0, 0);
        }
    }
    __syncthreads();

    // epilogue: bias, stats partials, pack, store
    #pragma unroll
    for (int jt = 0; jt < 8; ++jt) {
        float bj = bias[jt * 16 + fr];
        float sl = 0.f, ql = 0.f;
        #pragma unroll
        for (int r = 0; r < 4; ++r) {
            int gr = r0 + w * 16 + fk * 4 + r;
            float val = acc[jt][r] + bj;
            val = (gr < N) ? val : 0.f;
            acc[jt][r] = val;
            sl += val; ql += val * val;
        }
        sred[w * 4 + fk][jt * 16 + fr] = sl;
        qred[w * 4 + fk][jt * 16 + fr] = ql;
    }
    __syncthreads();
    if (tid < 128) {
        float S = 0.f, Q = 0.f;
        #pragma unroll
        for (int g = 0; g < 16; ++g) { S += sred[g][tid]; Q += qred[g][tid]; }
        atomicAdd(&sums[tid], S);
        atomicAdd(&sums[128 + tid], Q);
    }
    #pragma unroll
    for (int jt = 0; jt < 8; ++jt) {
        #pragma unroll
        for (int r = 0; r < 4; ++r) {
            float val = acc[jt][r];
            float pv  = __shfl_xor(val, 1);
            if ((lane & 1) == 0) {
                int gr = r0 + w * 16 + fk * 4 + r;
                if (gr < N)
                    xb[(size_t)gr * 64 + jt * 8 + (fr >> 1)] = packbf(val, pv);
            }
        }
    }
}

// ---------------------------------------------------------------------------
// GEMM2 (MFMA): h = leakyrelu(a*x + b) @ Wg^T -> bf16 hb; BN-final inline.
__global__ __launch_bounds__(256) void k_h(const uint* __restrict__ xb,
                                           const uint* __restrict__ Wb,
                                           const float* __restrict__ sums,
                                           const float* __restrict__ gamma,
                                           const float* __restrict__ beta,
                                           float invN,
                                           uint* __restrict__ hb, int N)
{
    __shared__ uint xls[64][68];
    __shared__ float aff[256];
    const int tid  = threadIdx.x;
    const int r0   = blockIdx.x * 64;
    const int lane = tid & 63;
    const int w    = tid >> 6;
    const int fr   = lane & 15;
    const int fk   = lane >> 4;

    if (tid < 128) {
        float mean = sums[tid] * invN;
        float var  = sums[128 + tid] * invN - mean * mean;
        float coef = gamma[tid] * rsqrtf(var + BN_EPS);
        aff[tid]       = coef;
        aff[128 + tid] = beta[tid] - coef * mean;
    }
    __syncthreads();

    // stage: bf16 x -> affine+leaky -> bf16 LDS
    #pragma unroll
    for (int it = 0; it < 16; ++it) {
        int flat = it * 256 + tid;
        int row  = flat >> 6;
        int u    = flat & 63;
        int r    = r0 + row;
        uint v   = (r < N) ? xb[(size_t)r * 64 + u] : 0u;
        float y0 = fmaf(aff[2 * u],     bflo(v), aff[128 + 2 * u]);
        float y1 = fmaf(aff[2 * u + 1], bfhi(v), aff[128 + 2 * u + 1]);
        y0 = (y0 >= 0.f) ? y0 : LEAKY * y0;
        y1 = (y1 >= 0.f) ? y1 : LEAKY * y1;
        xls[row][u] = packbf(y0, y1);
    }
    __syncthreads();

    bf16x8 a[4];
    #pragma unroll
    for (int kk = 0; kk < 4; ++kk)
        a[kk] = *reinterpret_cast<const bf16x8*>(&xls[w * 16 + fr][kk * 16 + fk * 4]);

    f32x4 acc[8] = {};
    #pragma unroll
    for (int jt = 0; jt < 8; ++jt) {
        #pragma unroll
        for (int kk = 0; kk < 4; ++kk) {
            bf16x8 b = *reinterpret_cast<const bf16x8*>(
                &Wb[(size_t)(jt * 16 + fr) * 64 + kk * 16 + fk * 4]);
            acc[jt] = __builtin_amdgcn_mfma_f32_16x16x32_bf16(a[kk], b, acc[jt], 0, 0, 0);
        }
    }

    #pragma unroll
    for (int jt = 0; jt < 8; ++jt) {
        #pragma unroll
        for (int r = 0; r < 4; ++r) {
            float val = acc[jt][r];
            float pv  = __shfl_xor(val, 1);
            if ((lane & 1) == 0) {
                int gr = r0 + w * 16 + fk * 4 + r;
                if (gr < N)
                    hb[(size_t)gr * 64 + jt * 8 + (fr >> 1)] = packbf(val, pv);
            }
        }
    }
}

// ---------------------------------------------------------------------------
// Gather aggregation: 1 wave/node; lane = 16B chunk (8 features); 4 lane-groups
// process 4 edges per load instruction. csr2 = (src, norm), src-sorted.
__global__ __launch_bounds__(256) void k_agg(const uint* __restrict__ hb,
                                             const uint2* __restrict__ csr2,
                                             const int* __restrict__ offs,
                                             const int* __restrict__ cnt,
                                             const float* __restrict__ dinv,
                                             const float* __restrict__ bg,
                                             float* __restrict__ out, int N)
{
    const int wid  = (blockIdx.x * blockDim.x + threadIdx.x) >> 6;
    const int lane = threadIdx.x & 63;
    if (wid >= N) return;
    const int i = wid;
    const int p = lane & 15;      // 16-B chunk within row (features 8p..8p+7)
    const int q = lane >> 4;      // edge subgroup 0..3

    float acc[8] = {};
    const int start = offs[i];
    const int m     = cnt[i];

    for (int base = 0; base < m; base += 64) {
        const int nb = min(64, m - base);
        uint sx = 0; float nv = 0.f;
        if (lane < nb) {
            unsigned long long cw = __builtin_nontemporal_load(
                reinterpret_cast<const unsigned long long*>(&csr2[start + base + lane]));
            sx = (uint)cw;
            nv = __uint_as_float((uint)(cw >> 32));
        }
        for (int j = 0; j < nb; j += 8) {
            #pragma unroll
            for (int hh = 0; hh < 2; ++hh) {
                int eidx = j + hh * 4 + q;
                int   s  = __shfl((int)sx, eidx);
                float nr = __shfl(nv, eidx);
                nr = (eidx < nb) ? nr : 0.f;
                const uint4 v = *reinterpret_cast<const uint4*>(
                    &hb[(size_t)(uint)s * 64 + p * 4]);
                acc[0] = fmaf(nr, bflo(v.x), acc[0]);
                acc[1] = fmaf(nr, bfhi(v.x), acc[1]);
                acc[2] = fmaf(nr, bflo(v.y), acc[2]);
                acc[3] = fmaf(nr, bfhi(v.y), acc[3]);
                acc[4] = fmaf(nr, bflo(v.z), acc[4]);
                acc[5] = fmaf(nr, bfhi(v.z), acc[5]);
                acc[6] = fmaf(nr, bflo(v.w), acc[6]);
                acc[7] = fmaf(nr, bfhi(v.w), acc[7]);
            }
        }
    }

    // reduce the 4 edge subgroups
    #pragma unroll
    for (int r = 0; r < 8; ++r) {
        acc[r] += __shfl_xor(acc[r], 16);
        acc[r] += __shfl_xor(acc[r], 32);
    }

    // self term + bias
    const float d0 = dinv[i];
    const float self = d0 * d0;
    const uint4 sv = *reinterpret_cast<const uint4*>(&hb[(size_t)i * 64 + p * 4]);
    float4 b0 = *reinterpret_cast<const float4*>(&bg[p * 8]);
    float4 b1 = *reinterpret_cast<const float4*>(&bg[p * 8 + 4]);
    float v0 = fmaf(self, bflo(sv.x), acc[0]) + b0.x;
    float v1 = fmaf(self, bfhi(sv.x), acc[1]) + b0.y;
    float v2 = fmaf(self, bflo(sv.y), acc[2]) + b0.z;
    float v3 = fmaf(self, bfhi(sv.y), acc[3]) + b0.w;
    float v4 = fmaf(self, bflo(sv.z), acc[4]) + b1.x;
    float v5 = fmaf(self, bfhi(sv.z), acc[5]) + b1.y;
    float v6 = fmaf(self, bflo(sv.w), acc[6]) + b1.z;
    float v7 = fmaf(self, bfhi(sv.w), acc[7]) + b1.w;

    // log_softmax over 128 features (distributed across 16 lanes)
    float mx = fmaxf(fmaxf(fmaxf(v0, v1), fmaxf(v2, v3)),
                     fmaxf(fmaxf(v4, v5), fmaxf(v6, v7)));
    #pragma unroll
    for (int o = 8; o > 0; o >>= 1) mx = fmaxf(mx, __shfl_xor(mx, o));
    float sum = __expf(v0 - mx) + __expf(v1 - mx) + __expf(v2 - mx) + __expf(v3 - mx)
              + __expf(v4 - mx) + __expf(v5 - mx) + __expf(v6 - mx) + __expf(v7 - mx);
    #pragma unroll
    for (int o = 8; o > 0; o >>= 1) sum += __shfl_xor(sum, o);
    float ls = mx + __logf(sum);

    if (q == 0) {
        f32x4 o0 = {v0 - ls, v1 - ls, v2 - ls, v3 - ls};
        f32x4 o1 = {v4 - ls, v5 - ls, v6 - ls, v7 - ls};
        __builtin_nontemporal_store(o0, reinterpret_cast<f32x4*>(&out[(size_t)i * 128 + p * 8]));
        __builtin_nontemporal_store(o1, reinterpret_cast<f32x4*>(&out[(size_t)i * 128 + p * 8 + 4]));
    }
}

// ---------------------------------------------------------------------------
extern "C" void kernel_launch(void* const* d_in, const int* in_sizes, int n_in,
                              void* d_out, int out_size, void* d_ws, size_t ws_size,
                              hipStream_t stream)
{
    (void)n_in; (void)out_size; (void)ws_size;
    const float* fea   = (const float*)d_in[0];
    const void*  edges = d_in[1];
    const float* Wlin  = (const float*)d_in[2];
    const float* blin  = (const float*)d_in[3];
    const float* gamma = (const float*)d_in[4];
    const float* beta  = (const float*)d_in[5];
    const float* Wg    = (const float*)d_in[6];
    const float* bg    = (const float*)d_in[7];
    float* out = (float*)d_out;

    const int N    = in_sizes[0] / 128;
    const int E    = in_sizes[1] / 2;
    const int NBUK = (N + 255) >> 8;          // dst buckets (256 nodes each)

    char* p = (char*)d_ws;
    // bins (graph phase, E*4 B) aliases xb (dense phase, N*256 B).
    size_t u0 = (size_t)N * 64 * 4;
    size_t u1 = (size_t)E * 4;
    uint*  xb   = (uint*)p;
    uint*  bins = (uint*)p;    p += (u0 > u1 ? u0 : u1);
    uint*  hb   = (uint*)p;    p += (size_t)N * 64 * 4;
    uint2* csr2 = (uint2*)p;   p += (size_t)E * 8;
    int*   histm = (int*)p;    p += (size_t)NBUK * NBLK * 4;
    float* sums = (float*)p;   p += 256 * 4;
    int*   cnt  = (int*)p;     p += (size_t)N * 4;
    int*   offs = (int*)p;     p += (size_t)N * 4;
    float* dinv = (float*)p;   p += (size_t)N * 4;
    int*   btot = (int*)p;     p += 512 * 4;
    int*   bbase = (int*)p;    p += 512 * 4;
    uint*  Wlinb = (uint*)p;   p += 8192 * 4;
    uint*  Wgb   = (uint*)p;   p += 8192 * 4;

    // --- prep (W -> bf16, zero sums) ---
    k_prep<<<64, 256, 0, stream>>>(Wlin, Wg, Wlinb, Wgb, sums);

    // --- graph build ---
    k_bhist<<<NBLK, 256, 0, stream>>>(edges, E, histm, NBUK);
    k_bscan<<<NBUK, 512, 0, stream>>>(histm, btot);
    k_btotscan<<<1, 512, 0, stream>>>(btot, bbase, NBUK);
    k_binscatter<<<NBLK, 256, 0, stream>>>(edges, E, histm, bbase, bins, NBUK);
    k_degdinv<<<NBUK, 256, 0, stream>>>(bins, bbase, btot, cnt, dinv, N);
    k_csr<<<NBUK, 256, 0, stream>>>(bins, bbase, btot, cnt, dinv, offs, csr2, N);

    // --- dense path (MFMA) ---
    k_lin<<<(N + 63) / 64, 256, 0, stream>>>(fea, Wlinb, blin, xb, sums, N);
    k_h<<<(N + 63) / 64, 256, 0, stream>>>(xb, Wgb, sums, gamma, beta,
                                           1.0f / (float)N, hb, N);

    // --- aggregation + log_softmax ---
    k_agg<<<(N + 3) / 4, 256, 0, stream>>>(hb, csr2, offs, cnt, dinv, bg, out, N);
}

// Round 7
// 253.457 us; speedup vs baseline: 3.7443x; 1.2015x over previous
//
#include <hip/hip_runtime.h>
#include <math.h>

#define LEAKY 0.01f
#define BN_EPS 1e-5f
#define NBLK 512          // partition blocks (fixed; histm row length)
#define EBUF 10240        // LDS edge-stage capacity in k_csrdeg (40 KB)

typedef unsigned int uint;
typedef float f32x2 __attribute__((ext_vector_type(2)));
typedef float f32x4 __attribute__((ext_vector_type(4)));
typedef short bf16x8 __attribute__((ext_vector_type(8)));

__device__ __forceinline__ float bflo(uint v) { return __uint_as_float(v << 16); }
__device__ __forceinline__ float bfhi(uint v) { return __uint_as_float(v & 0xffff0000u); }
__device__ __forceinline__ uint packbf(float a, float b) {
    uint ua = __float_as_uint(a), ub = __float_as_uint(b);
    ua += 0x7fffu + ((ua >> 16) & 1u);
    ub += 0x7fffu + ((ub >> 16) & 1u);
    return (ua >> 16) | (ub & 0xffff0000u);
}

// Inline probe: int64 edges have all-zero odd 32-bit words (first 64 checked).
__device__ __forceinline__ int detect_i64(const int* __restrict__ raw) {
    int t = threadIdx.x & 63;
    unsigned long long b = __ballot(raw[2 * t + 1] != 0);
    return b == 0ull;
}

// Per-block exclusive scan of btot[0..NBUK) into bb[0..512) (2 elems/thread).
__device__ __forceinline__ void build_bbase(const int* __restrict__ btot,
                                            int NBUK, int* bb, int* sd)
{
    const int t = threadIdx.x;
    int a0 = (2 * t     < NBUK) ? btot[2 * t]     : 0;
    int a1 = (2 * t + 1 < NBUK) ? btot[2 * t + 1] : 0;
    int s = a0 + a1;
    sd[t] = s;
    __syncthreads();
    for (int o = 1; o < 256; o <<= 1) {
        int u = (t >= o) ? sd[t - o] : 0;
        __syncthreads();
        sd[t] += u;
        __syncthreads();
    }
    int ex = sd[t] - s;
    bb[2 * t]     = ex;
    bb[2 * t + 1] = ex + a0;
    __syncthreads();
}

// ---------------------------------------------------------------------------
// Prep: Wlin, Wg -> bf16-pair arrays; zero sums. 64 blocks x 256.
__global__ __launch_bounds__(256) void k_prep(const float* __restrict__ Wlin,
                                              const float* __restrict__ Wg,
                                              uint* __restrict__ Wlinb,
                                              uint* __restrict__ Wgb,
                                              float* __restrict__ sums)
{
    const int idx = blockIdx.x * 256 + threadIdx.x;
    if (blockIdx.x == 0) sums[threadIdx.x] = 0.f;
    if (idx < 8192) {
        Wlinb[idx] = packbf(Wlin[2 * idx], Wlin[2 * idx + 1]);
    } else {
        int j = idx - 8192;
        Wgb[j] = packbf(Wg[2 * j], Wg[2 * j + 1]);
    }
}

// ---------------------------------------------------------------------------
// Partition pass A: per-block LDS histogram of dst>>8 -> histm[bucket][block].
__global__ __launch_bounds__(256) void k_bhist(const void* __restrict__ edges, int E,
                                               int* __restrict__ histm, int NBUK)
{
    __shared__ int hh[512];
    for (int b = threadIdx.x; b < 512; b += 256) hh[b] = 0;
    const int isI64 = detect_i64((const int*)edges);
    __syncthreads();

    const long long* e64 = (const long long*)edges;
    const int*       e32 = (const int*)edges;
    const int chunk = (E + NBLK - 1) / NBLK;
    const int lo = blockIdx.x * chunk;
    const int hi = min(lo + chunk, E);
    for (int e = lo + threadIdx.x; e < hi; e += 256) {
        int dst = isI64 ? (int)e64[(size_t)E + e] : e32[(size_t)E + e];
        atomicAdd(&hh[dst >> 8], 1);
    }
    __syncthreads();
    for (int b = threadIdx.x; b < NBUK; b += 256)
        histm[(size_t)b * NBLK + blockIdx.x] = hh[b];
}

// Pass A2: per-bucket exclusive scan across blocks; emit bucket totals.
__global__ __launch_bounds__(512) void k_bscan(int* __restrict__ histm,
                                               int* __restrict__ btot)
{
    __shared__ int sd[512];
    const int bkt = blockIdx.x;
    const int t = threadIdx.x;
    int v = histm[(size_t)bkt * NBLK + t];
    sd[t] = v;
    __syncthreads();
    for (int o = 1; o < 512; o <<= 1) {
        int u = (t >= o) ? sd[t - o] : 0;
        __syncthreads();
        sd[t] += u;
        __syncthreads();
    }
    histm[(size_t)bkt * NBLK + t] = sd[t] - v;     // exclusive within bucket
    if (t == 511) btot[bkt] = sd[511];
}

// Pass B: scatter packed (src | dstlow<<24) into dst-bucketed bins.
__global__ __launch_bounds__(256) void k_binscatter(const void* __restrict__ edges, int E,
                                                    const int* __restrict__ histm,
                                                    const int* __restrict__ btot,
                                                    uint* __restrict__ bins, int NBUK)
{
    __shared__ int cur[512];
    __shared__ int bb[512];
    __shared__ int sd[256];
    const int isI64 = detect_i64((const int*)edges);
    build_bbase(btot, NBUK, bb, sd);
    for (int b = threadIdx.x; b < NBUK; b += 256)
        cur[b] = bb[b] + histm[(size_t)b * NBLK + blockIdx.x];
    __syncthreads();

    const long long* e64 = (const long long*)edges;
    const int*       e32 = (const int*)edges;
    const int chunk = (E + NBLK - 1) / NBLK;
    const int lo = blockIdx.x * chunk;
    const int hi = min(lo + chunk, E);
    for (int e = lo + threadIdx.x; e < hi; e += 256) {
        int src, dst;
        if (isI64) { src = (int)e64[e]; dst = (int)e64[(size_t)E + e]; }
        else       { src = e32[e];      dst = e32[(size_t)E + e]; }
        int pos = atomicAdd(&cur[dst >> 8], 1);
        bins[pos] = (uint)src | ((uint)(dst & 255) << 24);
    }
}

// Pass C (merged deg+dinv+offs+CSR): one block per bucket; bins staged in LDS.
__global__ __launch_bounds__(256) void k_csrdeg(const uint* __restrict__ bins,
                                                const int* __restrict__ btot,
                                                int* __restrict__ cnt,
                                                float* __restrict__ dinv,
                                                int* __restrict__ offs,
                                                uint* __restrict__ csr,
                                                int N, int NBUK)
{
    __shared__ uint ebuf[EBUF];
    __shared__ int bb[512];
    __shared__ int sd[256];
    __shared__ int c[256];
    const int bkt = blockIdx.x;
    const int t = threadIdx.x;
    build_bbase(btot, NBUK, bb, sd);
    const int lo    = bb[bkt];
    const int total = btot[bkt];
    c[t] = 0;
    __syncthreads();

    const bool fits = (total <= EBUF);
    for (int i = t; i < total; i += 256) {
        uint e = bins[lo + i];
        if (fits) ebuf[i] = e;
        atomicAdd(&c[e >> 24], 1);
    }
    __syncthreads();

    const int node = (bkt << 8) + t;
    const int deg  = c[t];
    if (node < N) {
        cnt[node]  = deg;
        dinv[node] = rsqrtf((float)(deg + 1));
    }
    sd[t] = deg;
    __syncthreads();
    for (int o = 1; o < 256; o <<= 1) {
        int u = (t >= o) ? sd[t - o] : 0;
        __syncthreads();
        sd[t] += u;
        __syncthreads();
    }
    const int off = lo + sd[t] - deg;             // exclusive prefix within bucket
    if (node < N) offs[node] = off;
    c[t] = off;                                   // reuse as write cursor
    __syncthreads();
    for (int i = t; i < total; i += 256) {
        uint e = fits ? ebuf[i] : bins[lo + i];
        int pos = atomicAdd(&c[e >> 24], 1);
        csr[pos] = e & 0x00ffffffu;
    }
}

// ---------------------------------------------------------------------------
// GEMM1 (MFMA): x = fea @ Wlin^T + blin -> bf16 xb; fused BN batch stats.
__global__ __launch_bounds__(256) void k_lin(const float* __restrict__ fea,
                                             const uint* __restrict__ Wb,
                                             const float* __restrict__ bias,
                                             uint* __restrict__ xb,
                                             float* __restrict__ sums, int N)
{
    __shared__ uint xls[64][68];
    __shared__ float sred[16][128];
    __shared__ float qred[16][128];
    const int tid  = threadIdx.x;
    const int r0   = blockIdx.x * 64;
    const int lane = tid & 63;
    const int w    = tid >> 6;
    const int fr   = lane & 15;
    const int fk   = lane >> 4;

    #pragma unroll
    for (int it = 0; it < 8; ++it) {
        int flat = it * 256 + tid;
        int row  = flat >> 5;
        int c4   = flat & 31;
        int r    = r0 + row;
        float4 v = make_float4(0.f, 0.f, 0.f, 0.f);
        if (r < N) v = *reinterpret_cast<const float4*>(&fea[(size_t)r * 128 + c4 * 4]);
        xls[row][c4 * 2]     = packbf(v.x, v.y);
        xls[row][c4 * 2 + 1] = packbf(v.z, v.w);
    }
    __syncthreads();

    bf16x8 a[4];
    #pragma unroll
    for (int kk = 0; kk < 4; ++kk)
        a[kk] = *reinterpret_cast<const bf16x8*>(&xls[w * 16 + fr][kk * 16 + fk * 4]);

    f32x4 acc[8] = {};
    #pragma unroll
    for (int jt = 0; jt < 8; ++jt) {
        #pragma unroll
        for (int kk = 0; kk < 4; ++kk) {
            bf16x8 b = *reinterpret_cast<const bf16x8*>(
                &Wb[(size_t)(jt * 16 + fr) * 64 + kk * 16 + fk * 4]);
            acc[jt] = __builtin_amdgcn_mfma_f32_16x16x32_bf16(a[kk], b, acc[jt], 0, 0, 0);
        }
    }
    __syncthreads();

    #pragma unroll
    for (int jt = 0; jt < 8; ++jt) {
        float bj = bias[jt * 16 + fr];
        float sl = 0.f, ql = 0.f;
        #pragma unroll
        for (int r = 0; r < 4; ++r) {
            int gr = r0 + w * 16 + fk * 4 + r;
            float val = acc[jt][r] + bj;
            val = (gr < N) ? val : 0.f;
            acc[jt][r] = val;
            sl += val; ql += val * val;
        }
        sred[w * 4 + fk][jt * 16 + fr] = sl;
        qred[w * 4 + fk][jt * 16 + fr] = ql;
    }
    __syncthreads();
    if (tid < 128) {
        float S = 0.f, Q = 0.f;
        #pragma unroll
        for (int g = 0; g < 16; ++g) { S += sred[g][tid]; Q += qred[g][tid]; }
        atomicAdd(&sums[tid], S);
        atomicAdd(&sums[128 + tid], Q);
    }
    #pragma unroll
    for (int jt = 0; jt < 8; ++jt) {
        #pragma unroll
        for (int r = 0; r < 4; ++r) {
            float val = acc[jt][r];
            float pv  = __shfl_xor(val, 1);
            if ((lane & 1) == 0) {
                int gr = r0 + w * 16 + fk * 4 + r;
                if (gr < N)
                    xb[(size_t)gr * 64 + jt * 8 + (fr >> 1)] = packbf(val, pv);
            }
        }
    }
}

// ---------------------------------------------------------------------------
// GEMM2 (MFMA): h = leakyrelu(a*x + b) @ Wg^T -> fp8(e4m3) hb; BN-final inline.
__global__ __launch_bounds__(256) void k_h(const uint* __restrict__ xb,
                                           const uint* __restrict__ Wb,
                                           const float* __restrict__ sums,
                                           const float* __restrict__ gamma,
                                           const float* __restrict__ beta,
                                           float invN,
                                           uint* __restrict__ hb, int N)
{
    __shared__ uint xls[64][68];
    __shared__ float aff[256];
    const int tid  = threadIdx.x;
    const int r0   = blockIdx.x * 64;
    const int lane = tid & 63;
    const int w    = tid >> 6;
    const int fr   = lane & 15;
    const int fk   = lane >> 4;

    if (tid < 128) {
        float mean = sums[tid] * invN;
        float var  = sums[128 + tid] * invN - mean * mean;
        float coef = gamma[tid] * rsqrtf(var + BN_EPS);
        aff[tid]       = coef;
        aff[128 + tid] = beta[tid] - coef * mean;
    }
    __syncthreads();

    #pragma unroll
    for (int it = 0; it < 16; ++it) {
        int flat = it * 256 + tid;
        int row  = flat >> 6;
        int u    = flat & 63;
        int r    = r0 + row;
        uint v   = (r < N) ? xb[(size_t)r * 64 + u] : 0u;
        float y0 = fmaf(aff[2 * u],     bflo(v), aff[128 + 2 * u]);
        float y1 = fmaf(aff[2 * u + 1], bfhi(v), aff[128 + 2 * u + 1]);
        y0 = (y0 >= 0.f) ? y0 : LEAKY * y0;
        y1 = (y1 >= 0.f) ? y1 : LEAKY * y1;
        xls[row][u] = packbf(y0, y1);
    }
    __syncthreads();

    bf16x8 a[4];
    #pragma unroll
    for (int kk = 0; kk < 4; ++kk)
        a[kk] = *reinterpret_cast<const bf16x8*>(&xls[w * 16 + fr][kk * 16 + fk * 4]);

    f32x4 acc[8] = {};
    #pragma unroll
    for (int jt = 0; jt < 8; ++jt) {
        #pragma unroll
        for (int kk = 0; kk < 4; ++kk) {
            bf16x8 b = *reinterpret_cast<const bf16x8*>(
                &Wb[(size_t)(jt * 16 + fr) * 64 + kk * 16 + fk * 4]);
            acc[jt] = __builtin_amdgcn_mfma_f32_16x16x32_bf16(a[kk], b, acc[jt], 0, 0, 0);
        }
    }

    // epilogue: pack 4 cols/uint as fp8 e4m3 via cvt_pk + lane combines
    #pragma unroll
    for (int jt = 0; jt < 8; ++jt) {
        #pragma unroll
        for (int r = 0; r < 4; ++r) {
            float val = acc[jt][r];
            float p1  = __shfl_xor(val, 1);
            uint lo16 = (uint)__builtin_amdgcn_cvt_pk_fp8_f32(val, p1, 0, false) & 0xffffu;
            uint hi16 = __shfl_xor(lo16, 2);
            if ((fr & 3) == 0) {
                int gr = r0 + w * 16 + fk * 4 + r;
                if (gr < N)
                    hb[(size_t)gr * 32 + jt * 4 + (fr >> 2)] = lo16 | (hi16 << 16);
            }
        }
    }
}

// ---------------------------------------------------------------------------
// Gather aggregation: 1 wave/node; lane = 8B chunk (8 fp8 features);
// 4 lane-groups process 4 edges per load instruction. csr = src only.
__global__ __launch_bounds__(256) void k_agg(const uint* __restrict__ hb,
                                             const uint* __restrict__ csr,
                                             const int* __restrict__ offs,
                                             const int* __restrict__ cnt,
                                             const float* __restrict__ dinv,
                                             const float* __restrict__ bg,
                                             float* __restrict__ out, int N)
{
    const int wid  = (blockIdx.x * blockDim.x + threadIdx.x) >> 6;
    const int lane = threadIdx.x & 63;
    if (wid >= N) return;
    const int i = wid;
    const int p = lane & 15;      // 8-B chunk within row (features 8p..8p+7)
    const int q = lane >> 4;      // edge subgroup 0..3
    const float d0 = dinv[i];

    float acc[8] = {};
    const int start = offs[i];
    const int m     = cnt[i];

    for (int base = 0; base < m; base += 64) {
        const int nb = min(64, m - base);
        uint sx = 0; float dj = 0.f;
        if (lane < nb) {
            sx = __builtin_nontemporal_load(&csr[start + base + lane]);
            dj = dinv[sx];
        }
        for (int j = 0; j < nb; j += 8) {
            #pragma unroll
            for (int hh = 0; hh < 2; ++hh) {
                int eidx = j + hh * 4 + q;
                int   s  = __shfl((int)sx, eidx);
                float nr = __shfl(dj, eidx) * d0;
                nr = (eidx < nb) ? nr : 0.f;
                const uint2 v = *reinterpret_cast<const uint2*>(
                    &hb[(size_t)(uint)s * 32 + p * 2]);
                f32x2 f01 = __builtin_amdgcn_cvt_pk_f32_fp8((int)v.x, false);
                f32x2 f23 = __builtin_amdgcn_cvt_pk_f32_fp8((int)v.x, true);
                f32x2 f45 = __builtin_amdgcn_cvt_pk_f32_fp8((int)v.y, false);
                f32x2 f67 = __builtin_amdgcn_cvt_pk_f32_fp8((int)v.y, true);
                acc[0] = fmaf(nr, f01.x, acc[0]);
                acc[1] = fmaf(nr, f01.y, acc[1]);
                acc[2] = fmaf(nr, f23.x, acc[2]);
                acc[3] = fmaf(nr, f23.y, acc[3]);
                acc[4] = fmaf(nr, f45.x, acc[4]);
                acc[5] = fmaf(nr, f45.y, acc[5]);
                acc[6] = fmaf(nr, f67.x, acc[6]);
                acc[7] = fmaf(nr, f67.y, acc[7]);
            }
        }
    }

    #pragma unroll
    for (int r = 0; r < 8; ++r) {
        acc[r] += __shfl_xor(acc[r], 16);
        acc[r] += __shfl_xor(acc[r], 32);
    }

    // self term + bias
    const float self = d0 * d0;
    const uint2 sv = *reinterpret_cast<const uint2*>(&hb[(size_t)i * 32 + p * 2]);
    f32x2 s01 = __builtin_amdgcn_cvt_pk_f32_fp8((int)sv.x, false);
    f32x2 s23 = __builtin_amdgcn_cvt_pk_f32_fp8((int)sv.x, true);
    f32x2 s45 = __builtin_amdgcn_cvt_pk_f32_fp8((int)sv.y, false);
    f32x2 s67 = __builtin_amdgcn_cvt_pk_f32_fp8((int)sv.y, true);
    float4 b0 = *reinterpret_cast<const float4*>(&bg[p * 8]);
    float4 b1 = *reinterpret_cast<const float4*>(&bg[p * 8 + 4]);
    float v0 = fmaf(self, s01.x, acc[0]) + b0.x;
    float v1 = fmaf(self, s01.y, acc[1]) + b0.y;
    float v2 = fmaf(self, s23.x, acc[2]) + b0.z;
    float v3 = fmaf(self, s23.y, acc[3]) + b0.w;
    float v4 = fmaf(self, s45.x, acc[4]) + b1.x;
    float v5 = fmaf(self, s45.y, acc[5]) + b1.y;
    float v6 = fmaf(self, s67.x, acc[6]) + b1.z;
    float v7 = fmaf(self, s67.y, acc[7]) + b1.w;

    // log_softmax over 128 features (distributed across 16 lanes)
    float mx = fmaxf(fmaxf(fmaxf(v0, v1), fmaxf(v2, v3)),
                     fmaxf(fmaxf(v4, v5), fmaxf(v6, v7)));
    #pragma unroll
    for (int o = 8; o > 0; o >>= 1) mx = fmaxf(mx, __shfl_xor(mx, o));
    float sum = __expf(v0 - mx) + __expf(v1 - mx) + __expf(v2 - mx) + __expf(v3 - mx)
              + __expf(v4 - mx) + __expf(v5 - mx) + __expf(v6 - mx) + __expf(v7 - mx);
    #pragma unroll
    for (int o = 8; o > 0; o >>= 1) sum += __shfl_xor(sum, o);
    float ls = mx + __logf(sum);

    if (q == 0) {
        f32x4 o0 = {v0 - ls, v1 - ls, v2 - ls, v3 - ls};
        f32x4 o1 = {v4 - ls, v5 - ls, v6 - ls, v7 - ls};
        __builtin_nontemporal_store(o0, reinterpret_cast<f32x4*>(&out[(size_t)i * 128 + p * 8]));
        __builtin_nontemporal_store(o1, reinterpret_cast<f32x4*>(&out[(size_t)i * 128 + p * 8 + 4]));
    }
}

// ---------------------------------------------------------------------------
extern "C" void kernel_launch(void* const* d_in, const int* in_sizes, int n_in,
                              void* d_out, int out_size, void* d_ws, size_t ws_size,
                              hipStream_t stream)
{
    (void)n_in; (void)out_size; (void)ws_size;
    const float* fea   = (const float*)d_in[0];
    const void*  edges = d_in[1];
    const float* Wlin  = (const float*)d_in[2];
    const float* blin  = (const float*)d_in[3];
    const float* gamma = (const float*)d_in[4];
    const float* beta  = (const float*)d_in[5];
    const float* Wg    = (const float*)d_in[6];
    const float* bg    = (const float*)d_in[7];
    float* out = (float*)d_out;

    const int N    = in_sizes[0] / 128;
    const int E    = in_sizes[1] / 2;
    const int NBUK = (N + 255) >> 8;          // dst buckets (256 nodes each)

    char* p = (char*)d_ws;
    // bins (graph phase, E*4 B) aliases xb (dense phase, N*256 B).
    size_t u0 = (size_t)N * 64 * 4;
    size_t u1 = (size_t)E * 4;
    uint*  xb   = (uint*)p;
    uint*  bins = (uint*)p;    p += (u0 > u1 ? u0 : u1);
    uint*  hb   = (uint*)p;    p += (size_t)N * 32 * 4;   // fp8 h, 128 B/row
    uint*  csr  = (uint*)p;    p += (size_t)E * 4;
    int*   histm = (int*)p;    p += (size_t)NBUK * NBLK * 4;
    float* sums = (float*)p;   p += 256 * 4;
    int*   cnt  = (int*)p;     p += (size_t)N * 4;
    int*   offs = (int*)p;     p += (size_t)N * 4;
    float* dinv = (float*)p;   p += (size_t)N * 4;
    int*   btot = (int*)p;     p += 512 * 4;
    uint*  Wlinb = (uint*)p;   p += 8192 * 4;
    uint*  Wgb   = (uint*)p;   p += 8192 * 4;

    // --- prep (W -> bf16, zero sums) ---
    k_prep<<<64, 256, 0, stream>>>(Wlin, Wg, Wlinb, Wgb, sums);

    // --- graph build ---
    k_bhist<<<NBLK, 256, 0, stream>>>(edges, E, histm, NBUK);
    k_bscan<<<NBUK, 512, 0, stream>>>(histm, btot);
    k_binscatter<<<NBLK, 256, 0, stream>>>(edges, E, histm, btot, bins, NBUK);
    k_csrdeg<<<NBUK, 256, 0, stream>>>(bins, btot, cnt, dinv, offs, csr, N, NBUK);

    // --- dense path (MFMA) ---
    k_lin<<<(N + 63) / 64, 256, 0, stream>>>(fea, Wlinb, blin, xb, sums, N);
    k_h<<<(N + 63) / 64, 256, 0, stream>>>(xb, Wgb, sums, gamma, beta,
                                           1.0f / (float)N, hb, N);

    // --- aggregation + log_softmax ---
    k_agg<<<(N + 3) / 4, 256, 0, stream>>>(hb, csr, offs, cnt, dinv, bg, out, N);
}

// Round 8
// 250.116 us; speedup vs baseline: 3.7943x; 1.0134x over previous
//
#include <hip/hip_runtime.h>
#include <math.h>

#define LEAKY 0.01f
#define BN_EPS 1e-5f
#define NBLK 512          // partition blocks (fixed; histm row length)
#define EBUF 10240        // LDS edge-stage capacity in k_csrdeg (40 KB)

typedef unsigned int uint;
typedef float f32x2 __attribute__((ext_vector_type(2)));
typedef float f32x4 __attribute__((ext_vector_type(4)));
typedef short bf16x8 __attribute__((ext_vector_type(8)));

__device__ __forceinline__ float bflo(uint v) { return __uint_as_float(v << 16); }
__device__ __forceinline__ float bfhi(uint v) { return __uint_as_float(v & 0xffff0000u); }
__device__ __forceinline__ uint packbf(float a, float b) {
    uint ua = __float_as_uint(a), ub = __float_as_uint(b);
    ua += 0x7fffu + ((ua >> 16) & 1u);
    ub += 0x7fffu + ((ub >> 16) & 1u);
    return (ua >> 16) | (ub & 0xffff0000u);
}

// Inline probe: int64 edges have all-zero odd 32-bit words (first 64 checked).
__device__ __forceinline__ int detect_i64(const int* __restrict__ raw) {
    int t = threadIdx.x & 63;
    unsigned long long b = __ballot(raw[2 * t + 1] != 0);
    return b == 0ull;
}

// Per-block exclusive scan of btot[0..NBUK) into bb[0..512) (2 elems/thread).
__device__ __forceinline__ void build_bbase(const int* __restrict__ btot,
                                            int NBUK, int* bb, int* sd)
{
    const int t = threadIdx.x;
    int a0 = (2 * t     < NBUK) ? btot[2 * t]     : 0;
    int a1 = (2 * t + 1 < NBUK) ? btot[2 * t + 1] : 0;
    int s = a0 + a1;
    sd[t] = s;
    __syncthreads();
    for (int o = 1; o < 256; o <<= 1) {
        int u = (t >= o) ? sd[t - o] : 0;
        __syncthreads();
        sd[t] += u;
        __syncthreads();
    }
    int ex = sd[t] - s;
    bb[2 * t]     = ex;
    bb[2 * t + 1] = ex + a0;
    __syncthreads();
}

// ---------------------------------------------------------------------------
// Prep: Wlin, Wg -> bf16-pair arrays; zero sums. 64 blocks x 256.
__global__ __launch_bounds__(256) void k_prep(const float* __restrict__ Wlin,
                                              const float* __restrict__ Wg,
                                              uint* __restrict__ Wlinb,
                                              uint* __restrict__ Wgb,
                                              float* __restrict__ sums)
{
    const int idx = blockIdx.x * 256 + threadIdx.x;
    if (blockIdx.x == 0) sums[threadIdx.x] = 0.f;
    if (idx < 8192) {
        Wlinb[idx] = packbf(Wlin[2 * idx], Wlin[2 * idx + 1]);
    } else {
        int j = idx - 8192;
        Wgb[j] = packbf(Wg[2 * j], Wg[2 * j + 1]);
    }
}

// ---------------------------------------------------------------------------
// Partition pass A: per-block LDS histogram of dst>>8 -> histm[bucket][block].
__global__ __launch_bounds__(256) void k_bhist(const void* __restrict__ edges, int E,
                                               int* __restrict__ histm, int NBUK)
{
    __shared__ int hh[512];
    for (int b = threadIdx.x; b < 512; b += 256) hh[b] = 0;
    const int isI64 = detect_i64((const int*)edges);
    __syncthreads();

    const long long* e64 = (const long long*)edges;
    const int*       e32 = (const int*)edges;
    const int chunk = (E + NBLK - 1) / NBLK;
    const int lo = blockIdx.x * chunk;
    const int hi = min(lo + chunk, E);
    for (int e = lo + threadIdx.x; e < hi; e += 256) {
        int dst = isI64 ? (int)e64[(size_t)E + e] : e32[(size_t)E + e];
        atomicAdd(&hh[dst >> 8], 1);
    }
    __syncthreads();
    for (int b = threadIdx.x; b < NBUK; b += 256)
        histm[(size_t)b * NBLK + blockIdx.x] = hh[b];
}

// Pass A2: per-bucket exclusive scan across blocks; emit bucket totals.
__global__ __launch_bounds__(512) void k_bscan(int* __restrict__ histm,
                                               int* __restrict__ btot)
{
    __shared__ int sd[512];
    const int bkt = blockIdx.x;
    const int t = threadIdx.x;
    int v = histm[(size_t)bkt * NBLK + t];
    sd[t] = v;
    __syncthreads();
    for (int o = 1; o < 512; o <<= 1) {
        int u = (t >= o) ? sd[t - o] : 0;
        __syncthreads();
        sd[t] += u;
        __syncthreads();
    }
    histm[(size_t)bkt * NBLK + t] = sd[t] - v;     // exclusive within bucket
    if (t == 511) btot[bkt] = sd[511];
}

// Pass B: scatter packed (src | dstlow<<24) into dst-bucketed bins.
__global__ __launch_bounds__(256) void k_binscatter(const void* __restrict__ edges, int E,
                                                    const int* __restrict__ histm,
                                                    const int* __restrict__ btot,
                                                    uint* __restrict__ bins, int NBUK)
{
    __shared__ int cur[512];
    __shared__ int bb[512];
    __shared__ int sd[256];
    const int isI64 = detect_i64((const int*)edges);
    build_bbase(btot, NBUK, bb, sd);
    for (int b = threadIdx.x; b < NBUK; b += 256)
        cur[b] = bb[b] + histm[(size_t)b * NBLK + blockIdx.x];
    __syncthreads();

    const long long* e64 = (const long long*)edges;
    const int*       e32 = (const int*)edges;
    const int chunk = (E + NBLK - 1) / NBLK;
    const int lo = blockIdx.x * chunk;
    const int hi = min(lo + chunk, E);
    for (int e = lo + threadIdx.x; e < hi; e += 256) {
        int src, dst;
        if (isI64) { src = (int)e64[e]; dst = (int)e64[(size_t)E + e]; }
        else       { src = e32[e];      dst = e32[(size_t)E + e]; }
        int pos = atomicAdd(&cur[dst >> 8], 1);
        bins[pos] = (uint)src | ((uint)(dst & 255) << 24);
    }
}

// Pass C (merged deg+dinv+offs+CSR): one block per bucket; bins staged in LDS.
__global__ __launch_bounds__(256) void k_csrdeg(const uint* __restrict__ bins,
                                                const int* __restrict__ btot,
                                                int* __restrict__ cnt,
                                                float* __restrict__ dinv,
                                                int* __restrict__ offs,
                                                uint* __restrict__ csr,
                                                int N, int NBUK)
{
    __shared__ uint ebuf[EBUF];
    __shared__ int bb[512];
    __shared__ int sd[256];
    __shared__ int c[256];
    const int bkt = blockIdx.x;
    const int t = threadIdx.x;
    build_bbase(btot, NBUK, bb, sd);
    const int lo    = bb[bkt];
    const int total = btot[bkt];
    c[t] = 0;
    __syncthreads();

    const bool fits = (total <= EBUF);
    for (int i = t; i < total; i += 256) {
        uint e = bins[lo + i];
        if (fits) ebuf[i] = e;
        atomicAdd(&c[e >> 24], 1);
    }
    __syncthreads();

    const int node = (bkt << 8) + t;
    const int deg  = c[t];
    if (node < N) {
        cnt[node]  = deg;
        dinv[node] = rsqrtf((float)(deg + 1));
    }
    sd[t] = deg;
    __syncthreads();
    for (int o = 1; o < 256; o <<= 1) {
        int u = (t >= o) ? sd[t - o] : 0;
        __syncthreads();
        sd[t] += u;
        __syncthreads();
    }
    const int off = lo + sd[t] - deg;             // exclusive prefix within bucket
    if (node < N) offs[node] = off;
    c[t] = off;                                   // reuse as write cursor
    __syncthreads();
    for (int i = t; i < total; i += 256) {
        uint e = fits ? ebuf[i] : bins[lo + i];
        int pos = atomicAdd(&c[e >> 24], 1);
        csr[pos] = e & 0x00ffffffu;
    }
}

// ---------------------------------------------------------------------------
// GEMM1 (MFMA): x = fea @ Wlin^T + blin -> bf16 xb; fused BN batch stats.
__global__ __launch_bounds__(256) void k_lin(const float* __restrict__ fea,
                                             const uint* __restrict__ Wb,
                                             const float* __restrict__ bias,
                                             uint* __restrict__ xb,
                                             float* __restrict__ sums, int N)
{
    __shared__ uint xls[64][68];
    __shared__ float sred[16][128];
    __shared__ float qred[16][128];
    const int tid  = threadIdx.x;
    const int r0   = blockIdx.x * 64;
    const int lane = tid & 63;
    const int w    = tid >> 6;
    const int fr   = lane & 15;
    const int fk   = lane >> 4;

    #pragma unroll
    for (int it = 0; it < 8; ++it) {
        int flat = it * 256 + tid;
        int row  = flat >> 5;
        int c4   = flat & 31;
        int r    = r0 + row;
        float4 v = make_float4(0.f, 0.f, 0.f, 0.f);
        if (r < N) v = *reinterpret_cast<const float4*>(&fea[(size_t)r * 128 + c4 * 4]);
        xls[row][c4 * 2]     = packbf(v.x, v.y);
        xls[row][c4 * 2 + 1] = packbf(v.z, v.w);
    }
    __syncthreads();

    bf16x8 a[4];
    #pragma unroll
    for (int kk = 0; kk < 4; ++kk)
        a[kk] = *reinterpret_cast<const bf16x8*>(&xls[w * 16 + fr][kk * 16 + fk * 4]);

    f32x4 acc[8] = {};
    #pragma unroll
    for (int jt = 0; jt < 8; ++jt) {
        #pragma unroll
        for (int kk = 0; kk < 4; ++kk) {
            bf16x8 b = *reinterpret_cast<const bf16x8*>(
                &Wb[(size_t)(jt * 16 + fr) * 64 + kk * 16 + fk * 4]);
            acc[jt] = __builtin_amdgcn_mfma_f32_16x16x32_bf16(a[kk], b, acc[jt], 0, 0, 0);
        }
    }
    __syncthreads();

    #pragma unroll
    for (int jt = 0; jt < 8; ++jt) {
        float bj = bias[jt * 16 + fr];
        float sl = 0.f, ql = 0.f;
        #pragma unroll
        for (int r = 0; r < 4; ++r) {
            int gr = r0 + w * 16 + fk * 4 + r;
            float val = acc[jt][r] + bj;
            val = (gr < N) ? val : 0.f;
            acc[jt][r] = val;
            sl += val; ql += val * val;
        }
        sred[w * 4 + fk][jt * 16 + fr] = sl;
        qred[w * 4 + fk][jt * 16 + fr] = ql;
    }
    __syncthreads();
    if (tid < 128) {
        float S = 0.f, Q = 0.f;
        #pragma unroll
        for (int g = 0; g < 16; ++g) { S += sred[g][tid]; Q += qred[g][tid]; }
        atomicAdd(&sums[tid], S);
        atomicAdd(&sums[128 + tid], Q);
    }
    #pragma unroll
    for (int jt = 0; jt < 8; ++jt) {
        #pragma unroll
        for (int r = 0; r < 4; ++r) {
            float val = acc[jt][r];
            float pv  = __shfl_xor(val, 1);
            if ((lane & 1) == 0) {
                int gr = r0 + w * 16 + fk * 4 + r;
                if (gr < N)
                    xb[(size_t)gr * 64 + jt * 8 + (fr >> 1)] = packbf(val, pv);
            }
        }
    }
}

// ---------------------------------------------------------------------------
// GEMM2 (MFMA): h' = dinv * (leakyrelu(a*x + b) @ Wg^T) -> fp8(e4m3) hb.
// dinv pre-scaling folds the src-side norm into the stored rows.
__global__ __launch_bounds__(256) void k_h(const uint* __restrict__ xb,
                                           const uint* __restrict__ Wb,
                                           const float* __restrict__ sums,
                                           const float* __restrict__ gamma,
                                           const float* __restrict__ beta,
                                           const float* __restrict__ dinv,
                                           float invN,
                                           uint* __restrict__ hb, int N)
{
    __shared__ uint xls[64][68];
    __shared__ float aff[256];
    const int tid  = threadIdx.x;
    const int r0   = blockIdx.x * 64;
    const int lane = tid & 63;
    const int w    = tid >> 6;
    const int fr   = lane & 15;
    const int fk   = lane >> 4;

    if (tid < 128) {
        float mean = sums[tid] * invN;
        float var  = sums[128 + tid] * invN - mean * mean;
        float coef = gamma[tid] * rsqrtf(var + BN_EPS);
        aff[tid]       = coef;
        aff[128 + tid] = beta[tid] - coef * mean;
    }
    __syncthreads();

    #pragma unroll
    for (int it = 0; it < 16; ++it) {
        int flat = it * 256 + tid;
        int row  = flat >> 6;
        int u    = flat & 63;
        int r    = r0 + row;
        uint v   = (r < N) ? xb[(size_t)r * 64 + u] : 0u;
        float y0 = fmaf(aff[2 * u],     bflo(v), aff[128 + 2 * u]);
        float y1 = fmaf(aff[2 * u + 1], bfhi(v), aff[128 + 2 * u + 1]);
        y0 = (y0 >= 0.f) ? y0 : LEAKY * y0;
        y1 = (y1 >= 0.f) ? y1 : LEAKY * y1;
        xls[row][u] = packbf(y0, y1);
    }
    __syncthreads();

    bf16x8 a[4];
    #pragma unroll
    for (int kk = 0; kk < 4; ++kk)
        a[kk] = *reinterpret_cast<const bf16x8*>(&xls[w * 16 + fr][kk * 16 + fk * 4]);

    f32x4 acc[8] = {};
    #pragma unroll
    for (int jt = 0; jt < 8; ++jt) {
        #pragma unroll
        for (int kk = 0; kk < 4; ++kk) {
            bf16x8 b = *reinterpret_cast<const bf16x8*>(
                &Wb[(size_t)(jt * 16 + fr) * 64 + kk * 16 + fk * 4]);
            acc[jt] = __builtin_amdgcn_mfma_f32_16x16x32_bf16(a[kk], b, acc[jt], 0, 0, 0);
        }
    }

    float dv[4];
    #pragma unroll
    for (int r = 0; r < 4; ++r) {
        int gr = r0 + w * 16 + fk * 4 + r;
        dv[r] = (gr < N) ? dinv[gr] : 0.f;
    }

    // epilogue: scale by dinv[row], pack 4 cols/uint as fp8 e4m3
    #pragma unroll
    for (int jt = 0; jt < 8; ++jt) {
        #pragma unroll
        for (int r = 0; r < 4; ++r) {
            float val = acc[jt][r] * dv[r];
            float p1  = __shfl_xor(val, 1);
            uint lo16 = (uint)__builtin_amdgcn_cvt_pk_fp8_f32(val, p1, 0, false) & 0xffffu;
            uint hi16 = __shfl_xor(lo16, 2);
            if ((fr & 3) == 0) {
                int gr = r0 + w * 16 + fk * 4 + r;
                if (gr < N)
                    hb[(size_t)gr * 32 + jt * 4 + (fr >> 2)] = lo16 | (hi16 << 16);
            }
        }
    }
}

// ---------------------------------------------------------------------------
// Gather aggregation: out[i] = dinv[i]*(sum h'[src] + h'[i]) + bg, log_softmax.
// 1 wave/node; lane = 8B chunk (8 fp8 features); 4 lane-groups, 4 edges/instr.
__global__ __launch_bounds__(256) void k_agg(const uint* __restrict__ hb,
                                             const uint* __restrict__ csr,
                                             const int* __restrict__ offs,
                                             const int* __restrict__ cnt,
                                             const float* __restrict__ dinv,
                                             const float* __restrict__ bg,
                                             float* __restrict__ out, int N)
{
    const int wid  = (blockIdx.x * blockDim.x + threadIdx.x) >> 6;
    const int lane = threadIdx.x & 63;
    if (wid >= N) return;
    const int i = wid;
    const int p = lane & 15;      // 8-B chunk within row (features 8p..8p+7)
    const int q = lane >> 4;      // edge subgroup 0..3

    f32x2 acc[4] = {};
    const int start = offs[i];
    const int m     = cnt[i];

    for (int base = 0; base < m; base += 64) {
        const int nb = min(64, m - base);
        uint sx = 0;
        if (lane < nb)
            sx = __builtin_nontemporal_load(&csr[start + base + lane]);
        for (int j = 0; j < nb; j += 8) {
            #pragma unroll
            for (int hh = 0; hh < 2; ++hh) {
                int eidx = j + hh * 4 + q;
                int   s  = __shfl((int)sx, eidx);
                float msk = (eidx < nb) ? 1.f : 0.f;
                const uint2 v = *reinterpret_cast<const uint2*>(
                    &hb[(size_t)(uint)s * 32 + p * 2]);
                f32x2 f01 = __builtin_amdgcn_cvt_pk_f32_fp8((int)v.x, false);
                f32x2 f23 = __builtin_amdgcn_cvt_pk_f32_fp8((int)v.x, true);
                f32x2 f45 = __builtin_amdgcn_cvt_pk_f32_fp8((int)v.y, false);
                f32x2 f67 = __builtin_amdgcn_cvt_pk_f32_fp8((int)v.y, true);
                acc[0] += f01 * msk;
                acc[1] += f23 * msk;
                acc[2] += f45 * msk;
                acc[3] += f67 * msk;
            }
        }
    }

    // reduce the 4 edge subgroups
    #pragma unroll
    for (int r = 0; r < 4; ++r) {
        acc[r].x += __shfl_xor(acc[r].x, 16);
        acc[r].y += __shfl_xor(acc[r].y, 16);
        acc[r].x += __shfl_xor(acc[r].x, 32);
        acc[r].y += __shfl_xor(acc[r].y, 32);
    }

    // self term (h'[i]), then scale by dinv[i], add bias
    const uint2 sv = *reinterpret_cast<const uint2*>(&hb[(size_t)i * 32 + p * 2]);
    f32x2 s01 = __builtin_amdgcn_cvt_pk_f32_fp8((int)sv.x, false);
    f32x2 s23 = __builtin_amdgcn_cvt_pk_f32_fp8((int)sv.x, true);
    f32x2 s45 = __builtin_amdgcn_cvt_pk_f32_fp8((int)sv.y, false);
    f32x2 s67 = __builtin_amdgcn_cvt_pk_f32_fp8((int)sv.y, true);
    acc[0] += s01; acc[1] += s23; acc[2] += s45; acc[3] += s67;

    const float d0 = dinv[i];
    float4 b0 = *reinterpret_cast<const float4*>(&bg[p * 8]);
    float4 b1 = *reinterpret_cast<const float4*>(&bg[p * 8 + 4]);
    float v0 = fmaf(d0, acc[0].x, b0.x);
    float v1 = fmaf(d0, acc[0].y, b0.y);
    float v2 = fmaf(d0, acc[1].x, b0.z);
    float v3 = fmaf(d0, acc[1].y, b0.w);
    float v4 = fmaf(d0, acc[2].x, b1.x);
    float v5 = fmaf(d0, acc[2].y, b1.y);
    float v6 = fmaf(d0, acc[3].x, b1.z);
    float v7 = fmaf(d0, acc[3].y, b1.w);

    // log_softmax over 128 features (distributed across 16 lanes)
    float mx = fmaxf(fmaxf(fmaxf(v0, v1), fmaxf(v2, v3)),
                     fmaxf(fmaxf(v4, v5), fmaxf(v6, v7)));
    #pragma unroll
    for (int o = 8; o > 0; o >>= 1) mx = fmaxf(mx, __shfl_xor(mx, o));
    float sum = __expf(v0 - mx) + __expf(v1 - mx) + __expf(v2 - mx) + __expf(v3 - mx)
              + __expf(v4 - mx) + __expf(v5 - mx) + __expf(v6 - mx) + __expf(v7 - mx);
    #pragma unroll
    for (int o = 8; o > 0; o >>= 1) sum += __shfl_xor(sum, o);
    float ls = mx + __logf(sum);

    if (q == 0) {
        f32x4 o0 = {v0 - ls, v1 - ls, v2 - ls, v3 - ls};
        f32x4 o1 = {v4 - ls, v5 - ls, v6 - ls, v7 - ls};
        __builtin_nontemporal_store(o0, reinterpret_cast<f32x4*>(&out[(size_t)i * 128 + p * 8]));
        __builtin_nontemporal_store(o1, reinterpret_cast<f32x4*>(&out[(size_t)i * 128 + p * 8 + 4]));
    }
}

// ---------------------------------------------------------------------------
extern "C" void kernel_launch(void* const* d_in, const int* in_sizes, int n_in,
                              void* d_out, int out_size, void* d_ws, size_t ws_size,
                              hipStream_t stream)
{
    (void)n_in; (void)out_size; (void)ws_size;
    const float* fea   = (const float*)d_in[0];
    const void*  edges = d_in[1];
    const float* Wlin  = (const float*)d_in[2];
    const float* blin  = (const float*)d_in[3];
    const float* gamma = (const float*)d_in[4];
    const float* beta  = (const float*)d_in[5];
    const float* Wg    = (const float*)d_in[6];
    const float* bg    = (const float*)d_in[7];
    float* out = (float*)d_out;

    const int N    = in_sizes[0] / 128;
    const int E    = in_sizes[1] / 2;
    const int NBUK = (N + 255) >> 8;          // dst buckets (256 nodes each)

    char* p = (char*)d_ws;
    // bins (graph phase, E*4 B) aliases xb (dense phase, N*256 B).
    size_t u0 = (size_t)N * 64 * 4;
    size_t u1 = (size_t)E * 4;
    uint*  xb   = (uint*)p;
    uint*  bins = (uint*)p;    p += (u0 > u1 ? u0 : u1);
    uint*  hb   = (uint*)p;    p += (size_t)N * 32 * 4;   // fp8 h', 128 B/row
    uint*  csr  = (uint*)p;    p += (size_t)E * 4;
    int*   histm = (int*)p;    p += (size_t)NBUK * NBLK * 4;
    float* sums = (float*)p;   p += 256 * 4;
    int*   cnt  = (int*)p;     p += (size_t)N * 4;
    int*   offs = (int*)p;     p += (size_t)N * 4;
    float* dinv = (float*)p;   p += (size_t)N * 4;
    int*   btot = (int*)p;     p += 512 * 4;
    uint*  Wlinb = (uint*)p;   p += 8192 * 4;
    uint*  Wgb   = (uint*)p;   p += 8192 * 4;

    // --- prep (W -> bf16, zero sums) ---
    k_prep<<<64, 256, 0, stream>>>(Wlin, Wg, Wlinb, Wgb, sums);

    // --- graph build ---
    k_bhist<<<NBLK, 256, 0, stream>>>(edges, E, histm, NBUK);
    k_bscan<<<NBUK, 512, 0, stream>>>(histm, btot);
    k_binscatter<<<NBLK, 256, 0, stream>>>(edges, E, histm, btot, bins, NBUK);
    k_csrdeg<<<NBUK, 256, 0, stream>>>(bins, btot, cnt, dinv, offs, csr, N, NBUK);

    // --- dense path (MFMA) ---
    k_lin<<<(N + 63) / 64, 256, 0, stream>>>(fea, Wlinb, blin, xb, sums, N);
    k_h<<<(N + 63) / 64, 256, 0, stream>>>(xb, Wgb, sums, gamma, beta, dinv,
                                           1.0f / (float)N, hb, N);

    // --- aggregation + log_softmax ---
    k_agg<<<(N + 3) / 4, 256, 0, stream>>>(hb, csr, offs, cnt, dinv, bg, out, N);
}

// Round 9
// 244.356 us; speedup vs baseline: 3.8837x; 1.0236x over previous
//
#include <hip/hip_runtime.h>
#include <math.h>

#define LEAKY 0.01f
#define BN_EPS 1e-5f
#define NBLK 512          // partition blocks (fixed; histm row length)
#define EBUF 10240        // LDS edge-stage capacity in k_csrdeg (40 KB)

typedef unsigned int uint;
typedef float f32x2 __attribute__((ext_vector_type(2)));
typedef float f32x4 __attribute__((ext_vector_type(4)));
typedef short bf16x8 __attribute__((ext_vector_type(8)));

__device__ __forceinline__ float bflo(uint v) { return __uint_as_float(v << 16); }
__device__ __forceinline__ float bfhi(uint v) { return __uint_as_float(v & 0xffff0000u); }
__device__ __forceinline__ uint packbf(float a, float b) {
    uint ua = __float_as_uint(a), ub = __float_as_uint(b);
    ua += 0x7fffu + ((ua >> 16) & 1u);
    ub += 0x7fffu + ((ub >> 16) & 1u);
    return (ua >> 16) | (ub & 0xffff0000u);
}

// Inline probe: int64 edges have all-zero odd 32-bit words (first 64 checked).
__device__ __forceinline__ int detect_i64(const int* __restrict__ raw) {
    int t = threadIdx.x & 63;
    unsigned long long b = __ballot(raw[2 * t + 1] != 0);
    return b == 0ull;
}

// Per-block exclusive scan of btot[0..NBUK) into bb[0..512) (2 elems/thread).
__device__ __forceinline__ void build_bbase(const int* __restrict__ btot,
                                            int NBUK, int* bb, int* sd)
{
    const int t = threadIdx.x;
    int a0 = (2 * t     < NBUK) ? btot[2 * t]     : 0;
    int a1 = (2 * t + 1 < NBUK) ? btot[2 * t + 1] : 0;
    int s = a0 + a1;
    sd[t] = s;
    __syncthreads();
    for (int o = 1; o < 256; o <<= 1) {
        int u = (t >= o) ? sd[t - o] : 0;
        __syncthreads();
        sd[t] += u;
        __syncthreads();
    }
    int ex = sd[t] - s;
    bb[2 * t]     = ex;
    bb[2 * t + 1] = ex + a0;
    __syncthreads();
}

// ---------------------------------------------------------------------------
// Prep: Wlin, Wg -> bf16-pair arrays; zero sums. 64 blocks x 256.
__global__ __launch_bounds__(256) void k_prep(const float* __restrict__ Wlin,
                                              const float* __restrict__ Wg,
                                              uint* __restrict__ Wlinb,
                                              uint* __restrict__ Wgb,
                                              float* __restrict__ sums)
{
    const int idx = blockIdx.x * 256 + threadIdx.x;
    if (blockIdx.x == 0) sums[threadIdx.x] = 0.f;
    if (idx < 8192) {
        Wlinb[idx] = packbf(Wlin[2 * idx], Wlin[2 * idx + 1]);
    } else {
        int j = idx - 8192;
        Wgb[j] = packbf(Wg[2 * j], Wg[2 * j + 1]);
    }
}

// ---------------------------------------------------------------------------
// Fused front: blocks [0,G_lin) = GEMM1 (MFMA, x=fea@Wlin^T+blin -> bf16 xb,
// fused BN stats); blocks [G_lin, G_lin+NBLK) = dst-bucket histogram (bhist).
__global__ __launch_bounds__(256) void k_front(const float* __restrict__ fea,
                                               const uint* __restrict__ Wb,
                                               const float* __restrict__ bias,
                                               uint* __restrict__ xb,
                                               float* __restrict__ sums,
                                               const void* __restrict__ edges, int E,
                                               int* __restrict__ histm,
                                               int NBUK, int N, int G_lin)
{
    __shared__ uint smem[4352];       // 17408 B: lin x-tile / bhist hist
    const int tid = threadIdx.x;

    if ((int)blockIdx.x >= G_lin) {
        // ---- bhist role ----
        const int bid = blockIdx.x - G_lin;
        int* hh = (int*)smem;
        for (int b = tid; b < 512; b += 256) hh[b] = 0;
        const int isI64 = detect_i64((const int*)edges);
        __syncthreads();
        const long long* e64 = (const long long*)edges;
        const int*       e32 = (const int*)edges;
        const int chunk = (E + NBLK - 1) / NBLK;
        const int lo = bid * chunk;
        const int hi = min(lo + chunk, E);
        for (int e = lo + tid; e < hi; e += 256) {
            int dst = isI64 ? (int)e64[(size_t)E + e] : e32[(size_t)E + e];
            atomicAdd(&hh[dst >> 8], 1);
        }
        __syncthreads();
        for (int b = tid; b < NBUK; b += 256)
            histm[(size_t)b * NBLK + bid] = hh[b];
        return;
    }

    // ---- lin role ----
    const int r0   = blockIdx.x * 64;
    const int lane = tid & 63;
    const int w    = tid >> 6;
    const int fr   = lane & 15;
    const int fk   = lane >> 4;

    #pragma unroll
    for (int it = 0; it < 8; ++it) {
        int flat = it * 256 + tid;
        int row  = flat >> 5;
        int c4   = flat & 31;
        int r    = r0 + row;
        float4 v = make_float4(0.f, 0.f, 0.f, 0.f);
        if (r < N) v = *reinterpret_cast<const float4*>(&fea[(size_t)r * 128 + c4 * 4]);
        smem[row * 68 + c4 * 2]     = packbf(v.x, v.y);
        smem[row * 68 + c4 * 2 + 1] = packbf(v.z, v.w);
    }
    __syncthreads();

    bf16x8 a[4];
    #pragma unroll
    for (int kk = 0; kk < 4; ++kk)
        a[kk] = *reinterpret_cast<const bf16x8*>(
            &smem[(w * 16 + fr) * 68 + kk * 16 + fk * 4]);

    f32x4 acc[8] = {};
    #pragma unroll
    for (int jt = 0; jt < 8; ++jt) {
        #pragma unroll
        for (int kk = 0; kk < 4; ++kk) {
            bf16x8 b = *reinterpret_cast<const bf16x8*>(
                &Wb[(size_t)(jt * 16 + fr) * 64 + kk * 16 + fk * 4]);
            acc[jt] = __builtin_amdgcn_mfma_f32_16x16x32_bf16(a[kk], b, acc[jt], 0, 0, 0);
        }
    }
    __syncthreads();                  // x-tile dead; reuse smem for stats

    float* sred = (float*)smem;       // [16][128]
    float* qred = sred + 2048;        // [16][128]
    #pragma unroll
    for (int jt = 0; jt < 8; ++jt) {
        float bj = bias[jt * 16 + fr];
        float sl = 0.f, ql = 0.f;
        #pragma unroll
        for (int r = 0; r < 4; ++r) {
            int gr = r0 + w * 16 + fk * 4 + r;
            float val = acc[jt][r] + bj;
            val = (gr < N) ? val : 0.f;
            acc[jt][r] = val;
            sl += val; ql += val * val;
        }
        sred[(w * 4 + fk) * 128 + jt * 16 + fr] = sl;
        qred[(w * 4 + fk) * 128 + jt * 16 + fr] = ql;
    }
    __syncthreads();
    if (tid < 128) {
        float S = 0.f, Q = 0.f;
        #pragma unroll
        for (int g = 0; g < 16; ++g) {
            S += sred[g * 128 + tid];
            Q += qred[g * 128 + tid];
        }
        atomicAdd(&sums[tid], S);
        atomicAdd(&sums[128 + tid], Q);
    }
    #pragma unroll
    for (int jt = 0; jt < 8; ++jt) {
        #pragma unroll
        for (int r = 0; r < 4; ++r) {
            float val = acc[jt][r];
            float pv  = __shfl_xor(val, 1);
            if ((lane & 1) == 0) {
                int gr = r0 + w * 16 + fk * 4 + r;
                if (gr < N)
                    xb[(size_t)gr * 64 + jt * 8 + (fr >> 1)] = packbf(val, pv);
            }
        }
    }
}

// ---------------------------------------------------------------------------
// Pass A2: per-bucket exclusive scan across blocks; emit bucket totals.
__global__ __launch_bounds__(512) void k_bscan(int* __restrict__ histm,
                                               int* __restrict__ btot)
{
    __shared__ int sd[512];
    const int bkt = blockIdx.x;
    const int t = threadIdx.x;
    int v = histm[(size_t)bkt * NBLK + t];
    sd[t] = v;
    __syncthreads();
    for (int o = 1; o < 512; o <<= 1) {
        int u = (t >= o) ? sd[t - o] : 0;
        __syncthreads();
        sd[t] += u;
        __syncthreads();
    }
    histm[(size_t)bkt * NBLK + t] = sd[t] - v;     // exclusive within bucket
    if (t == 511) btot[bkt] = sd[511];
}

// Pass B: scatter packed (src | dstlow<<24) into dst-bucketed bins.
__global__ __launch_bounds__(256) void k_binscatter(const void* __restrict__ edges, int E,
                                                    const int* __restrict__ histm,
                                                    const int* __restrict__ btot,
                                                    uint* __restrict__ bins, int NBUK)
{
    __shared__ int cur[512];
    __shared__ int bb[512];
    __shared__ int sd[256];
    const int isI64 = detect_i64((const int*)edges);
    build_bbase(btot, NBUK, bb, sd);
    for (int b = threadIdx.x; b < NBUK; b += 256)
        cur[b] = bb[b] + histm[(size_t)b * NBLK + blockIdx.x];
    __syncthreads();

    const long long* e64 = (const long long*)edges;
    const int*       e32 = (const int*)edges;
    const int chunk = (E + NBLK - 1) / NBLK;
    const int lo = blockIdx.x * chunk;
    const int hi = min(lo + chunk, E);
    for (int e = lo + threadIdx.x; e < hi; e += 256) {
        int src, dst;
        if (isI64) { src = (int)e64[e]; dst = (int)e64[(size_t)E + e]; }
        else       { src = e32[e];      dst = e32[(size_t)E + e]; }
        int pos = atomicAdd(&cur[dst >> 8], 1);
        bins[pos] = (uint)src | ((uint)(dst & 255) << 24);
    }
}

// Pass C (merged deg+dinv+offs+CSR, 8-padded): one block per bucket.
// Each node's csr list is padded to a multiple of 8 with dummy id N (zero row).
__global__ __launch_bounds__(256) void k_csrdeg(const uint* __restrict__ bins,
                                                const int* __restrict__ btot,
                                                int* __restrict__ pcnt,
                                                float* __restrict__ dinv,
                                                int* __restrict__ offs,
                                                uint* __restrict__ csr,
                                                int N, int NBUK)
{
    __shared__ uint ebuf[EBUF];
    __shared__ int bb[512];
    __shared__ int sd[256];
    __shared__ int c[256];
    const int bkt = blockIdx.x;
    const int t = threadIdx.x;
    build_bbase(btot, NBUK, bb, sd);
    const int lo    = bb[bkt];
    const int total = btot[bkt];
    c[t] = 0;
    __syncthreads();

    const bool fits = (total <= EBUF);
    for (int i = t; i < total; i += 256) {
        uint e = bins[lo + i];
        if (fits) ebuf[i] = e;
        atomicAdd(&c[e >> 24], 1);
    }
    __syncthreads();

    const int node = (bkt << 8) + t;
    const int deg  = c[t];
    const int pdeg = (deg + 7) & ~7;              // pad to multiple of 8
    if (node < N) {
        pcnt[node] = pdeg;
        dinv[node] = rsqrtf((float)(deg + 1));
    }
    sd[t] = pdeg;
    __syncthreads();
    for (int o = 1; o < 256; o <<= 1) {
        int u = (t >= o) ? sd[t - o] : 0;
        __syncthreads();
        sd[t] += u;
        __syncthreads();
    }
    // padded bucket base: unpadded base + bkt*2048 (max pad 256*7 < 2048)
    const int myoff = lo + (bkt << 11) + sd[t] - pdeg;
    if (node < N) offs[node] = myoff;
    c[t] = myoff;                                 // reuse as write cursor
    __syncthreads();
    for (int i = t; i < total; i += 256) {
        uint e = fits ? ebuf[i] : bins[lo + i];
        int pos = atomicAdd(&c[e >> 24], 1);
        csr[pos] = e & 0x00ffffffu;
    }
    // padding slots -> dummy node N (its hb row is all zeros)
    for (int k2 = deg; k2 < pdeg; ++k2)
        csr[myoff + k2] = (uint)N;
}

// ---------------------------------------------------------------------------
// GEMM2 (MFMA): h' = dinv * (leakyrelu(a*x + b) @ Wg^T) -> fp8(e4m3) hb.
// Also writes the all-zero dummy row N.
__global__ __launch_bounds__(256) void k_h(const uint* __restrict__ xb,
                                           const uint* __restrict__ Wb,
                                           const float* __restrict__ sums,
                                           const float* __restrict__ gamma,
                                           const float* __restrict__ beta,
                                           const float* __restrict__ dinv,
                                           float invN,
                                           uint* __restrict__ hb, int N)
{
    __shared__ uint xls[64][68];
    __shared__ float aff[256];
    const int tid  = threadIdx.x;
    const int r0   = blockIdx.x * 64;
    const int lane = tid & 63;
    const int w    = tid >> 6;
    const int fr   = lane & 15;
    const int fk   = lane >> 4;

    if (tid < 128) {
        float mean = sums[tid] * invN;
        float var  = sums[128 + tid] * invN - mean * mean;
        float coef = gamma[tid] * rsqrtf(var + BN_EPS);
        aff[tid]       = coef;
        aff[128 + tid] = beta[tid] - coef * mean;
    }
    __syncthreads();

    #pragma unroll
    for (int it = 0; it < 16; ++it) {
        int flat = it * 256 + tid;
        int row  = flat >> 6;
        int u    = flat & 63;
        int r    = r0 + row;
        uint v   = (r < N) ? xb[(size_t)r * 64 + u] : 0u;
        float y0 = fmaf(aff[2 * u],     bflo(v), aff[128 + 2 * u]);
        float y1 = fmaf(aff[2 * u + 1], bfhi(v), aff[128 + 2 * u + 1]);
        y0 = (y0 >= 0.f) ? y0 : LEAKY * y0;
        y1 = (y1 >= 0.f) ? y1 : LEAKY * y1;
        xls[row][u] = packbf(y0, y1);
    }
    __syncthreads();

    bf16x8 a[4];
    #pragma unroll
    for (int kk = 0; kk < 4; ++kk)
        a[kk] = *reinterpret_cast<const bf16x8*>(&xls[w * 16 + fr][kk * 16 + fk * 4]);

    f32x4 acc[8] = {};
    #pragma unroll
    for (int jt = 0; jt < 8; ++jt) {
        #pragma unroll
        for (int kk = 0; kk < 4; ++kk) {
            bf16x8 b = *reinterpret_cast<const bf16x8*>(
                &Wb[(size_t)(jt * 16 + fr) * 64 + kk * 16 + fk * 4]);
            acc[jt] = __builtin_amdgcn_mfma_f32_16x16x32_bf16(a[kk], b, acc[jt], 0, 0, 0);
        }
    }

    float dv[4];
    #pragma unroll
    for (int r = 0; r < 4; ++r) {
        int gr = r0 + w * 16 + fk * 4 + r;
        dv[r] = (gr < N) ? dinv[gr] : 0.f;        // row N (and beyond) -> 0
    }

    // epilogue: scale by dinv[row], pack 4 cols/uint as fp8 e4m3
    #pragma unroll
    for (int jt = 0; jt < 8; ++jt) {
        #pragma unroll
        for (int r = 0; r < 4; ++r) {
            float val = acc[jt][r] * dv[r];
            float p1  = __shfl_xor(val, 1);
            uint lo16 = (uint)__builtin_amdgcn_cvt_pk_fp8_f32(val, p1, 0, false) & 0xffffu;
            uint hi16 = __shfl_xor(lo16, 2);
            if ((fr & 3) == 0) {
                int gr = r0 + w * 16 + fk * 4 + r;
                if (gr <= N)                       // include zero row N
                    hb[(size_t)gr * 32 + jt * 4 + (fr >> 2)] = lo16 | (hi16 << 16);
            }
        }
    }
}

// ---------------------------------------------------------------------------
// Gather aggregation: out[i] = dinv[i]*(sum h'[src] + h'[i]) + bg, log_softmax.
// Maskless inner loop (edge lists padded to x8 with zero-row ids).
__global__ __launch_bounds__(256) void k_agg(const uint* __restrict__ hb,
                                             const uint* __restrict__ csr,
                                             const int* __restrict__ offs,
                                             const int* __restrict__ pcnt,
                                             const float* __restrict__ dinv,
                                             const float* __restrict__ bg,
                                             float* __restrict__ out, int N)
{
    const int wid  = (blockIdx.x * blockDim.x + threadIdx.x) >> 6;
    const int lane = threadIdx.x & 63;
    if (wid >= N) return;
    const int i = wid;
    const int p = lane & 15;      // 8-B chunk within row (features 8p..8p+7)
    const int q = lane >> 4;      // edge subgroup 0..3
    const uint2* hbp = reinterpret_cast<const uint2*>(hb) + p;

    f32x2 acc[4] = {};
    const int start = offs[i];
    const int m     = pcnt[i];    // multiple of 8

    for (int base = 0; base < m; base += 64) {
        const int nb = min(64, m - base);          // multiple of 8
        uint sx = (uint)N;
        if (lane < nb)
            sx = __builtin_nontemporal_load(&csr[start + base + lane]);
        for (int j = 0; j < nb; j += 8) {
            #pragma unroll
            for (int hh = 0; hh < 2; ++hh) {
                int s = __shfl((int)sx, j + hh * 4 + q);
                const uint2 v = hbp[(uint)s * 16];
                acc[0] += __builtin_amdgcn_cvt_pk_f32_fp8((int)v.x, false);
                acc[1] += __builtin_amdgcn_cvt_pk_f32_fp8((int)v.x, true);
                acc[2] += __builtin_amdgcn_cvt_pk_f32_fp8((int)v.y, false);
                acc[3] += __builtin_amdgcn_cvt_pk_f32_fp8((int)v.y, true);
            }
        }
    }

    // reduce the 4 edge subgroups
    #pragma unroll
    for (int r = 0; r < 4; ++r) {
        acc[r].x += __shfl_xor(acc[r].x, 16);
        acc[r].y += __shfl_xor(acc[r].y, 16);
        acc[r].x += __shfl_xor(acc[r].x, 32);
        acc[r].y += __shfl_xor(acc[r].y, 32);
    }

    // self term (h'[i]), then scale by dinv[i], add bias
    const uint2 sv = hbp[(uint)i * 16];
    acc[0] += __builtin_amdgcn_cvt_pk_f32_fp8((int)sv.x, false);
    acc[1] += __builtin_amdgcn_cvt_pk_f32_fp8((int)sv.x, true);
    acc[2] += __builtin_amdgcn_cvt_pk_f32_fp8((int)sv.y, false);
    acc[3] += __builtin_amdgcn_cvt_pk_f32_fp8((int)sv.y, true);

    const float d0 = dinv[i];
    float4 b0 = *reinterpret_cast<const float4*>(&bg[p * 8]);
    float4 b1 = *reinterpret_cast<const float4*>(&bg[p * 8 + 4]);
    float v0 = fmaf(d0, acc[0].x, b0.x);
    float v1 = fmaf(d0, acc[0].y, b0.y);
    float v2 = fmaf(d0, acc[1].x, b0.z);
    float v3 = fmaf(d0, acc[1].y, b0.w);
    float v4 = fmaf(d0, acc[2].x, b1.x);
    float v5 = fmaf(d0, acc[2].y, b1.y);
    float v6 = fmaf(d0, acc[3].x, b1.z);
    float v7 = fmaf(d0, acc[3].y, b1.w);

    // log_softmax over 128 features (distributed across 16 lanes)
    float mx = fmaxf(fmaxf(fmaxf(v0, v1), fmaxf(v2, v3)),
                     fmaxf(fmaxf(v4, v5), fmaxf(v6, v7)));
    #pragma unroll
    for (int o = 8; o > 0; o >>= 1) mx = fmaxf(mx, __shfl_xor(mx, o));
    float sum = __expf(v0 - mx) + __expf(v1 - mx) + __expf(v2 - mx) + __expf(v3 - mx)
              + __expf(v4 - mx) + __expf(v5 - mx) + __expf(v6 - mx) + __expf(v7 - mx);
    #pragma unroll
    for (int o = 8; o > 0; o >>= 1) sum += __shfl_xor(sum, o);
    float ls = mx + __logf(sum);

    if (q == 0) {
        f32x4 o0 = {v0 - ls, v1 - ls, v2 - ls, v3 - ls};
        f32x4 o1 = {v4 - ls, v5 - ls, v6 - ls, v7 - ls};
        __builtin_nontemporal_store(o0, reinterpret_cast<f32x4*>(&out[(size_t)i * 128 + p * 8]));
        __builtin_nontemporal_store(o1, reinterpret_cast<f32x4*>(&out[(size_t)i * 128 + p * 8 + 4]));
    }
}

// ---------------------------------------------------------------------------
extern "C" void kernel_launch(void* const* d_in, const int* in_sizes, int n_in,
                              void* d_out, int out_size, void* d_ws, size_t ws_size,
                              hipStream_t stream)
{
    (void)n_in; (void)out_size; (void)ws_size;
    const float* fea   = (const float*)d_in[0];
    const void*  edges = d_in[1];
    const float* Wlin  = (const float*)d_in[2];
    const float* blin  = (const float*)d_in[3];
    const float* gamma = (const float*)d_in[4];
    const float* beta  = (const float*)d_in[5];
    const float* Wg    = (const float*)d_in[6];
    const float* bg    = (const float*)d_in[7];
    float* out = (float*)d_out;

    const int N    = in_sizes[0] / 128;
    const int E    = in_sizes[1] / 2;
    const int NBUK = (N + 255) >> 8;          // dst buckets (256 nodes each)
    const int GLIN = (N + 63) / 64;

    char* p = (char*)d_ws;
    uint*  xb   = (uint*)p;    p += (size_t)N * 64 * 4;
    uint*  bins = (uint*)p;    p += (size_t)E * 4;
    uint*  hb   = (uint*)p;    p += ((size_t)N + 1) * 32 * 4;  // fp8 h' + zero row
    uint*  csr  = (uint*)p;    p += ((size_t)E + ((size_t)NBUK << 11)) * 4;
    int*   histm = (int*)p;    p += (size_t)NBUK * NBLK * 4;
    float* sums = (float*)p;   p += 256 * 4;
    int*   pcnt = (int*)p;     p += (size_t)N * 4;
    int*   offs = (int*)p;     p += (size_t)N * 4;
    float* dinv = (float*)p;   p += (size_t)N * 4;
    int*   btot = (int*)p;     p += 512 * 4;
    uint*  Wlinb = (uint*)p;   p += 8192 * 4;
    uint*  Wgb   = (uint*)p;   p += 8192 * 4;

    // --- prep (W -> bf16, zero sums) ---
    k_prep<<<64, 256, 0, stream>>>(Wlin, Wg, Wlinb, Wgb, sums);

    // --- fused GEMM1 || edge histogram ---
    k_front<<<GLIN + NBLK, 256, 0, stream>>>(fea, Wlinb, blin, xb, sums,
                                             edges, E, histm, NBUK, N, GLIN);

    // --- graph build ---
    k_bscan<<<NBUK, 512, 0, stream>>>(histm, btot);
    k_binscatter<<<NBLK, 256, 0, stream>>>(edges, E, histm, btot, bins, NBUK);
    k_csrdeg<<<NBUK, 256, 0, stream>>>(bins, btot, pcnt, dinv, offs, csr, N, NBUK);

    // --- GEMM2 (covers zero row N) ---
    k_h<<<(N + 64) / 64, 256, 0, stream>>>(xb, Wgb, sums, gamma, beta, dinv,
                                           1.0f / (float)N, hb, N);

    // --- aggregation + log_softmax ---
    k_agg<<<(N + 3) / 4, 256, 0, stream>>>(hb, csr, offs, pcnt, dinv, bg, out, N);
}

// Round 10
// 227.514 us; speedup vs baseline: 4.1712x; 1.0740x over previous
//
#include <hip/hip_runtime.h>
#include <math.h>

#define LEAKY 0.01f
#define BN_EPS 1e-5f
#define NBLK 512          // partition blocks (fixed; histm row length)
#define EBUF 10240        // LDS edge-stage capacity in k_csrdeg (40 KB)

typedef unsigned int uint;
typedef float f32x2 __attribute__((ext_vector_type(2)));
typedef float f32x4 __attribute__((ext_vector_type(4)));
typedef short bf16x8 __attribute__((ext_vector_type(8)));

__device__ __forceinline__ float bflo(uint v) { return __uint_as_float(v << 16); }
__device__ __forceinline__ float bfhi(uint v) { return __uint_as_float(v & 0xffff0000u); }
__device__ __forceinline__ uint packbf(float a, float b) {
    uint ua = __float_as_uint(a), ub = __float_as_uint(b);
    ua += 0x7fffu + ((ua >> 16) & 1u);
    ub += 0x7fffu + ((ub >> 16) & 1u);
    return (ua >> 16) | (ub & 0xffff0000u);
}

// Inline probe: int64 edges have all-zero odd 32-bit words (first 64 checked).
__device__ __forceinline__ int detect_i64(const int* __restrict__ raw) {
    int t = threadIdx.x & 63;
    unsigned long long b = __ballot(raw[2 * t + 1] != 0);
    return b == 0ull;
}

// Per-block exclusive scan of btot[0..NBUK) into bb[0..512) (2 elems/thread).
__device__ __forceinline__ void build_bbase(const int* __restrict__ btot,
                                            int NBUK, int* bb, int* sd)
{
    const int t = threadIdx.x;
    int a0 = (2 * t     < NBUK) ? btot[2 * t]     : 0;
    int a1 = (2 * t + 1 < NBUK) ? btot[2 * t + 1] : 0;
    int s = a0 + a1;
    sd[t] = s;
    __syncthreads();
    for (int o = 1; o < 256; o <<= 1) {
        int u = (t >= o) ? sd[t - o] : 0;
        __syncthreads();
        sd[t] += u;
        __syncthreads();
    }
    int ex = sd[t] - s;
    bb[2 * t]     = ex;
    bb[2 * t + 1] = ex + a0;
    __syncthreads();
}

// ---------------------------------------------------------------------------
// Prep: Wlin, Wg -> bf16-pair arrays; zero sumsr (32 replicas). 64 blocks x 256.
__global__ __launch_bounds__(256) void k_prep(const float* __restrict__ Wlin,
                                              const float* __restrict__ Wg,
                                              uint* __restrict__ Wlinb,
                                              uint* __restrict__ Wgb,
                                              float* __restrict__ sumsr)
{
    const int idx = blockIdx.x * 256 + threadIdx.x;
    if (blockIdx.x < 32) sumsr[blockIdx.x * 256 + threadIdx.x] = 0.f;
    if (idx < 8192) {
        Wlinb[idx] = packbf(Wlin[2 * idx], Wlin[2 * idx + 1]);
    } else {
        int j = idx - 8192;
        Wgb[j] = packbf(Wg[2 * j], Wg[2 * j + 1]);
    }
}

// ---------------------------------------------------------------------------
// Fused front: blocks [0,G_lin) = GEMM1 (MFMA, x=fea@Wlin^T+blin -> bf16 xb,
// fused BN stats); blocks [G_lin, G_lin+NBLK) = dst-bucket histogram (bhist).
__global__ __launch_bounds__(256) void k_front(const float* __restrict__ fea,
                                               const uint* __restrict__ Wb,
                                               const float* __restrict__ bias,
                                               uint* __restrict__ xb,
                                               float* __restrict__ sumsr,
                                               const void* __restrict__ edges, int E,
                                               int* __restrict__ histm,
                                               int NBUK, int N, int G_lin)
{
    __shared__ uint smem[4352];       // 17408 B: lin x-tile/stats/pack | bhist hist
    const int tid = threadIdx.x;

    if ((int)blockIdx.x >= G_lin) {
        // ---- bhist role ----
        const int bid = blockIdx.x - G_lin;
        int* hh = (int*)smem;
        for (int b = tid; b < 512; b += 256) hh[b] = 0;
        const int isI64 = detect_i64((const int*)edges);
        __syncthreads();
        const long long* e64 = (const long long*)edges;
        const int*       e32 = (const int*)edges;
        const int chunk = (E + NBLK - 1) / NBLK;
        const int lo = bid * chunk;
        const int hi = min(lo + chunk, E);
        for (int e = lo + tid; e < hi; e += 256) {
            int dst = isI64 ? (int)e64[(size_t)E + e] : e32[(size_t)E + e];
            atomicAdd(&hh[dst >> 8], 1);
        }
        __syncthreads();
        for (int b = tid; b < NBUK; b += 256)
            histm[(size_t)b * NBLK + bid] = hh[b];
        return;
    }

    // ---- lin role ----
    const int r0   = blockIdx.x * 64;
    const int lane = tid & 63;
    const int w    = tid >> 6;
    const int fr   = lane & 15;
    const int fk   = lane >> 4;

    #pragma unroll
    for (int it = 0; it < 8; ++it) {
        int flat = it * 256 + tid;
        int row  = flat >> 5;
        int c4   = flat & 31;
        int r    = r0 + row;
        float4 v = make_float4(0.f, 0.f, 0.f, 0.f);
        if (r < N) v = *reinterpret_cast<const float4*>(&fea[(size_t)r * 128 + c4 * 4]);
        smem[row * 68 + c4 * 2]     = packbf(v.x, v.y);
        smem[row * 68 + c4 * 2 + 1] = packbf(v.z, v.w);
    }
    __syncthreads();

    bf16x8 a[4];
    #pragma unroll
    for (int kk = 0; kk < 4; ++kk)
        a[kk] = *reinterpret_cast<const bf16x8*>(
            &smem[(w * 16 + fr) * 68 + kk * 16 + fk * 4]);

    f32x4 acc[8] = {};
    #pragma unroll
    for (int jt = 0; jt < 8; ++jt) {
        #pragma unroll
        for (int kk = 0; kk < 4; ++kk) {
            bf16x8 b = *reinterpret_cast<const bf16x8*>(
                &Wb[(size_t)(jt * 16 + fr) * 64 + kk * 16 + fk * 4]);
            acc[jt] = __builtin_amdgcn_mfma_f32_16x16x32_bf16(a[kk], b, acc[jt], 0, 0, 0);
        }
    }
    __syncthreads();                  // x-tile dead; reuse smem for stats

    float* sred = (float*)smem;       // [16][128]
    float* qred = sred + 2048;        // [16][128]
    #pragma unroll
    for (int jt = 0; jt < 8; ++jt) {
        float bj = bias[jt * 16 + fr];
        float sl = 0.f, ql = 0.f;
        #pragma unroll
        for (int r = 0; r < 4; ++r) {
            int gr = r0 + w * 16 + fk * 4 + r;
            float val = acc[jt][r] + bj;
            val = (gr < N) ? val : 0.f;
            acc[jt][r] = val;
            sl += val; ql += val * val;
        }
        sred[(w * 4 + fk) * 128 + jt * 16 + fr] = sl;
        qred[(w * 4 + fk) * 128 + jt * 16 + fr] = ql;
    }
    __syncthreads();
    if (tid < 128) {
        float S = 0.f, Q = 0.f;
        #pragma unroll
        for (int g = 0; g < 16; ++g) {
            S += sred[g * 128 + tid];
            Q += qred[g * 128 + tid];
        }
        float* dstp = sumsr + (blockIdx.x & 31) * 256;
        atomicAdd(&dstp[tid], S);
        atomicAdd(&dstp[128 + tid], Q);
    }
    __syncthreads();                  // stats reads done; reuse smem for pack

    // pack bf16 pairs into LDS [64][68] then coalesced uint4 store
    #pragma unroll
    for (int jt = 0; jt < 8; ++jt) {
        #pragma unroll
        for (int r = 0; r < 4; ++r) {
            float val = acc[jt][r];
            float pv  = __shfl_xor(val, 1);
            if ((lane & 1) == 0)
                smem[(w * 16 + fk * 4 + r) * 68 + jt * 8 + (fr >> 1)] = packbf(val, pv);
        }
    }
    __syncthreads();
    #pragma unroll
    for (int it = 0; it < 4; ++it) {
        int idx4 = it * 256 + tid;        // 0..1023
        int row  = idx4 >> 4;
        int c4   = idx4 & 15;
        if (r0 + row < N) {
            uint4 v = *reinterpret_cast<const uint4*>(&smem[row * 68 + c4 * 4]);
            *reinterpret_cast<uint4*>(&xb[(size_t)(r0 + row) * 64 + c4 * 4]) = v;
        }
    }
}

// ---------------------------------------------------------------------------
// Pass A2: per-bucket exclusive scan across blocks; emit bucket totals.
__global__ __launch_bounds__(512) void k_bscan(int* __restrict__ histm,
                                               int* __restrict__ btot)
{
    __shared__ int sd[512];
    const int bkt = blockIdx.x;
    const int t = threadIdx.x;
    int v = histm[(size_t)bkt * NBLK + t];
    sd[t] = v;
    __syncthreads();
    for (int o = 1; o < 512; o <<= 1) {
        int u = (t >= o) ? sd[t - o] : 0;
        __syncthreads();
        sd[t] += u;
        __syncthreads();
    }
    histm[(size_t)bkt * NBLK + t] = sd[t] - v;     // exclusive within bucket
    if (t == 511) btot[bkt] = sd[511];
}

// Pass B: scatter packed (src | dstlow<<24) into dst-bucketed bins.
__global__ __launch_bounds__(256) void k_binscatter(const void* __restrict__ edges, int E,
                                                    const int* __restrict__ histm,
                                                    const int* __restrict__ btot,
                                                    uint* __restrict__ bins, int NBUK)
{
    __shared__ int cur[512];
    __shared__ int bb[512];
    __shared__ int sd[256];
    const int isI64 = detect_i64((const int*)edges);
    build_bbase(btot, NBUK, bb, sd);
    for (int b = threadIdx.x; b < NBUK; b += 256)
        cur[b] = bb[b] + histm[(size_t)b * NBLK + blockIdx.x];
    __syncthreads();

    const long long* e64 = (const long long*)edges;
    const int*       e32 = (const int*)edges;
    const int chunk = (E + NBLK - 1) / NBLK;
    const int lo = blockIdx.x * chunk;
    const int hi = min(lo + chunk, E);
    for (int e = lo + threadIdx.x; e < hi; e += 256) {
        int src, dst;
        if (isI64) { src = (int)e64[e]; dst = (int)e64[(size_t)E + e]; }
        else       { src = e32[e];      dst = e32[(size_t)E + e]; }
        int pos = atomicAdd(&cur[dst >> 8], 1);
        bins[pos] = (uint)src | ((uint)(dst & 255) << 24);
    }
}

// Pass C (merged deg+dinv+offs+CSR, 8-padded): one block per bucket.
// Each node's csr list is padded to a multiple of 8 with dummy id N (zero row).
__global__ __launch_bounds__(256) void k_csrdeg(const uint* __restrict__ bins,
                                                const int* __restrict__ btot,
                                                int* __restrict__ pcnt,
                                                float* __restrict__ dinv,
                                                int* __restrict__ offs,
                                                uint* __restrict__ csr,
                                                int N, int NBUK)
{
    __shared__ uint ebuf[EBUF];
    __shared__ int bb[512];
    __shared__ int sd[256];
    __shared__ int c[256];
    const int bkt = blockIdx.x;
    const int t = threadIdx.x;
    build_bbase(btot, NBUK, bb, sd);
    const int lo    = bb[bkt];
    const int total = btot[bkt];
    c[t] = 0;
    __syncthreads();

    const bool fits = (total <= EBUF);
    for (int i = t; i < total; i += 256) {
        uint e = bins[lo + i];
        if (fits) ebuf[i] = e;
        atomicAdd(&c[e >> 24], 1);
    }
    __syncthreads();

    const int node = (bkt << 8) + t;
    const int deg  = c[t];
    const int pdeg = (deg + 7) & ~7;              // pad to multiple of 8
    if (node < N) {
        pcnt[node] = pdeg;
        dinv[node] = rsqrtf((float)(deg + 1));
    }
    sd[t] = pdeg;
    __syncthreads();
    for (int o = 1; o < 256; o <<= 1) {
        int u = (t >= o) ? sd[t - o] : 0;
        __syncthreads();
        sd[t] += u;
        __syncthreads();
    }
    // padded bucket base: unpadded base + bkt*2048 (max pad 256*7 < 2048)
    const int myoff = lo + (bkt << 11) + sd[t] - pdeg;
    if (node < N) offs[node] = myoff;
    c[t] = myoff;                                 // reuse as write cursor
    __syncthreads();
    for (int i = t; i < total; i += 256) {
        uint e = fits ? ebuf[i] : bins[lo + i];
        int pos = atomicAdd(&c[e >> 24], 1);
        csr[pos] = e & 0x00ffffffu;
    }
    // padding slots -> dummy node N (its hb row is all zeros)
    for (int k2 = deg; k2 < pdeg; ++k2)
        csr[myoff + k2] = (uint)N;
}

// ---------------------------------------------------------------------------
// GEMM2 (MFMA): h' = dinv * (leakyrelu(a*x + b) @ Wg^T) -> fp8(e4m3) hb.
// Also writes the all-zero dummy row N. Coalesced stores via LDS staging.
__global__ __launch_bounds__(256) void k_h(const uint* __restrict__ xb,
                                           const uint* __restrict__ Wb,
                                           const float* __restrict__ sumsr,
                                           const float* __restrict__ gamma,
                                           const float* __restrict__ beta,
                                           const float* __restrict__ dinv,
                                           float invN,
                                           uint* __restrict__ hb, int N)
{
    __shared__ uint xls[4352];        // x-tile [64][68] / fp8 pack [64][36]
    __shared__ float aff[256];
    const int tid  = threadIdx.x;
    const int r0   = blockIdx.x * 64;
    const int lane = tid & 63;
    const int w    = tid >> 6;
    const int fr   = lane & 15;
    const int fk   = lane >> 4;

    if (tid < 128) {
        float S = 0.f, Q = 0.f;
        #pragma unroll
        for (int rep = 0; rep < 32; ++rep) {
            S += sumsr[rep * 256 + tid];
            Q += sumsr[rep * 256 + 128 + tid];
        }
        float mean = S * invN;
        float var  = Q * invN - mean * mean;
        float coef = gamma[tid] * rsqrtf(var + BN_EPS);
        aff[tid]       = coef;
        aff[128 + tid] = beta[tid] - coef * mean;
    }
    __syncthreads();

    #pragma unroll
    for (int it = 0; it < 16; ++it) {
        int flat = it * 256 + tid;
        int row  = flat >> 6;
        int u    = flat & 63;
        int r    = r0 + row;
        uint v   = (r < N) ? xb[(size_t)r * 64 + u] : 0u;
        float y0 = fmaf(aff[2 * u],     bflo(v), aff[128 + 2 * u]);
        float y1 = fmaf(aff[2 * u + 1], bfhi(v), aff[128 + 2 * u + 1]);
        y0 = (y0 >= 0.f) ? y0 : LEAKY * y0;
        y1 = (y1 >= 0.f) ? y1 : LEAKY * y1;
        xls[row * 68 + u] = packbf(y0, y1);
    }
    __syncthreads();

    bf16x8 a[4];
    #pragma unroll
    for (int kk = 0; kk < 4; ++kk)
        a[kk] = *reinterpret_cast<const bf16x8*>(
            &xls[(w * 16 + fr) * 68 + kk * 16 + fk * 4]);

    f32x4 acc[8] = {};
    #pragma unroll
    for (int jt = 0; jt < 8; ++jt) {
        #pragma unroll
        for (int kk = 0; kk < 4; ++kk) {
            bf16x8 b = *reinterpret_cast<const bf16x8*>(
                &Wb[(size_t)(jt * 16 + fr) * 64 + kk * 16 + fk * 4]);
            acc[jt] = __builtin_amdgcn_mfma_f32_16x16x32_bf16(a[kk], b, acc[jt], 0, 0, 0);
        }
    }

    float dv[4];
    #pragma unroll
    for (int r = 0; r < 4; ++r) {
        int gr = r0 + w * 16 + fk * 4 + r;
        dv[r] = (gr < N) ? dinv[gr] : 0.f;        // row N (and beyond) -> 0
    }
    __syncthreads();                  // x-tile dead; reuse for fp8 pack

    #pragma unroll
    for (int jt = 0; jt < 8; ++jt) {
        #pragma unroll
        for (int r = 0; r < 4; ++r) {
            float val = acc[jt][r] * dv[r];
            float p1  = __shfl_xor(val, 1);
            uint lo16 = (uint)__builtin_amdgcn_cvt_pk_fp8_f32(val, p1, 0, false) & 0xffffu;
            uint hi16 = __shfl_xor(lo16, 2);
            if ((fr & 3) == 0)
                xls[(w * 16 + fk * 4 + r) * 36 + jt * 4 + (fr >> 2)] = lo16 | (hi16 << 16);
        }
    }
    __syncthreads();
    #pragma unroll
    for (int it = 0; it < 2; ++it) {
        int idx4 = it * 256 + tid;        // 0..511
        int row  = idx4 >> 3;
        int c4   = idx4 & 7;
        if (r0 + row <= N) {              // include zero row N
            uint4 v = *reinterpret_cast<const uint4*>(&xls[row * 36 + c4 * 4]);
            *reinterpret_cast<uint4*>(&hb[(size_t)(r0 + row) * 32 + c4 * 4]) = v;
        }
    }
}

// ---------------------------------------------------------------------------
// Gather aggregation: out[i] = dinv[i]*(sum h'[src] + h'[i]) + bg, log_softmax.
// Maskless inner loop (edge lists padded to x8 with zero-row ids).
__global__ __launch_bounds__(256) void k_agg(const uint* __restrict__ hb,
                                             const uint* __restrict__ csr,
                                             const int* __restrict__ offs,
                                             const int* __restrict__ pcnt,
                                             const float* __restrict__ dinv,
                                             const float* __restrict__ bg,
                                             float* __restrict__ out, int N)
{
    const int wid  = (blockIdx.x * blockDim.x + threadIdx.x) >> 6;
    const int lane = threadIdx.x & 63;
    if (wid >= N) return;
    const int i = wid;
    const int p = lane & 15;      // 8-B chunk within row (features 8p..8p+7)
    const int q = lane >> 4;      // edge subgroup 0..3
    const uint2* hbp = reinterpret_cast<const uint2*>(hb) + p;

    f32x2 acc[4] = {};
    const int start = offs[i];
    const int m     = pcnt[i];    // multiple of 8

    for (int base = 0; base < m; base += 64) {
        const int nb = min(64, m - base);          // multiple of 8
        uint sx = (uint)N;
        if (lane < nb)
            sx = __builtin_nontemporal_load(&csr[start + base + lane]);
        for (int j = 0; j < nb; j += 8) {
            #pragma unroll
            for (int hh = 0; hh < 2; ++hh) {
                int s = __shfl((int)sx, j + hh * 4 + q);
                const uint2 v = hbp[(uint)s * 16];
                acc[0] += __builtin_amdgcn_cvt_pk_f32_fp8((int)v.x, false);
                acc[1] += __builtin_amdgcn_cvt_pk_f32_fp8((int)v.x, true);
                acc[2] += __builtin_amdgcn_cvt_pk_f32_fp8((int)v.y, false);
                acc[3] += __builtin_amdgcn_cvt_pk_f32_fp8((int)v.y, true);
            }
        }
    }

    // reduce the 4 edge subgroups
    #pragma unroll
    for (int r = 0; r < 4; ++r) {
        acc[r].x += __shfl_xor(acc[r].x, 16);
        acc[r].y += __shfl_xor(acc[r].y, 16);
        acc[r].x += __shfl_xor(acc[r].x, 32);
        acc[r].y += __shfl_xor(acc[r].y, 32);
    }

    // self term (h'[i]), then scale by dinv[i], add bias
    const uint2 sv = hbp[(uint)i * 16];
    acc[0] += __builtin_amdgcn_cvt_pk_f32_fp8((int)sv.x, false);
    acc[1] += __builtin_amdgcn_cvt_pk_f32_fp8((int)sv.x, true);
    acc[2] += __builtin_amdgcn_cvt_pk_f32_fp8((int)sv.y, false);
    acc[3] += __builtin_amdgcn_cvt_pk_f32_fp8((int)sv.y, true);

    const float d0 = dinv[i];
    float4 b0 = *reinterpret_cast<const float4*>(&bg[p * 8]);
    float4 b1 = *reinterpret_cast<const float4*>(&bg[p * 8 + 4]);
    float v0 = fmaf(d0, acc[0].x, b0.x);
    float v1 = fmaf(d0, acc[0].y, b0.y);
    float v2 = fmaf(d0, acc[1].x, b0.z);
    float v3 = fmaf(d0, acc[1].y, b0.w);
    float v4 = fmaf(d0, acc[2].x, b1.x);
    float v5 = fmaf(d0, acc[2].y, b1.y);
    float v6 = fmaf(d0, acc[3].x, b1.z);
    float v7 = fmaf(d0, acc[3].y, b1.w);

    // log_softmax over 128 features (distributed across 16 lanes)
    float mx = fmaxf(fmaxf(fmaxf(v0, v1), fmaxf(v2, v3)),
                     fmaxf(fmaxf(v4, v5), fmaxf(v6, v7)));
    #pragma unroll
    for (int o = 8; o > 0; o >>= 1) mx = fmaxf(mx, __shfl_xor(mx, o));
    float sum = __expf(v0 - mx) + __expf(v1 - mx) + __expf(v2 - mx) + __expf(v3 - mx)
              + __expf(v4 - mx) + __expf(v5 - mx) + __expf(v6 - mx) + __expf(v7 - mx);
    #pragma unroll
    for (int o = 8; o > 0; o >>= 1) sum += __shfl_xor(sum, o);
    float ls = mx + __logf(sum);

    if (q == 0) {
        f32x4 o0 = {v0 - ls, v1 - ls, v2 - ls, v3 - ls};
        f32x4 o1 = {v4 - ls, v5 - ls, v6 - ls, v7 - ls};
        __builtin_nontemporal_store(o0, reinterpret_cast<f32x4*>(&out[(size_t)i * 128 + p * 8]));
        __builtin_nontemporal_store(o1, reinterpret_cast<f32x4*>(&out[(size_t)i * 128 + p * 8 + 4]));
    }
}

// ---------------------------------------------------------------------------
extern "C" void kernel_launch(void* const* d_in, const int* in_sizes, int n_in,
                              void* d_out, int out_size, void* d_ws, size_t ws_size,
                              hipStream_t stream)
{
    (void)n_in; (void)out_size; (void)ws_size;
    const float* fea   = (const float*)d_in[0];
    const void*  edges = d_in[1];
    const float* Wlin  = (const float*)d_in[2];
    const float* blin  = (const float*)d_in[3];
    const float* gamma = (const float*)d_in[4];
    const float* beta  = (const float*)d_in[5];
    const float* Wg    = (const float*)d_in[6];
    const float* bg    = (const float*)d_in[7];
    float* out = (float*)d_out;

    const int N    = in_sizes[0] / 128;
    const int E    = in_sizes[1] / 2;
    const int NBUK = (N + 255) >> 8;          // dst buckets (256 nodes each)
    const int GLIN = (N + 63) / 64;

    char* p = (char*)d_ws;
    uint*  xb   = (uint*)p;    p += (size_t)N * 64 * 4;
    uint*  bins = (uint*)p;    p += (size_t)E * 4;
    uint*  hb   = (uint*)p;    p += ((size_t)N + 1) * 32 * 4;  // fp8 h' + zero row
    uint*  csr  = (uint*)p;    p += ((size_t)E + ((size_t)NBUK << 11)) * 4;
    int*   histm = (int*)p;    p += (size_t)NBUK * NBLK * 4;
    float* sumsr = (float*)p;  p += 32 * 256 * 4;              // 32 replicas
    int*   pcnt = (int*)p;     p += (size_t)N * 4;
    int*   offs = (int*)p;     p += (size_t)N * 4;
    float* dinv = (float*)p;   p += (size_t)N * 4;
    int*   btot = (int*)p;     p += 512 * 4;
    uint*  Wlinb = (uint*)p;   p += 8192 * 4;
    uint*  Wgb   = (uint*)p;   p += 8192 * 4;

    // --- prep (W -> bf16, zero sumsr) ---
    k_prep<<<64, 256, 0, stream>>>(Wlin, Wg, Wlinb, Wgb, sumsr);

    // --- fused GEMM1 || edge histogram ---
    k_front<<<GLIN + NBLK, 256, 0, stream>>>(fea, Wlinb, blin, xb, sumsr,
                                             edges, E, histm, NBUK, N, GLIN);

    // --- graph build ---
    k_bscan<<<NBUK, 512, 0, stream>>>(histm, btot);
    k_binscatter<<<NBLK, 256, 0, stream>>>(edges, E, histm, btot, bins, NBUK);
    k_csrdeg<<<NBUK, 256, 0, stream>>>(bins, btot, pcnt, dinv, offs, csr, N, NBUK);

    // --- GEMM2 (covers zero row N) ---
    k_h<<<(N + 64) / 64, 256, 0, stream>>>(xb, Wgb, sumsr, gamma, beta, dinv,
                                           1.0f / (float)N, hb, N);

    // --- aggregation + log_softmax ---
    k_agg<<<(N + 3) / 4, 256, 0, stream>>>(hb, csr, offs, pcnt, dinv, bg, out, N);
}